// Round 6
// baseline (168.864 us; speedup 1.0000x reference)
//
#include <hip/hip_runtime.h>
#include <cstdint>
#include <cstddef>

typedef float    f32x4  __attribute__((ext_vector_type(4)));
typedef __bf16   bf16x8 __attribute__((ext_vector_type(8)));
typedef unsigned u32x4  __attribute__((ext_vector_type(4)));
typedef unsigned u32x2  __attribute__((ext_vector_type(2)));
typedef unsigned short u16;
typedef unsigned int   u32;

#define SCL2E 0.18033688011112042f   /* 0.125 * log2(e) */
#define NEGC  (-34.624681566719483f) /* -24 * log2(e)   */

static __device__ __forceinline__ u16 f2bf(float f) {
    u32 u = __builtin_bit_cast(u32, f);
    u32 r = (u + 0x7FFFu + ((u >> 16) & 1u)) >> 16;
    return (u16)r;
}

static __device__ __forceinline__ u32 cvtpk_bf16(float lo, float hi) {
    u32 r;
    asm("v_cvt_pk_bf16_f32 %0, %1, %2" : "=v"(r) : "v"(lo), "v"(hi));
    return r;
}

static __device__ __forceinline__ void gll16(const u16* g, void* l) {
    __builtin_amdgcn_global_load_lds((const __attribute__((address_space(1))) void*)g,
                                     (__attribute__((address_space(3))) void*)l, 16, 0, 0);
}

// ---------------- prep kernels ----------------

__global__ void conv_x_k(const float* __restrict__ x, u16* __restrict__ xb) {
    const long i = ((long)blockIdx.x * 256 + threadIdx.x) * 8;
    f32x4 a = *(const f32x4*)(x + i);
    f32x4 c = *(const f32x4*)(x + i + 4);
    u32x4 o;
    o[0] = (u32)f2bf(a[0]) | ((u32)f2bf(a[1]) << 16);
    o[1] = (u32)f2bf(a[2]) | ((u32)f2bf(a[3]) << 16);
    o[2] = (u32)f2bf(c[0]) | ((u32)f2bf(c[1]) << 16);
    o[3] = (u32)f2bf(c[2]) | ((u32)f2bf(c[3]) << 16);
    *(u32x4*)(xb + i) = o;
}

// transpose 1024x1024 f32 -> bf16 [N][K]
__global__ __launch_bounds__(256) void conv_w_k(
    const float* __restrict__ W0, const float* __restrict__ W1,
    const float* __restrict__ W2, const float* __restrict__ W3,
    u16* __restrict__ T0, u16* __restrict__ T1,
    u16* __restrict__ T2, u16* __restrict__ T3)
{
    __shared__ float T[64][65];
    const int z = blockIdx.z;
    const float* W = (z == 0) ? W0 : (z == 1) ? W1 : (z == 2) ? W2 : W3;
    u16* Wt = (z == 0) ? T0 : (z == 1) ? T1 : (z == 2) ? T2 : T3;
    const int k0 = blockIdx.y * 64, n0 = blockIdx.x * 64;
    const int c = threadIdx.x & 63, r0 = (threadIdx.x >> 6) * 16;
#pragma unroll
    for (int i = 0; i < 16; ++i)
        T[r0 + i][c] = W[(long)(k0 + r0 + i) * 1024 + n0 + c];
    __syncthreads();
#pragma unroll
    for (int i = 0; i < 16; ++i)
        Wt[(long)(n0 + r0 + i) * 1024 + k0 + c] = f2bf(T[c][r0 + i]);
}

// pack mask int32 -> bit per element (bit set == masked out); 1 u32 word per thread
__global__ void pack_mask_k(const int* __restrict__ mask, u32* __restrict__ mp) {
    const long wi = (long)blockIdx.x * 256 + threadIdx.x;
    const int* src = mask + wi * 32;
    u32 word = 0;
#pragma unroll
    for (int c = 0; c < 8; ++c) {
        const int4 v = *(const int4*)(src + c * 4);
        word |= (u32)(v.x != 0) << (c * 4);
        word |= (u32)(v.y != 0) << (c * 4 + 1);
        word |= (u32)(v.z != 0) << (c * 4 + 2);
        word |= (u32)(v.w != 0) << (c * 4 + 3);
    }
    mp[wi] = word;
}

// ---------------- QK GEMM: [4096x1024] @ [1024x2048] (Wq,Wk fused) ----------

__global__ __launch_bounds__(256, 3) void gemm_qkv(
    const u16* __restrict__ A, const u16* __restrict__ Bt, u16* __restrict__ C0)
{
    constexpr int K = 1024;
    __shared__ u16 As[2][128 * 32];
    __shared__ u16 Bs[2][128 * 32];
    const int tid = threadIdx.x;
    const int wave = tid >> 6, lane = tid & 63;
    const int wr = wave >> 1, wc = wave & 1;
    const int g = lane >> 4, lr = lane & 15;
    const long mBase = (long)blockIdx.y * 128;
    const long nBase = (long)blockIdx.x * 128;

    f32x4 acc[4][4];
#pragma unroll
    for (int i = 0; i < 4; ++i)
#pragma unroll
        for (int j = 0; j < 4; ++j) acc[i][j] = f32x4{0.f, 0.f, 0.f, 0.f};

    const int o0 = tid * 16, o1 = (256 + tid) * 16;
    const int r0 = o0 >> 6, cb0 = o0 & 63;
    const int r1 = o1 >> 6, cb1 = o1 & 63;

    gll16(A  + (mBase + r0) * K + (cb0 >> 1), (char*)&As[0][0] + o0);
    gll16(A  + (mBase + r1) * K + (cb1 >> 1), (char*)&As[0][0] + o1);
    gll16(Bt + (nBase + r0) * K + (cb0 >> 1), (char*)&Bs[0][0] + o0);
    gll16(Bt + (nBase + r1) * K + (cb1 >> 1), (char*)&Bs[0][0] + o1);
    __syncthreads();

    for (int kt = 0; kt < 32; ++kt) {
        const int buf = kt & 1;
        if (kt + 1 < 32) {
            const long ko = (long)(kt + 1) * 32;
            gll16(A  + (mBase + r0) * K + ko + (cb0 >> 1), (char*)&As[buf ^ 1][0] + o0);
            gll16(A  + (mBase + r1) * K + ko + (cb1 >> 1), (char*)&As[buf ^ 1][0] + o1);
            gll16(Bt + (nBase + r0) * K + ko + (cb0 >> 1), (char*)&Bs[buf ^ 1][0] + o0);
            gll16(Bt + (nBase + r1) * K + ko + (cb1 >> 1), (char*)&Bs[buf ^ 1][0] + o1);
        }
        bf16x8 af[4], bfv[4];
#pragma unroll
        for (int mi = 0; mi < 4; ++mi)
            af[mi] = *(const bf16x8*)((const char*)&As[buf][0] + (wr * 64 + mi * 16 + lr) * 64 + g * 16);
#pragma unroll
        for (int ni = 0; ni < 4; ++ni)
            bfv[ni] = *(const bf16x8*)((const char*)&Bs[buf][0] + (wc * 64 + ni * 16 + lr) * 64 + g * 16);
#pragma unroll
        for (int mi = 0; mi < 4; ++mi)
#pragma unroll
            for (int ni = 0; ni < 4; ++ni)
                acc[mi][ni] = __builtin_amdgcn_mfma_f32_16x16x32_bf16(af[mi], bfv[ni], acc[mi][ni], 0, 0, 0);
        __syncthreads();
    }

    const int wsel = (int)(nBase >> 10);
    u16* Cw = C0 + (long)wsel * (4096l * 1024);
    const long ncl = nBase & 1023;
#pragma unroll
    for (int mi = 0; mi < 4; ++mi)
#pragma unroll
        for (int r = 0; r < 4; ++r) {
            const long row = mBase + wr * 64 + mi * 16 + g * 4 + r;
#pragma unroll
            for (int ni = 0; ni < 4; ++ni) {
                const long col = ncl + wc * 64 + ni * 16 + lr;
                Cw[row * 1024 + col] = f2bf(acc[mi][ni][r]);
            }
        }
}

// ---------------- V^T GEMM: vt[d][token] = sum_k WvT[d][k] * xb[token][k] ----
// M=1024 (d rows), N=4096 (tokens), C stride 4096. grid (32, 8).

__global__ __launch_bounds__(256, 3) void gemm_vt(
    const u16* __restrict__ A, const u16* __restrict__ Bt, u16* __restrict__ Cb)
{
    constexpr int K = 1024;
    __shared__ u16 As[2][128 * 32];
    __shared__ u16 Bs[2][128 * 32];
    const int tid = threadIdx.x;
    const int wave = tid >> 6, lane = tid & 63;
    const int wr = wave >> 1, wc = wave & 1;
    const int g = lane >> 4, lr = lane & 15;
    const long mBase = (long)blockIdx.y * 128;
    const long nBase = (long)blockIdx.x * 128;

    f32x4 acc[4][4];
#pragma unroll
    for (int i = 0; i < 4; ++i)
#pragma unroll
        for (int j = 0; j < 4; ++j) acc[i][j] = f32x4{0.f, 0.f, 0.f, 0.f};

    const int o0 = tid * 16, o1 = (256 + tid) * 16;
    const int r0 = o0 >> 6, cb0 = o0 & 63;
    const int r1 = o1 >> 6, cb1 = o1 & 63;

    gll16(A  + (mBase + r0) * K + (cb0 >> 1), (char*)&As[0][0] + o0);
    gll16(A  + (mBase + r1) * K + (cb1 >> 1), (char*)&As[0][0] + o1);
    gll16(Bt + (nBase + r0) * K + (cb0 >> 1), (char*)&Bs[0][0] + o0);
    gll16(Bt + (nBase + r1) * K + (cb1 >> 1), (char*)&Bs[0][0] + o1);
    __syncthreads();

    for (int kt = 0; kt < 32; ++kt) {
        const int buf = kt & 1;
        if (kt + 1 < 32) {
            const long ko = (long)(kt + 1) * 32;
            gll16(A  + (mBase + r0) * K + ko + (cb0 >> 1), (char*)&As[buf ^ 1][0] + o0);
            gll16(A  + (mBase + r1) * K + ko + (cb1 >> 1), (char*)&As[buf ^ 1][0] + o1);
            gll16(Bt + (nBase + r0) * K + ko + (cb0 >> 1), (char*)&Bs[buf ^ 1][0] + o0);
            gll16(Bt + (nBase + r1) * K + ko + (cb1 >> 1), (char*)&Bs[buf ^ 1][0] + o1);
        }
        bf16x8 af[4], bfv[4];
#pragma unroll
        for (int mi = 0; mi < 4; ++mi)
            af[mi] = *(const bf16x8*)((const char*)&As[buf][0] + (wr * 64 + mi * 16 + lr) * 64 + g * 16);
#pragma unroll
        for (int ni = 0; ni < 4; ++ni)
            bfv[ni] = *(const bf16x8*)((const char*)&Bs[buf][0] + (wc * 64 + ni * 16 + lr) * 64 + g * 16);
#pragma unroll
        for (int mi = 0; mi < 4; ++mi)
#pragma unroll
            for (int ni = 0; ni < 4; ++ni)
                acc[mi][ni] = __builtin_amdgcn_mfma_f32_16x16x32_bf16(af[mi], bfv[ni], acc[mi][ni], 0, 0, 0);
        __syncthreads();
    }

#pragma unroll
    for (int mi = 0; mi < 4; ++mi)
#pragma unroll
        for (int r = 0; r < 4; ++r) {
            const long row = mBase + wr * 64 + mi * 16 + g * 4 + r;
#pragma unroll
            for (int ni = 0; ni < 4; ++ni) {
                const long col = nBase + wc * 64 + ni * 16 + lr;
                Cb[row * 4096 + col] = f2bf(acc[mi][ni][r]);
            }
        }
}

// ---------------- output-proj GEMM (f32 out + bias) ----------------

__global__ __launch_bounds__(256, 3) void gemm_out(
    const u16* __restrict__ A, const u16* __restrict__ Bt,
    float* __restrict__ Cf, const float* __restrict__ bias)
{
    constexpr int K = 1024, N = 1024;
    __shared__ u16 As[2][128 * 32];
    __shared__ u16 Bs[2][128 * 32];
    const int tid = threadIdx.x;
    const int wave = tid >> 6, lane = tid & 63;
    const int wr = wave >> 1, wc = wave & 1;
    const int g = lane >> 4, lr = lane & 15;
    const long mBase = (long)blockIdx.y * 128;
    const long nBase = (long)blockIdx.x * 128;

    f32x4 acc[4][4];
#pragma unroll
    for (int i = 0; i < 4; ++i)
#pragma unroll
        for (int j = 0; j < 4; ++j) acc[i][j] = f32x4{0.f, 0.f, 0.f, 0.f};

    const int o0 = tid * 16, o1 = (256 + tid) * 16;
    const int r0 = o0 >> 6, cb0 = o0 & 63;
    const int r1 = o1 >> 6, cb1 = o1 & 63;

    gll16(A  + (mBase + r0) * K + (cb0 >> 1), (char*)&As[0][0] + o0);
    gll16(A  + (mBase + r1) * K + (cb1 >> 1), (char*)&As[0][0] + o1);
    gll16(Bt + (nBase + r0) * K + (cb0 >> 1), (char*)&Bs[0][0] + o0);
    gll16(Bt + (nBase + r1) * K + (cb1 >> 1), (char*)&Bs[0][0] + o1);
    __syncthreads();

    for (int kt = 0; kt < 32; ++kt) {
        const int buf = kt & 1;
        if (kt + 1 < 32) {
            const long ko = (long)(kt + 1) * 32;
            gll16(A  + (mBase + r0) * K + ko + (cb0 >> 1), (char*)&As[buf ^ 1][0] + o0);
            gll16(A  + (mBase + r1) * K + ko + (cb1 >> 1), (char*)&As[buf ^ 1][0] + o1);
            gll16(Bt + (nBase + r0) * K + ko + (cb0 >> 1), (char*)&Bs[buf ^ 1][0] + o0);
            gll16(Bt + (nBase + r1) * K + ko + (cb1 >> 1), (char*)&Bs[buf ^ 1][0] + o1);
        }
        bf16x8 af[4], bfv[4];
#pragma unroll
        for (int mi = 0; mi < 4; ++mi)
            af[mi] = *(const bf16x8*)((const char*)&As[buf][0] + (wr * 64 + mi * 16 + lr) * 64 + g * 16);
#pragma unroll
        for (int ni = 0; ni < 4; ++ni)
            bfv[ni] = *(const bf16x8*)((const char*)&Bs[buf][0] + (wc * 64 + ni * 16 + lr) * 64 + g * 16);
#pragma unroll
        for (int mi = 0; mi < 4; ++mi)
#pragma unroll
            for (int ni = 0; ni < 4; ++ni)
                acc[mi][ni] = __builtin_amdgcn_mfma_f32_16x16x32_bf16(af[mi], bfv[ni], acc[mi][ni], 0, 0, 0);
        __syncthreads();
    }

#pragma unroll
    for (int mi = 0; mi < 4; ++mi)
#pragma unroll
        for (int r = 0; r < 4; ++r) {
            const long row = mBase + wr * 64 + mi * 16 + g * 4 + r;
#pragma unroll
            for (int ni = 0; ni < 4; ++ni) {
                const long col = nBase + wc * 64 + ni * 16 + lr;
                Cf[row * N + col] = acc[mi][ni][r] + bias[col];
            }
        }
}

// ---------------- flash attention (KVBLK=128: 2 proven 64-halves per sync) --
// grid (N/128, H, B); block 256 = 4 waves, 32 q-rows per wave (nq=2).
// S^T = mfma(K,Q); kappa-permuted K; V^T computed directly by gemm_vt
// (global [1024 d][4096 token], stride 4096). 16 iterations of 128 kv each:
// stage next 128-tile (2 sets x 2 halves), compute both halves, one
// __syncthreads per 128 kv. Fixed-C softmax (C=24 exp-units).

__global__ __launch_bounds__(256, 2) void attn_fwd(
    const u16* __restrict__ Qg_, const u16* __restrict__ Kg_, const u16* __restrict__ Vtg_,
    const u32* __restrict__ maskp, u16* __restrict__ Og_)
{
    __shared__ u16 Ks[2][2][64 * 64];  // [set][half], kappa-permuted + swizzled
    __shared__ u16 Vs[2][2][64 * 64];  // [set][half], rows=d, swizzled

    const int tid = threadIdx.x, w = tid >> 6, lane = tid & 63;
    const int g = lane >> 4, lr = lane & 15;
    const int q0 = blockIdx.x * 128, h = blockIdx.y, b = blockIdx.z;
    const u16* Qg = Qg_ + ((long)b * 2048) * 1024 + h * 64;
    const u16* Kg = Kg_ + ((long)b * 2048) * 1024 + h * 64;
    const u16* Vtg = Vtg_ + (long)(h * 64) * 4096 + b * 2048;
    u16* Og = Og_ + ((long)b * 2048) * 1024 + h * 64;

    // ---- staging address precompute (2 chunks of 16B per thread each) ----
    long ksrc[2], vsrc[2];
    int ldso[2];
#pragma unroll
    for (int c = 0; c < 2; ++c) {
        const int o = (tid + c * 256) * 16;
        const int m = o >> 7, cb = o & 127;
        const int sb = cb ^ ((m & 7) << 4);
        ldso[c] = o;
        const int kap = ((m >> 4) & 1) * 32 + ((m >> 2) & 3) * 8 + ((m >> 5) & 1) * 4 + (m & 3);
        ksrc[c] = (long)kap * 1024 + (sb >> 1);
        vsrc[c] = (long)m * 4096 + (sb >> 1);
    }

    // ---- Q straight to registers (no LDS) ----
    bf16x8 qf[2][2];
#pragma unroll
    for (int nq = 0; nq < 2; ++nq)
#pragma unroll
        for (int ks = 0; ks < 2; ++ks)
            qf[nq][ks] = *(const bf16x8*)(Qg + (long)(q0 + w * 32 + nq * 16 + lr) * 1024 + ks * 32 + g * 8);

    const long mrow0 = (long)b * 2048 + q0 + w * 32 + lr;
    const u32* mpr0 = maskp + mrow0 * 64;
    const u32* mpr1 = maskp + (mrow0 + 16) * 64;

    // ---- prologue: mask(0) -> regs; stage set 0 (both halves) ----
    u32x4 mwC0 = *(const u32x4*)(mpr0);
    u32x4 mwC1 = *(const u32x4*)(mpr1);
#pragma unroll
    for (int hh = 0; hh < 2; ++hh)
#pragma unroll
        for (int c = 0; c < 2; ++c) {
            gll16(Kg + hh * 65536 + ksrc[c], (char*)&Ks[0][hh][0] + ldso[c]);
            gll16(Vtg + hh * 64 + vsrc[c], (char*)&Vs[0][hh][0] + ldso[c]);
        }
    __syncthreads();

    const int swz = (lr & 7) << 4;
    int kb[2];
#pragma unroll
    for (int ks = 0; ks < 2; ++ks) kb[ks] = (ks * 64 + g * 16) ^ swz;

    f32x4 oacc[2][4];
#pragma unroll
    for (int i = 0; i < 2; ++i)
#pragma unroll
        for (int j = 0; j < 4; ++j) oacc[i][j] = f32x4{0.f, 0.f, 0.f, 0.f};
    float sum[2] = {0.f, 0.f};
    const f32x4 z4 = {0.f, 0.f, 0.f, 0.f};

    for (int t = 0; t < 16; ++t) {
        const int cur = t & 1;
        // ---- prefetch mask(t+1) -> regs; stage(t+1) -> other set ----
        u32x4 mwN0, mwN1;
        if (t + 1 < 16) {
            mwN0 = *(const u32x4*)(mpr0 + (t + 1) * 4);
            mwN1 = *(const u32x4*)(mpr1 + (t + 1) * 4);
            const long kv0 = (long)(t + 1) * 128;
#pragma unroll
            for (int hh = 0; hh < 2; ++hh)
#pragma unroll
                for (int c = 0; c < 2; ++c) {
                    gll16(Kg + (kv0 + hh * 64) * 1024 + ksrc[c], (char*)&Ks[cur ^ 1][hh][0] + ldso[c]);
                    gll16(Vtg + kv0 + hh * 64 + vsrc[c], (char*)&Vs[cur ^ 1][hh][0] + ldso[c]);
                }
        }

        // ---- two 64-kv halves, identical proven structure ----
#pragma unroll
        for (int hh = 0; hh < 2; ++hh) {
            const char* kbase = (const char*)&Ks[cur][hh][0];
            const char* vbase = (const char*)&Vs[cur][hh][0];

            // S^T = K . Q^T
            f32x4 s[4][2];
            __builtin_amdgcn_s_setprio(1);
#pragma unroll
            for (int mt = 0; mt < 4; ++mt) {
                const bf16x8 kf0 = *(const bf16x8*)(kbase + (mt * 16 + lr) * 128 + kb[0]);
                const bf16x8 kf1 = *(const bf16x8*)(kbase + (mt * 16 + lr) * 128 + kb[1]);
#pragma unroll
                for (int nq = 0; nq < 2; ++nq) {
                    s[mt][nq] = __builtin_amdgcn_mfma_f32_16x16x32_bf16(kf0, qf[nq][0], z4, 0, 0, 0);
                    s[mt][nq] = __builtin_amdgcn_mfma_f32_16x16x32_bf16(kf1, qf[nq][1], s[mt][nq], 0, 0, 0);
                }
            }
            __builtin_amdgcn_s_setprio(0);

            // fixed-C masked softmax (in-register)
            u32 pk[4][2][2];
#pragma unroll
            for (int ts = 0; ts < 4; ++ts) {
                const int sh = g * 8 + (ts >> 1) * 4;
                const int wi = hh * 2 + (ts & 1);
#pragma unroll
                for (int nq = 0; nq < 2; ++nq) {
                    const u32 word = nq ? mwC1[wi] : mwC0[wi];
                    const u32 wsh = word >> sh;
                    float e[4];
#pragma unroll
                    for (int r = 0; r < 4; ++r) {
                        float sv = fmaf(s[ts][nq][r], SCL2E, NEGC);
                        sv = ((wsh >> r) & 1u) ? -512.f : sv;
                        const float ev = __builtin_exp2f(sv);
                        e[r] = ev;
                        sum[nq] += ev;
                    }
                    pk[ts][nq][0] = cvtpk_bf16(e[0], e[1]);
                    pk[ts][nq][1] = cvtpk_bf16(e[2], e[3]);
                }
            }

            // O += P . V
            bf16x8 pa[2][2];
#pragma unroll
            for (int nq = 0; nq < 2; ++nq)
#pragma unroll
                for (int ks = 0; ks < 2; ++ks) {
                    u32x4 t4;
                    t4[0] = pk[ks][nq][0]; t4[1] = pk[ks][nq][1];
                    t4[2] = pk[ks + 2][nq][0]; t4[3] = pk[ks + 2][nq][1];
                    pa[nq][ks] = __builtin_bit_cast(bf16x8, t4);
                }
            __builtin_amdgcn_s_setprio(1);
#pragma unroll
            for (int dt = 0; dt < 4; ++dt)
#pragma unroll
                for (int ks = 0; ks < 2; ++ks) {
                    const bf16x8 vf = *(const bf16x8*)(vbase + (dt * 16 + lr) * 128 + kb[ks]);
#pragma unroll
                    for (int nq = 0; nq < 2; ++nq)
                        oacc[nq][dt] = __builtin_amdgcn_mfma_f32_16x16x32_bf16(pa[nq][ks], vf, oacc[nq][dt], 0, 0, 0);
                }
            __builtin_amdgcn_s_setprio(0);
        }
        __syncthreads();

        mwC0 = mwN0; mwC1 = mwN1;
    }

    // ---- epilogue: final sum reduce + normalize + store ----
#pragma unroll
    for (int nq = 0; nq < 2; ++nq) {
        sum[nq] += __shfl_xor(sum[nq], 16);
        sum[nq] += __shfl_xor(sum[nq], 32);
    }
#pragma unroll
    for (int nq = 0; nq < 2; ++nq)
#pragma unroll
        for (int rr = 0; rr < 4; ++rr) {
            const float den = __shfl(sum[nq], g * 4 + rr);
            const float inv = __builtin_amdgcn_rcpf(den);
            const long row = (long)q0 + w * 32 + nq * 16 + g * 4 + rr;
#pragma unroll
            for (int dt = 0; dt < 4; ++dt)
                Og[row * 1024 + dt * 16 + lr] = f2bf(oacc[nq][dt][rr] * inv);
        }
}

// ---------------- launcher ----------------

extern "C" void kernel_launch(void* const* d_in, const int* in_sizes, int n_in,
                              void* d_out, int out_size, void* d_ws, size_t ws_size,
                              hipStream_t stream)
{
    (void)in_sizes; (void)n_in; (void)out_size; (void)ws_size;
    const float* x    = (const float*)d_in[0];
    const int*   mask = (const int*)d_in[1];
    const float* Wq   = (const float*)d_in[2];
    const float* Wk   = (const float*)d_in[3];
    const float* Wv   = (const float*)d_in[4];
    const float* Wo   = (const float*)d_in[5];
    const float* bo   = (const float*)d_in[6];
    float* out = (float*)d_out;

    char* ws = (char*)d_ws;
    u16* xb    = (u16*)(ws);                 // 8 MB  x as bf16 (alive thru gemm_vt)
    u16* WqT   = (u16*)(ws + (8l  << 20));   // 2 MB each, transposed bf16 (q,k contiguous)
    u16* WkT   = (u16*)(ws + (10l << 20));
    u16* WvT   = (u16*)(ws + (12l << 20));
    u16* WoT   = (u16*)(ws + (14l << 20));
    u16* qws   = (u16*)(ws + (16l << 20));   // 8 MB each (q,k contiguous)
    u16* kws   = (u16*)(ws + (24l << 20));
    u16* vtC   = (u16*)(ws + (32l << 20));   // 8 MB  V^T [1024][4096]
    u16* inner = (u16*)(ws + (40l << 20));   // 8 MB
    u32* mp    = (u32*)(ws + (48l << 20));   // 1 MB packed mask

    conv_x_k<<<2048, 256, 0, stream>>>(x, xb);
    conv_w_k<<<dim3(16, 16, 4), 256, 0, stream>>>(Wq, Wk, Wv, Wo, WqT, WkT, WvT, WoT);
    pack_mask_k<<<1024, 256, 0, stream>>>(mask, mp);
    gemm_qkv<<<dim3(16, 32), 256, 0, stream>>>(xb, WqT, qws);
    gemm_vt<<<dim3(32, 8), 256, 0, stream>>>(WvT, xb, vtC);
    attn_fwd<<<dim3(16, 16, 2), 256, 0, stream>>>(qws, kws, vtC, mp, inner);
    gemm_out<<<dim3(8, 32), 256, 0, stream>>>(inner, WoT, out, bo);
    (void)kws;
}

// Round 7
// 159.468 us; speedup vs baseline: 1.0589x; 1.0589x over previous
//
#include <hip/hip_runtime.h>
#include <cstdint>
#include <cstddef>

typedef float    f32x4  __attribute__((ext_vector_type(4)));
typedef __bf16   bf16x8 __attribute__((ext_vector_type(8)));
typedef unsigned u32x4  __attribute__((ext_vector_type(4)));
typedef unsigned u32x2  __attribute__((ext_vector_type(2)));
typedef unsigned short u16;
typedef unsigned int   u32;

#define SCL2E 0.18033688011112042f   /* 0.125 * log2(e) */
#define NEGC  (-34.624681566719483f) /* -24 * log2(e)   */

static __device__ __forceinline__ u16 f2bf(float f) {
    u32 u = __builtin_bit_cast(u32, f);
    u32 r = (u + 0x7FFFu + ((u >> 16) & 1u)) >> 16;
    return (u16)r;
}

static __device__ __forceinline__ u32 cvtpk_bf16(float lo, float hi) {
    u32 r;
    asm("v_cvt_pk_bf16_f32 %0, %1, %2" : "=v"(r) : "v"(lo), "v"(hi));
    return r;
}

static __device__ __forceinline__ void gll16(const u16* g, void* l) {
    __builtin_amdgcn_global_load_lds((const __attribute__((address_space(1))) void*)g,
                                     (__attribute__((address_space(3))) void*)l, 16, 0, 0);
}

// ---------------- prep kernels ----------------

__global__ void conv_x_k(const float* __restrict__ x, u16* __restrict__ xb) {
    const long i = ((long)blockIdx.x * 256 + threadIdx.x) * 8;
    f32x4 a = *(const f32x4*)(x + i);
    f32x4 c = *(const f32x4*)(x + i + 4);
    u32x4 o;
    o[0] = (u32)f2bf(a[0]) | ((u32)f2bf(a[1]) << 16);
    o[1] = (u32)f2bf(a[2]) | ((u32)f2bf(a[3]) << 16);
    o[2] = (u32)f2bf(c[0]) | ((u32)f2bf(c[1]) << 16);
    o[3] = (u32)f2bf(c[2]) | ((u32)f2bf(c[3]) << 16);
    *(u32x4*)(xb + i) = o;
}

// transpose 1024x1024 f32 -> bf16 [N][K]
__global__ __launch_bounds__(256) void conv_w_k(
    const float* __restrict__ W0, const float* __restrict__ W1,
    const float* __restrict__ W2, const float* __restrict__ W3,
    u16* __restrict__ T0, u16* __restrict__ T1,
    u16* __restrict__ T2, u16* __restrict__ T3)
{
    __shared__ float T[64][65];
    const int z = blockIdx.z;
    const float* W = (z == 0) ? W0 : (z == 1) ? W1 : (z == 2) ? W2 : W3;
    u16* Wt = (z == 0) ? T0 : (z == 1) ? T1 : (z == 2) ? T2 : T3;
    const int k0 = blockIdx.y * 64, n0 = blockIdx.x * 64;
    const int c = threadIdx.x & 63, r0 = (threadIdx.x >> 6) * 16;
#pragma unroll
    for (int i = 0; i < 16; ++i)
        T[r0 + i][c] = W[(long)(k0 + r0 + i) * 1024 + n0 + c];
    __syncthreads();
#pragma unroll
    for (int i = 0; i < 16; ++i)
        Wt[(long)(n0 + r0 + i) * 1024 + k0 + c] = f2bf(T[c][r0 + i]);
}

// pack mask int32 -> bit per element (bit set == masked out); 1 u32 word per thread
__global__ void pack_mask_k(const int* __restrict__ mask, u32* __restrict__ mp) {
    const long wi = (long)blockIdx.x * 256 + threadIdx.x;
    const int* src = mask + wi * 32;
    u32 word = 0;
#pragma unroll
    for (int c = 0; c < 8; ++c) {
        const int4 v = *(const int4*)(src + c * 4);
        word |= (u32)(v.x != 0) << (c * 4);
        word |= (u32)(v.y != 0) << (c * 4 + 1);
        word |= (u32)(v.z != 0) << (c * 4 + 2);
        word |= (u32)(v.w != 0) << (c * 4 + 3);
    }
    mp[wi] = word;
}

// transpose V [b*2048 n][h*64+d] -> vt [(b*16+h)*64 + d][2048 n]  (bf16)
__global__ __launch_bounds__(256) void vt_k(const u16* __restrict__ v, u16* __restrict__ vt) {
    __shared__ u16 T[64][66];
    const int nt = blockIdx.x, h = blockIdx.y, b = blockIdx.z;
    const int c = threadIdx.x & 63, r0 = (threadIdx.x >> 6) * 16;
    const u16* src = v + ((long)b * 2048 + nt * 64) * 1024 + h * 64;
    u16* dst = vt + ((long)(b * 16 + h) * 64) * 2048 + nt * 64;
#pragma unroll
    for (int i = 0; i < 16; ++i)
        T[r0 + i][c] = src[(long)(r0 + i) * 1024 + c];
    __syncthreads();
#pragma unroll
    for (int i = 0; i < 16; ++i)
        dst[(long)(r0 + i) * 2048 + c] = T[c][r0 + i];
}

// ---------------- fused QKV GEMM: [4096x1024] @ [1024x3072] ----------------

__global__ __launch_bounds__(256, 3) void gemm_qkv(
    const u16* __restrict__ A, const u16* __restrict__ Bt, u16* __restrict__ C0)
{
    constexpr int K = 1024;
    __shared__ u16 As[2][128 * 32];
    __shared__ u16 Bs[2][128 * 32];
    const int tid = threadIdx.x;
    const int wave = tid >> 6, lane = tid & 63;
    const int wr = wave >> 1, wc = wave & 1;
    const int g = lane >> 4, lr = lane & 15;
    const long mBase = (long)blockIdx.y * 128;
    const long nBase = (long)blockIdx.x * 128;

    f32x4 acc[4][4];
#pragma unroll
    for (int i = 0; i < 4; ++i)
#pragma unroll
        for (int j = 0; j < 4; ++j) acc[i][j] = f32x4{0.f, 0.f, 0.f, 0.f};

    const int o0 = tid * 16, o1 = (256 + tid) * 16;
    const int r0 = o0 >> 6, cb0 = o0 & 63;
    const int r1 = o1 >> 6, cb1 = o1 & 63;

    gll16(A  + (mBase + r0) * K + (cb0 >> 1), (char*)&As[0][0] + o0);
    gll16(A  + (mBase + r1) * K + (cb1 >> 1), (char*)&As[0][0] + o1);
    gll16(Bt + (nBase + r0) * K + (cb0 >> 1), (char*)&Bs[0][0] + o0);
    gll16(Bt + (nBase + r1) * K + (cb1 >> 1), (char*)&Bs[0][0] + o1);
    __syncthreads();

    for (int kt = 0; kt < 32; ++kt) {
        const int buf = kt & 1;
        if (kt + 1 < 32) {
            const long ko = (long)(kt + 1) * 32;
            gll16(A  + (mBase + r0) * K + ko + (cb0 >> 1), (char*)&As[buf ^ 1][0] + o0);
            gll16(A  + (mBase + r1) * K + ko + (cb1 >> 1), (char*)&As[buf ^ 1][0] + o1);
            gll16(Bt + (nBase + r0) * K + ko + (cb0 >> 1), (char*)&Bs[buf ^ 1][0] + o0);
            gll16(Bt + (nBase + r1) * K + ko + (cb1 >> 1), (char*)&Bs[buf ^ 1][0] + o1);
        }
        bf16x8 af[4], bfv[4];
#pragma unroll
        for (int mi = 0; mi < 4; ++mi)
            af[mi] = *(const bf16x8*)((const char*)&As[buf][0] + (wr * 64 + mi * 16 + lr) * 64 + g * 16);
#pragma unroll
        for (int ni = 0; ni < 4; ++ni)
            bfv[ni] = *(const bf16x8*)((const char*)&Bs[buf][0] + (wc * 64 + ni * 16 + lr) * 64 + g * 16);
#pragma unroll
        for (int mi = 0; mi < 4; ++mi)
#pragma unroll
            for (int ni = 0; ni < 4; ++ni)
                acc[mi][ni] = __builtin_amdgcn_mfma_f32_16x16x32_bf16(af[mi], bfv[ni], acc[mi][ni], 0, 0, 0);
        __syncthreads();
    }

    const int wsel = (int)(nBase >> 10);
    u16* Cw = C0 + (long)wsel * (4096l * 1024);
    const long ncl = nBase & 1023;
#pragma unroll
    for (int mi = 0; mi < 4; ++mi)
#pragma unroll
        for (int r = 0; r < 4; ++r) {
            const long row = mBase + wr * 64 + mi * 16 + g * 4 + r;
#pragma unroll
            for (int ni = 0; ni < 4; ++ni) {
                const long col = ncl + wc * 64 + ni * 16 + lr;
                Cw[row * 1024 + col] = f2bf(acc[mi][ni][r]);
            }
        }
}

// ---------------- output-proj GEMM (f32 out + bias) ----------------

__global__ __launch_bounds__(256, 3) void gemm_out(
    const u16* __restrict__ A, const u16* __restrict__ Bt,
    float* __restrict__ Cf, const float* __restrict__ bias)
{
    constexpr int K = 1024, N = 1024;
    __shared__ u16 As[2][128 * 32];
    __shared__ u16 Bs[2][128 * 32];
    const int tid = threadIdx.x;
    const int wave = tid >> 6, lane = tid & 63;
    const int wr = wave >> 1, wc = wave & 1;
    const int g = lane >> 4, lr = lane & 15;
    const long mBase = (long)blockIdx.y * 128;
    const long nBase = (long)blockIdx.x * 128;

    f32x4 acc[4][4];
#pragma unroll
    for (int i = 0; i < 4; ++i)
#pragma unroll
        for (int j = 0; j < 4; ++j) acc[i][j] = f32x4{0.f, 0.f, 0.f, 0.f};

    const int o0 = tid * 16, o1 = (256 + tid) * 16;
    const int r0 = o0 >> 6, cb0 = o0 & 63;
    const int r1 = o1 >> 6, cb1 = o1 & 63;

    gll16(A  + (mBase + r0) * K + (cb0 >> 1), (char*)&As[0][0] + o0);
    gll16(A  + (mBase + r1) * K + (cb1 >> 1), (char*)&As[0][0] + o1);
    gll16(Bt + (nBase + r0) * K + (cb0 >> 1), (char*)&Bs[0][0] + o0);
    gll16(Bt + (nBase + r1) * K + (cb1 >> 1), (char*)&Bs[0][0] + o1);
    __syncthreads();

    for (int kt = 0; kt < 32; ++kt) {
        const int buf = kt & 1;
        if (kt + 1 < 32) {
            const long ko = (long)(kt + 1) * 32;
            gll16(A  + (mBase + r0) * K + ko + (cb0 >> 1), (char*)&As[buf ^ 1][0] + o0);
            gll16(A  + (mBase + r1) * K + ko + (cb1 >> 1), (char*)&As[buf ^ 1][0] + o1);
            gll16(Bt + (nBase + r0) * K + ko + (cb0 >> 1), (char*)&Bs[buf ^ 1][0] + o0);
            gll16(Bt + (nBase + r1) * K + ko + (cb1 >> 1), (char*)&Bs[buf ^ 1][0] + o1);
        }
        bf16x8 af[4], bfv[4];
#pragma unroll
        for (int mi = 0; mi < 4; ++mi)
            af[mi] = *(const bf16x8*)((const char*)&As[buf][0] + (wr * 64 + mi * 16 + lr) * 64 + g * 16);
#pragma unroll
        for (int ni = 0; ni < 4; ++ni)
            bfv[ni] = *(const bf16x8*)((const char*)&Bs[buf][0] + (wc * 64 + ni * 16 + lr) * 64 + g * 16);
#pragma unroll
        for (int mi = 0; mi < 4; ++mi)
#pragma unroll
            for (int ni = 0; ni < 4; ++ni)
                acc[mi][ni] = __builtin_amdgcn_mfma_f32_16x16x32_bf16(af[mi], bfv[ni], acc[mi][ni], 0, 0, 0);
        __syncthreads();
    }

#pragma unroll
    for (int mi = 0; mi < 4; ++mi)
#pragma unroll
        for (int r = 0; r < 4; ++r) {
            const long row = mBase + wr * 64 + mi * 16 + g * 4 + r;
#pragma unroll
            for (int ni = 0; ni < 4; ++ni) {
                const long col = nBase + wc * 64 + ni * 16 + lr;
                Cf[row * N + col] = acc[mi][ni][r] + bias[col];
            }
        }
}

// ---------------- flash attention (XCD-group swizzle, KVBLK=128) -----------
// grid 512 linear. Block L -> XCD L%8 (HW round-robin). All 16 q-blocks of
// one (b,h) group mapped to ONE XCD so its 1MB K/V panel stays L2-resident:
//   xcd = L&7; slot = L>>3; q-tile = slot&15; group = xcd + 8*(slot>>4).
// Block: 4 waves, 32 q-rows/wave (nq=2). S^T = mfma(K,Q); kappa-permuted K;
// V pre-transposed (vt_k, [(b*16+h)*64+d][2048]). 16 iters x 128 kv,
// one __syncthreads per iter. Fixed-C softmax (C=24 exp-units).

__global__ __launch_bounds__(256, 2) void attn_fwd(
    const u16* __restrict__ Qg_, const u16* __restrict__ Kg_, const u16* __restrict__ Vtg_,
    const u32* __restrict__ maskp, u16* __restrict__ Og_)
{
    __shared__ u16 Ks[2][2][64 * 64];  // [set][half], kappa-permuted + swizzled
    __shared__ u16 Vs[2][2][64 * 64];  // [set][half], rows=d, swizzled

    const int tid = threadIdx.x, w = tid >> 6, lane = tid & 63;
    const int g = lane >> 4, lr = lane & 15;
    const int L = blockIdx.x;
    const int slot = L >> 3;
    const int grp = (L & 7) + 8 * (slot >> 4);   // (b*16+h) group, XCD-pinned
    const int q0 = (slot & 15) * 128;
    const int b = grp >> 4, h = grp & 15;
    const u16* Qg = Qg_ + ((long)b * 2048) * 1024 + h * 64;
    const u16* Kg = Kg_ + ((long)b * 2048) * 1024 + h * 64;
    const u16* Vtg = Vtg_ + ((long)grp * 64) * 2048;
    u16* Og = Og_ + ((long)b * 2048) * 1024 + h * 64;

    // ---- staging address precompute (2 chunks of 16B per thread each) ----
    long ksrc[2], vsrc[2];
    int ldso[2];
#pragma unroll
    for (int c = 0; c < 2; ++c) {
        const int o = (tid + c * 256) * 16;
        const int m = o >> 7, cb = o & 127;
        const int sb = cb ^ ((m & 7) << 4);
        ldso[c] = o;
        const int kap = ((m >> 4) & 1) * 32 + ((m >> 2) & 3) * 8 + ((m >> 5) & 1) * 4 + (m & 3);
        ksrc[c] = (long)kap * 1024 + (sb >> 1);
        vsrc[c] = (long)m * 2048 + (sb >> 1);
    }

    // ---- Q straight to registers (no LDS) ----
    bf16x8 qf[2][2];
#pragma unroll
    for (int nq = 0; nq < 2; ++nq)
#pragma unroll
        for (int ks = 0; ks < 2; ++ks)
            qf[nq][ks] = *(const bf16x8*)(Qg + (long)(q0 + w * 32 + nq * 16 + lr) * 1024 + ks * 32 + g * 8);

    const long mrow0 = (long)b * 2048 + q0 + w * 32 + lr;
    const u32* mpr0 = maskp + mrow0 * 64;
    const u32* mpr1 = maskp + (mrow0 + 16) * 64;

    // ---- prologue: mask(0) -> regs; stage set 0 (both halves) ----
    u32x4 mwC0 = *(const u32x4*)(mpr0);
    u32x4 mwC1 = *(const u32x4*)(mpr1);
#pragma unroll
    for (int hh = 0; hh < 2; ++hh)
#pragma unroll
        for (int c = 0; c < 2; ++c) {
            gll16(Kg + hh * 65536 + ksrc[c], (char*)&Ks[0][hh][0] + ldso[c]);
            gll16(Vtg + hh * 64 + vsrc[c], (char*)&Vs[0][hh][0] + ldso[c]);
        }
    __syncthreads();

    const int swz = (lr & 7) << 4;
    int kb[2];
#pragma unroll
    for (int ks = 0; ks < 2; ++ks) kb[ks] = (ks * 64 + g * 16) ^ swz;

    f32x4 oacc[2][4];
#pragma unroll
    for (int i = 0; i < 2; ++i)
#pragma unroll
        for (int j = 0; j < 4; ++j) oacc[i][j] = f32x4{0.f, 0.f, 0.f, 0.f};
    float sum[2] = {0.f, 0.f};
    const f32x4 z4 = {0.f, 0.f, 0.f, 0.f};

    for (int t = 0; t < 16; ++t) {
        const int cur = t & 1;
        // ---- prefetch mask(t+1) -> regs; stage(t+1) -> other set ----
        u32x4 mwN0, mwN1;
        if (t + 1 < 16) {
            mwN0 = *(const u32x4*)(mpr0 + (t + 1) * 4);
            mwN1 = *(const u32x4*)(mpr1 + (t + 1) * 4);
            const long kv0 = (long)(t + 1) * 128;
#pragma unroll
            for (int hh = 0; hh < 2; ++hh)
#pragma unroll
                for (int c = 0; c < 2; ++c) {
                    gll16(Kg + (kv0 + hh * 64) * 1024 + ksrc[c], (char*)&Ks[cur ^ 1][hh][0] + ldso[c]);
                    gll16(Vtg + kv0 + hh * 64 + vsrc[c], (char*)&Vs[cur ^ 1][hh][0] + ldso[c]);
                }
        }

        // ---- two 64-kv halves, identical proven structure ----
#pragma unroll
        for (int hh = 0; hh < 2; ++hh) {
            const char* kbase = (const char*)&Ks[cur][hh][0];
            const char* vbase = (const char*)&Vs[cur][hh][0];

            // S^T = K . Q^T
            f32x4 s[4][2];
            __builtin_amdgcn_s_setprio(1);
#pragma unroll
            for (int mt = 0; mt < 4; ++mt) {
                const bf16x8 kf0 = *(const bf16x8*)(kbase + (mt * 16 + lr) * 128 + kb[0]);
                const bf16x8 kf1 = *(const bf16x8*)(kbase + (mt * 16 + lr) * 128 + kb[1]);
#pragma unroll
                for (int nq = 0; nq < 2; ++nq) {
                    s[mt][nq] = __builtin_amdgcn_mfma_f32_16x16x32_bf16(kf0, qf[nq][0], z4, 0, 0, 0);
                    s[mt][nq] = __builtin_amdgcn_mfma_f32_16x16x32_bf16(kf1, qf[nq][1], s[mt][nq], 0, 0, 0);
                }
            }
            __builtin_amdgcn_s_setprio(0);

            // fixed-C masked softmax (in-register)
            u32 pk[4][2][2];
#pragma unroll
            for (int ts = 0; ts < 4; ++ts) {
                const int sh = g * 8 + (ts >> 1) * 4;
                const int wi = hh * 2 + (ts & 1);
#pragma unroll
                for (int nq = 0; nq < 2; ++nq) {
                    const u32 word = nq ? mwC1[wi] : mwC0[wi];
                    const u32 wsh = word >> sh;
                    float e[4];
#pragma unroll
                    for (int r = 0; r < 4; ++r) {
                        float sv = fmaf(s[ts][nq][r], SCL2E, NEGC);
                        sv = ((wsh >> r) & 1u) ? -512.f : sv;
                        const float ev = __builtin_exp2f(sv);
                        e[r] = ev;
                        sum[nq] += ev;
                    }
                    pk[ts][nq][0] = cvtpk_bf16(e[0], e[1]);
                    pk[ts][nq][1] = cvtpk_bf16(e[2], e[3]);
                }
            }

            // O += P . V
            bf16x8 pa[2][2];
#pragma unroll
            for (int nq = 0; nq < 2; ++nq)
#pragma unroll
                for (int ks = 0; ks < 2; ++ks) {
                    u32x4 t4;
                    t4[0] = pk[ks][nq][0]; t4[1] = pk[ks][nq][1];
                    t4[2] = pk[ks + 2][nq][0]; t4[3] = pk[ks + 2][nq][1];
                    pa[nq][ks] = __builtin_bit_cast(bf16x8, t4);
                }
            __builtin_amdgcn_s_setprio(1);
#pragma unroll
            for (int dt = 0; dt < 4; ++dt)
#pragma unroll
                for (int ks = 0; ks < 2; ++ks) {
                    const bf16x8 vf = *(const bf16x8*)(vbase + (dt * 16 + lr) * 128 + kb[ks]);
#pragma unroll
                    for (int nq = 0; nq < 2; ++nq)
                        oacc[nq][dt] = __builtin_amdgcn_mfma_f32_16x16x32_bf16(pa[nq][ks], vf, oacc[nq][dt], 0, 0, 0);
                }
            __builtin_amdgcn_s_setprio(0);
        }
        __syncthreads();

        mwC0 = mwN0; mwC1 = mwN1;
    }

    // ---- epilogue: final sum reduce + normalize + store ----
#pragma unroll
    for (int nq = 0; nq < 2; ++nq) {
        sum[nq] += __shfl_xor(sum[nq], 16);
        sum[nq] += __shfl_xor(sum[nq], 32);
    }
#pragma unroll
    for (int nq = 0; nq < 2; ++nq)
#pragma unroll
        for (int rr = 0; rr < 4; ++rr) {
            const float den = __shfl(sum[nq], g * 4 + rr);
            const float inv = __builtin_amdgcn_rcpf(den);
            const long row = (long)q0 + w * 32 + nq * 16 + g * 4 + rr;
#pragma unroll
            for (int dt = 0; dt < 4; ++dt)
                Og[row * 1024 + dt * 16 + lr] = f2bf(oacc[nq][dt][rr] * inv);
        }
}

// ---------------- launcher ----------------

extern "C" void kernel_launch(void* const* d_in, const int* in_sizes, int n_in,
                              void* d_out, int out_size, void* d_ws, size_t ws_size,
                              hipStream_t stream)
{
    (void)in_sizes; (void)n_in; (void)out_size; (void)ws_size;
    const float* x    = (const float*)d_in[0];
    const int*   mask = (const int*)d_in[1];
    const float* Wq   = (const float*)d_in[2];
    const float* Wk   = (const float*)d_in[3];
    const float* Wv   = (const float*)d_in[4];
    const float* Wo   = (const float*)d_in[5];
    const float* bo   = (const float*)d_in[6];
    float* out = (float*)d_out;

    char* ws = (char*)d_ws;
    u16* xb    = (u16*)(ws);                 // 8 MB  x as bf16 (dead after gemm_qkv)
    u16* vtws  = (u16*)(ws);                 // 8 MB  V^T, reuses xb region
    u16* WqT   = (u16*)(ws + (8l  << 20));   // 2 MB each, transposed bf16 (q,k,v contiguous)
    u16* WkT   = (u16*)(ws + (10l << 20));
    u16* WvT   = (u16*)(ws + (12l << 20));
    u16* WoT   = (u16*)(ws + (14l << 20));
    u16* qws   = (u16*)(ws + (16l << 20));   // 8 MB each (q,k,v contiguous)
    u16* kws   = (u16*)(ws + (24l << 20));
    u16* vws   = (u16*)(ws + (32l << 20));
    u16* inner = (u16*)(ws + (40l << 20));   // 8 MB
    u32* mp    = (u32*)(ws + (48l << 20));   // 1 MB packed mask

    conv_x_k<<<2048, 256, 0, stream>>>(x, xb);
    conv_w_k<<<dim3(16, 16, 4), 256, 0, stream>>>(Wq, Wk, Wv, Wo, WqT, WkT, WvT, WoT);
    pack_mask_k<<<1024, 256, 0, stream>>>(mask, mp);
    gemm_qkv<<<dim3(24, 32), 256, 0, stream>>>(xb, WqT, qws);
    vt_k<<<dim3(32, 16, 2), 256, 0, stream>>>(vws, vtws);
    attn_fwd<<<512, 256, 0, stream>>>(qws, kws, vtws, mp, inner);
    gemm_out<<<dim3(8, 32), 256, 0, stream>>>(inner, WoT, out, bo);
}

// Round 8
// 136.165 us; speedup vs baseline: 1.2401x; 1.1711x over previous
//
#include <hip/hip_runtime.h>
#include <cstdint>
#include <cstddef>

typedef float    f32x4  __attribute__((ext_vector_type(4)));
typedef __bf16   bf16x8 __attribute__((ext_vector_type(8)));
typedef unsigned u32x4  __attribute__((ext_vector_type(4)));
typedef unsigned u32x2  __attribute__((ext_vector_type(2)));
typedef unsigned short u16;
typedef unsigned int   u32;

#define SCL2E 0.18033688011112042f   /* 0.125 * log2(e), folded into Wq */

static __device__ __forceinline__ u16 f2bf(float f) {
    u32 u = __builtin_bit_cast(u32, f);
    u32 r = (u + 0x7FFFu + ((u >> 16) & 1u)) >> 16;
    return (u16)r;
}

static __device__ __forceinline__ u32 cvtpk_bf16(float lo, float hi) {
    u32 r;
    asm("v_cvt_pk_bf16_f32 %0, %1, %2" : "=v"(r) : "v"(lo), "v"(hi));
    return r;
}

// raw hardware exp2 — avoids llvm.exp2's denormal-fixup expansion (~6 VALU).
// arg -512 (masked) flushes to 0 under FTZ: exactly the desired P=0.
static __device__ __forceinline__ float fexp2(float x) {
    float r;
    asm("v_exp_f32 %0, %1" : "=v"(r) : "v"(x));
    return r;
}

static __device__ __forceinline__ void gll16(const u16* g, void* l) {
    __builtin_amdgcn_global_load_lds((const __attribute__((address_space(1))) void*)g,
                                     (__attribute__((address_space(3))) void*)l, 16, 0, 0);
}

// ---------------- fused prep kernel ----------------
// blocks 0..2047: x f32->bf16; 2048..3071: W transpose (Wq pre-scaled);
// 3072..4095: mask bit-pack. All independent.

__global__ __launch_bounds__(256) void prep_k(
    const float* __restrict__ x, u16* __restrict__ xb,
    const float* __restrict__ W0, const float* __restrict__ W1,
    const float* __restrict__ W2, const float* __restrict__ W3,
    u16* __restrict__ T0, u16* __restrict__ T1,
    u16* __restrict__ T2, u16* __restrict__ T3,
    const int* __restrict__ mask, u32* __restrict__ mp)
{
    __shared__ float T[64][65];
    const int bid = blockIdx.x;
    if (bid < 2048) {
        // ---- x -> bf16 ----
        const long i = ((long)bid * 256 + threadIdx.x) * 8;
        f32x4 a = *(const f32x4*)(x + i);
        f32x4 c = *(const f32x4*)(x + i + 4);
        u32x4 o;
        o[0] = (u32)f2bf(a[0]) | ((u32)f2bf(a[1]) << 16);
        o[1] = (u32)f2bf(a[2]) | ((u32)f2bf(a[3]) << 16);
        o[2] = (u32)f2bf(c[0]) | ((u32)f2bf(c[1]) << 16);
        o[3] = (u32)f2bf(c[2]) | ((u32)f2bf(c[3]) << 16);
        *(u32x4*)(xb + i) = o;
    } else if (bid < 3072) {
        // ---- W transpose f32 -> bf16 [N][K]; Wq scaled by SCL2E ----
        const int idx = bid - 2048;
        const int z = idx >> 8, rem = idx & 255;
        const int n0 = (rem & 15) * 64, k0 = (rem >> 4) * 64;
        const float* W = (z == 0) ? W0 : (z == 1) ? W1 : (z == 2) ? W2 : W3;
        u16* Wt = (z == 0) ? T0 : (z == 1) ? T1 : (z == 2) ? T2 : T3;
        const float scl = (z == 0) ? SCL2E : 1.0f;
        const int c = threadIdx.x & 63, r0 = (threadIdx.x >> 6) * 16;
#pragma unroll
        for (int i = 0; i < 16; ++i)
            T[r0 + i][c] = W[(long)(k0 + r0 + i) * 1024 + n0 + c];
        __syncthreads();
#pragma unroll
        for (int i = 0; i < 16; ++i)
            Wt[(long)(n0 + r0 + i) * 1024 + k0 + c] = f2bf(T[c][r0 + i] * scl);
    } else {
        // ---- mask int32 -> bit pack (bit set == masked out) ----
        const long wi = (long)(bid - 3072) * 256 + threadIdx.x;
        const int* src = mask + wi * 32;
        u32 word = 0;
#pragma unroll
        for (int c = 0; c < 8; ++c) {
            const int4 v = *(const int4*)(src + c * 4);
            word |= (u32)(v.x != 0) << (c * 4);
            word |= (u32)(v.y != 0) << (c * 4 + 1);
            word |= (u32)(v.z != 0) << (c * 4 + 2);
            word |= (u32)(v.w != 0) << (c * 4 + 3);
        }
        mp[wi] = word;
    }
}

// transpose V [b*2048 n][h*64+d] -> vt [(b*16+h)*64 + d][2048 n]  (bf16)
__global__ __launch_bounds__(256) void vt_k(const u16* __restrict__ v, u16* __restrict__ vt) {
    __shared__ u16 T[64][66];
    const int nt = blockIdx.x, h = blockIdx.y, b = blockIdx.z;
    const int c = threadIdx.x & 63, r0 = (threadIdx.x >> 6) * 16;
    const u16* src = v + ((long)b * 2048 + nt * 64) * 1024 + h * 64;
    u16* dst = vt + ((long)(b * 16 + h) * 64) * 2048 + nt * 64;
#pragma unroll
    for (int i = 0; i < 16; ++i)
        T[r0 + i][c] = src[(long)(r0 + i) * 1024 + c];
    __syncthreads();
#pragma unroll
    for (int i = 0; i < 16; ++i)
        dst[(long)(r0 + i) * 2048 + c] = T[c][r0 + i];
}

// ---------------- fused QKV GEMM: [4096x1024] @ [1024x3072] ----------------

__global__ __launch_bounds__(256, 3) void gemm_qkv(
    const u16* __restrict__ A, const u16* __restrict__ Bt, u16* __restrict__ C0)
{
    constexpr int K = 1024;
    __shared__ u16 As[2][128 * 32];
    __shared__ u16 Bs[2][128 * 32];
    const int tid = threadIdx.x;
    const int wave = tid >> 6, lane = tid & 63;
    const int wr = wave >> 1, wc = wave & 1;
    const int g = lane >> 4, lr = lane & 15;
    const long mBase = (long)blockIdx.y * 128;
    const long nBase = (long)blockIdx.x * 128;

    f32x4 acc[4][4];
#pragma unroll
    for (int i = 0; i < 4; ++i)
#pragma unroll
        for (int j = 0; j < 4; ++j) acc[i][j] = f32x4{0.f, 0.f, 0.f, 0.f};

    const int o0 = tid * 16, o1 = (256 + tid) * 16;
    const int r0 = o0 >> 6, cb0 = o0 & 63;
    const int r1 = o1 >> 6, cb1 = o1 & 63;

    gll16(A  + (mBase + r0) * K + (cb0 >> 1), (char*)&As[0][0] + o0);
    gll16(A  + (mBase + r1) * K + (cb1 >> 1), (char*)&As[0][0] + o1);
    gll16(Bt + (nBase + r0) * K + (cb0 >> 1), (char*)&Bs[0][0] + o0);
    gll16(Bt + (nBase + r1) * K + (cb1 >> 1), (char*)&Bs[0][0] + o1);
    __syncthreads();

    for (int kt = 0; kt < 32; ++kt) {
        const int buf = kt & 1;
        if (kt + 1 < 32) {
            const long ko = (long)(kt + 1) * 32;
            gll16(A  + (mBase + r0) * K + ko + (cb0 >> 1), (char*)&As[buf ^ 1][0] + o0);
            gll16(A  + (mBase + r1) * K + ko + (cb1 >> 1), (char*)&As[buf ^ 1][0] + o1);
            gll16(Bt + (nBase + r0) * K + ko + (cb0 >> 1), (char*)&Bs[buf ^ 1][0] + o0);
            gll16(Bt + (nBase + r1) * K + ko + (cb1 >> 1), (char*)&Bs[buf ^ 1][0] + o1);
        }
        bf16x8 af[4], bfv[4];
#pragma unroll
        for (int mi = 0; mi < 4; ++mi)
            af[mi] = *(const bf16x8*)((const char*)&As[buf][0] + (wr * 64 + mi * 16 + lr) * 64 + g * 16);
#pragma unroll
        for (int ni = 0; ni < 4; ++ni)
            bfv[ni] = *(const bf16x8*)((const char*)&Bs[buf][0] + (wc * 64 + ni * 16 + lr) * 64 + g * 16);
#pragma unroll
        for (int mi = 0; mi < 4; ++mi)
#pragma unroll
            for (int ni = 0; ni < 4; ++ni)
                acc[mi][ni] = __builtin_amdgcn_mfma_f32_16x16x32_bf16(af[mi], bfv[ni], acc[mi][ni], 0, 0, 0);
        __syncthreads();
    }

    const int wsel = (int)(nBase >> 10);
    u16* Cw = C0 + (long)wsel * (4096l * 1024);
    const long ncl = nBase & 1023;
#pragma unroll
    for (int mi = 0; mi < 4; ++mi)
#pragma unroll
        for (int r = 0; r < 4; ++r) {
            const long row = mBase + wr * 64 + mi * 16 + g * 4 + r;
#pragma unroll
            for (int ni = 0; ni < 4; ++ni) {
                const long col = ncl + wc * 64 + ni * 16 + lr;
                Cw[row * 1024 + col] = f2bf(acc[mi][ni][r]);
            }
        }
}

// ---------------- output-proj GEMM (f32 out + bias) ----------------

__global__ __launch_bounds__(256, 3) void gemm_out(
    const u16* __restrict__ A, const u16* __restrict__ Bt,
    float* __restrict__ Cf, const float* __restrict__ bias)
{
    constexpr int K = 1024, N = 1024;
    __shared__ u16 As[2][128 * 32];
    __shared__ u16 Bs[2][128 * 32];
    const int tid = threadIdx.x;
    const int wave = tid >> 6, lane = tid & 63;
    const int wr = wave >> 1, wc = wave & 1;
    const int g = lane >> 4, lr = lane & 15;
    const long mBase = (long)blockIdx.y * 128;
    const long nBase = (long)blockIdx.x * 128;

    f32x4 acc[4][4];
#pragma unroll
    for (int i = 0; i < 4; ++i)
#pragma unroll
        for (int j = 0; j < 4; ++j) acc[i][j] = f32x4{0.f, 0.f, 0.f, 0.f};

    const int o0 = tid * 16, o1 = (256 + tid) * 16;
    const int r0 = o0 >> 6, cb0 = o0 & 63;
    const int r1 = o1 >> 6, cb1 = o1 & 63;

    gll16(A  + (mBase + r0) * K + (cb0 >> 1), (char*)&As[0][0] + o0);
    gll16(A  + (mBase + r1) * K + (cb1 >> 1), (char*)&As[0][0] + o1);
    gll16(Bt + (nBase + r0) * K + (cb0 >> 1), (char*)&Bs[0][0] + o0);
    gll16(Bt + (nBase + r1) * K + (cb1 >> 1), (char*)&Bs[0][0] + o1);
    __syncthreads();

    for (int kt = 0; kt < 32; ++kt) {
        const int buf = kt & 1;
        if (kt + 1 < 32) {
            const long ko = (long)(kt + 1) * 32;
            gll16(A  + (mBase + r0) * K + ko + (cb0 >> 1), (char*)&As[buf ^ 1][0] + o0);
            gll16(A  + (mBase + r1) * K + ko + (cb1 >> 1), (char*)&As[buf ^ 1][0] + o1);
            gll16(Bt + (nBase + r0) * K + ko + (cb0 >> 1), (char*)&Bs[buf ^ 1][0] + o0);
            gll16(Bt + (nBase + r1) * K + ko + (cb1 >> 1), (char*)&Bs[buf ^ 1][0] + o1);
        }
        bf16x8 af[4], bfv[4];
#pragma unroll
        for (int mi = 0; mi < 4; ++mi)
            af[mi] = *(const bf16x8*)((const char*)&As[buf][0] + (wr * 64 + mi * 16 + lr) * 64 + g * 16);
#pragma unroll
        for (int ni = 0; ni < 4; ++ni)
            bfv[ni] = *(const bf16x8*)((const char*)&Bs[buf][0] + (wc * 64 + ni * 16 + lr) * 64 + g * 16);
#pragma unroll
        for (int mi = 0; mi < 4; ++mi)
#pragma unroll
            for (int ni = 0; ni < 4; ++ni)
                acc[mi][ni] = __builtin_amdgcn_mfma_f32_16x16x32_bf16(af[mi], bfv[ni], acc[mi][ni], 0, 0, 0);
        __syncthreads();
    }

#pragma unroll
    for (int mi = 0; mi < 4; ++mi)
#pragma unroll
        for (int r = 0; r < 4; ++r) {
            const long row = mBase + wr * 64 + mi * 16 + g * 4 + r;
#pragma unroll
            for (int ni = 0; ni < 4; ++ni) {
                const long col = nBase + wc * 64 + ni * 16 + lr;
                Cf[row * N + col] = acc[mi][ni][r] + bias[col];
            }
        }
}

// ---------------- flash attention (lean-VALU softmax) -----------------------
// grid 512 linear, XCD-group swizzle (16 q-blocks of one (b,h) pinned to one
// XCD -> K/V panel L2-resident; r7-verified FETCH 70->16.5MB).
// 4 waves, 32 q-rows/wave. S^T = mfma(K,Q); kappa-permuted K; V pre-transposed.
// Softmax: Q pre-scaled by 0.125*log2e (prep_k), raw v_exp_f32, no offset
// (constant cancels in normalization), row-sum via ones-MFMA (osum).
// KVBLK=128 (2 halves per sync). Fixed mask bit set == masked -> arg -512 -> P=0.

__global__ __launch_bounds__(256, 2) void attn_fwd(
    const u16* __restrict__ Qg_, const u16* __restrict__ Kg_, const u16* __restrict__ Vtg_,
    const u32* __restrict__ maskp, u16* __restrict__ Og_)
{
    __shared__ u16 Ks[2][2][64 * 64];  // [set][half], kappa-permuted + swizzled
    __shared__ u16 Vs[2][2][64 * 64];  // [set][half], rows=d, swizzled

    const int tid = threadIdx.x, w = tid >> 6, lane = tid & 63;
    const int g = lane >> 4, lr = lane & 15;
    const int L = blockIdx.x;
    const int slot = L >> 3;
    const int grp = (L & 7) + 8 * (slot >> 4);   // (b*16+h) group, XCD-pinned
    const int q0 = (slot & 15) * 128;
    const int b = grp >> 4, h = grp & 15;
    const u16* Qg = Qg_ + ((long)b * 2048) * 1024 + h * 64;
    const u16* Kg = Kg_ + ((long)b * 2048) * 1024 + h * 64;
    const u16* Vtg = Vtg_ + ((long)grp * 64) * 2048;
    u16* Og = Og_ + ((long)b * 2048) * 1024 + h * 64;

    // ---- staging address precompute (2 chunks of 16B per thread each) ----
    long ksrc[2], vsrc[2];
    int ldso[2];
#pragma unroll
    for (int c = 0; c < 2; ++c) {
        const int o = (tid + c * 256) * 16;
        const int m = o >> 7, cb = o & 127;
        const int sb = cb ^ ((m & 7) << 4);
        ldso[c] = o;
        const int kap = ((m >> 4) & 1) * 32 + ((m >> 2) & 3) * 8 + ((m >> 5) & 1) * 4 + (m & 3);
        ksrc[c] = (long)kap * 1024 + (sb >> 1);
        vsrc[c] = (long)m * 2048 + (sb >> 1);
    }

    // ---- Q straight to registers (no LDS) ----
    bf16x8 qf[2][2];
#pragma unroll
    for (int nq = 0; nq < 2; ++nq)
#pragma unroll
        for (int ks = 0; ks < 2; ++ks)
            qf[nq][ks] = *(const bf16x8*)(Qg + (long)(q0 + w * 32 + nq * 16 + lr) * 1024 + ks * 32 + g * 8);

    const long mrow0 = (long)b * 2048 + q0 + w * 32 + lr;
    const u32* mpr0 = maskp + mrow0 * 64;
    const u32* mpr1 = maskp + (mrow0 + 16) * 64;

    // ---- prologue: mask(0) -> regs; stage set 0 (both halves) ----
    u32x4 mwC0 = *(const u32x4*)(mpr0);
    u32x4 mwC1 = *(const u32x4*)(mpr1);
#pragma unroll
    for (int hh = 0; hh < 2; ++hh)
#pragma unroll
        for (int c = 0; c < 2; ++c) {
            gll16(Kg + hh * 65536 + ksrc[c], (char*)&Ks[0][hh][0] + ldso[c]);
            gll16(Vtg + hh * 64 + vsrc[c], (char*)&Vs[0][hh][0] + ldso[c]);
        }
    __syncthreads();

    const int swz = (lr & 7) << 4;
    int kb[2];
#pragma unroll
    for (int ks = 0; ks < 2; ++ks) kb[ks] = (ks * 64 + g * 16) ^ swz;

    f32x4 oacc[2][4];
#pragma unroll
    for (int i = 0; i < 2; ++i)
#pragma unroll
        for (int j = 0; j < 4; ++j) oacc[i][j] = f32x4{0.f, 0.f, 0.f, 0.f};
    f32x4 osum[2];
    osum[0] = f32x4{0.f, 0.f, 0.f, 0.f};
    osum[1] = f32x4{0.f, 0.f, 0.f, 0.f};
    const f32x4 z4 = {0.f, 0.f, 0.f, 0.f};
    const u32x4 ones4 = {0x3F803F80u, 0x3F803F80u, 0x3F803F80u, 0x3F803F80u};
    const bf16x8 ones8 = __builtin_bit_cast(bf16x8, ones4);

    for (int t = 0; t < 16; ++t) {
        const int cur = t & 1;
        // ---- prefetch mask(t+1) -> regs; stage(t+1) -> other set ----
        u32x4 mwN0, mwN1;
        if (t + 1 < 16) {
            mwN0 = *(const u32x4*)(mpr0 + (t + 1) * 4);
            mwN1 = *(const u32x4*)(mpr1 + (t + 1) * 4);
            const long kv0 = (long)(t + 1) * 128;
#pragma unroll
            for (int hh = 0; hh < 2; ++hh)
#pragma unroll
                for (int c = 0; c < 2; ++c) {
                    gll16(Kg + (kv0 + hh * 64) * 1024 + ksrc[c], (char*)&Ks[cur ^ 1][hh][0] + ldso[c]);
                    gll16(Vtg + kv0 + hh * 64 + vsrc[c], (char*)&Vs[cur ^ 1][hh][0] + ldso[c]);
                }
        }

        // ---- two 64-kv halves ----
#pragma unroll
        for (int hh = 0; hh < 2; ++hh) {
            const char* kbase = (const char*)&Ks[cur][hh][0];
            const char* vbase = (const char*)&Vs[cur][hh][0];

            // S^T = K . Q^T (Q pre-scaled)
            f32x4 s[4][2];
            __builtin_amdgcn_s_setprio(1);
#pragma unroll
            for (int mt = 0; mt < 4; ++mt) {
                const bf16x8 kf0 = *(const bf16x8*)(kbase + (mt * 16 + lr) * 128 + kb[0]);
                const bf16x8 kf1 = *(const bf16x8*)(kbase + (mt * 16 + lr) * 128 + kb[1]);
#pragma unroll
                for (int nq = 0; nq < 2; ++nq) {
                    s[mt][nq] = __builtin_amdgcn_mfma_f32_16x16x32_bf16(kf0, qf[nq][0], z4, 0, 0, 0);
                    s[mt][nq] = __builtin_amdgcn_mfma_f32_16x16x32_bf16(kf1, qf[nq][1], s[mt][nq], 0, 0, 0);
                }
            }
            __builtin_amdgcn_s_setprio(0);

            // masked softmax: P = exp2(s) (no offset; 2^C cancels), masked -> 0
            u32 pk[4][2][2];
#pragma unroll
            for (int ts = 0; ts < 4; ++ts) {
                const int sh = g * 8 + (ts >> 1) * 4;
                const int wi = hh * 2 + (ts & 1);
#pragma unroll
                for (int nq = 0; nq < 2; ++nq) {
                    const u32 word = nq ? mwC1[wi] : mwC0[wi];
                    const u32 wsh = word >> sh;
                    float e[4];
#pragma unroll
                    for (int r = 0; r < 4; ++r) {
                        const float sv = ((wsh >> r) & 1u) ? -512.f : s[ts][nq][r];
                        e[r] = fexp2(sv);
                    }
                    pk[ts][nq][0] = cvtpk_bf16(e[0], e[1]);
                    pk[ts][nq][1] = cvtpk_bf16(e[2], e[3]);
                }
            }

            // O += P.V ; row-sum via ones-MFMA
            bf16x8 pa[2][2];
#pragma unroll
            for (int nq = 0; nq < 2; ++nq)
#pragma unroll
                for (int ks = 0; ks < 2; ++ks) {
                    u32x4 t4;
                    t4[0] = pk[ks][nq][0]; t4[1] = pk[ks][nq][1];
                    t4[2] = pk[ks + 2][nq][0]; t4[3] = pk[ks + 2][nq][1];
                    pa[nq][ks] = __builtin_bit_cast(bf16x8, t4);
                }
            __builtin_amdgcn_s_setprio(1);
#pragma unroll
            for (int nq = 0; nq < 2; ++nq)
#pragma unroll
                for (int ks = 0; ks < 2; ++ks)
                    osum[nq] = __builtin_amdgcn_mfma_f32_16x16x32_bf16(pa[nq][ks], ones8, osum[nq], 0, 0, 0);
#pragma unroll
            for (int dt = 0; dt < 4; ++dt)
#pragma unroll
                for (int ks = 0; ks < 2; ++ks) {
                    const bf16x8 vf = *(const bf16x8*)(vbase + (dt * 16 + lr) * 128 + kb[ks]);
#pragma unroll
                    for (int nq = 0; nq < 2; ++nq)
                        oacc[nq][dt] = __builtin_amdgcn_mfma_f32_16x16x32_bf16(pa[nq][ks], vf, oacc[nq][dt], 0, 0, 0);
                }
            __builtin_amdgcn_s_setprio(0);
        }
        __syncthreads();

        mwC0 = mwN0; mwC1 = mwN1;
    }

    // ---- epilogue: osum already holds per-row denominators in-lane ----
#pragma unroll
    for (int nq = 0; nq < 2; ++nq)
#pragma unroll
        for (int rr = 0; rr < 4; ++rr) {
            const float inv = __builtin_amdgcn_rcpf(osum[nq][rr]);
            const long row = (long)q0 + w * 32 + nq * 16 + g * 4 + rr;
#pragma unroll
            for (int dt = 0; dt < 4; ++dt)
                Og[row * 1024 + dt * 16 + lr] = f2bf(oacc[nq][dt][rr] * inv);
        }
}

// ---------------- launcher ----------------

extern "C" void kernel_launch(void* const* d_in, const int* in_sizes, int n_in,
                              void* d_out, int out_size, void* d_ws, size_t ws_size,
                              hipStream_t stream)
{
    (void)in_sizes; (void)n_in; (void)out_size; (void)ws_size;
    const float* x    = (const float*)d_in[0];
    const int*   mask = (const int*)d_in[1];
    const float* Wq   = (const float*)d_in[2];
    const float* Wk   = (const float*)d_in[3];
    const float* Wv   = (const float*)d_in[4];
    const float* Wo   = (const float*)d_in[5];
    const float* bo   = (const float*)d_in[6];
    float* out = (float*)d_out;

    char* ws = (char*)d_ws;
    u16* xb    = (u16*)(ws);                 // 8 MB  x as bf16 (dead after gemm_qkv)
    u16* vtws  = (u16*)(ws);                 // 8 MB  V^T, reuses xb region
    u16* WqT   = (u16*)(ws + (8l  << 20));   // 2 MB each, transposed bf16 (q,k,v contiguous)
    u16* WkT   = (u16*)(ws + (10l << 20));
    u16* WvT   = (u16*)(ws + (12l << 20));
    u16* WoT   = (u16*)(ws + (14l << 20));
    u16* qws   = (u16*)(ws + (16l << 20));   // 8 MB each (q,k,v contiguous)
    u16* kws   = (u16*)(ws + (24l << 20));
    u16* vws   = (u16*)(ws + (32l << 20));
    u16* inner = (u16*)(ws + (40l << 20));   // 8 MB
    u32* mp    = (u32*)(ws + (48l << 20));   // 1 MB packed mask

    prep_k<<<4096, 256, 0, stream>>>(x, xb, Wq, Wk, Wv, Wo, WqT, WkT, WvT, WoT, mask, mp);
    gemm_qkv<<<dim3(24, 32), 256, 0, stream>>>(xb, WqT, qws);
    vt_k<<<dim3(32, 16, 2), 256, 0, stream>>>(vws, vtws);
    attn_fwd<<<512, 256, 0, stream>>>(qws, kws, vtws, mp, inner);
    gemm_out<<<dim3(8, 32), 256, 0, stream>>>(inner, WoT, out, bo);
}

// Round 9
// 135.466 us; speedup vs baseline: 1.2465x; 1.0052x over previous
//
#include <hip/hip_runtime.h>
#include <cstdint>
#include <cstddef>

typedef float    f32x4  __attribute__((ext_vector_type(4)));
typedef __bf16   bf16x8 __attribute__((ext_vector_type(8)));
typedef unsigned u32x4  __attribute__((ext_vector_type(4)));
typedef unsigned u32x2  __attribute__((ext_vector_type(2)));
typedef unsigned short u16;
typedef unsigned int   u32;

#define SCL2E 0.18033688011112042f   /* 0.125 * log2(e), folded into Wq */

static __device__ __forceinline__ u16 f2bf(float f) {
    u32 u = __builtin_bit_cast(u32, f);
    u32 r = (u + 0x7FFFu + ((u >> 16) & 1u)) >> 16;
    return (u16)r;
}

static __device__ __forceinline__ u32 cvtpk_bf16(float lo, float hi) {
    u32 r;
    asm("v_cvt_pk_bf16_f32 %0, %1, %2" : "=v"(r) : "v"(lo), "v"(hi));
    return r;
}

// raw hardware exp2 — avoids llvm.exp2's denormal-fixup expansion (~6 VALU).
// arg -512 (masked) flushes to 0 under FTZ: exactly the desired P=0.
static __device__ __forceinline__ float fexp2(float x) {
    float r;
    asm("v_exp_f32 %0, %1" : "=v"(r) : "v"(x));
    return r;
}

static __device__ __forceinline__ void gll16(const u16* g, void* l) {
    __builtin_amdgcn_global_load_lds((const __attribute__((address_space(1))) void*)g,
                                     (__attribute__((address_space(3))) void*)l, 16, 0, 0);
}

// ---------------- fused prep kernel ----------------
// blocks 0..2047: x f32->bf16; 2048..3071: W transpose (Wq pre-scaled);
// 3072..4095: mask bit-pack. All independent.

__global__ __launch_bounds__(256) void prep_k(
    const float* __restrict__ x, u16* __restrict__ xb,
    const float* __restrict__ W0, const float* __restrict__ W1,
    const float* __restrict__ W2, const float* __restrict__ W3,
    u16* __restrict__ T0, u16* __restrict__ T1,
    u16* __restrict__ T2, u16* __restrict__ T3,
    const int* __restrict__ mask, u32* __restrict__ mp)
{
    __shared__ float T[64][65];
    const int bid = blockIdx.x;
    if (bid < 2048) {
        // ---- x -> bf16 ----
        const long i = ((long)bid * 256 + threadIdx.x) * 8;
        f32x4 a = *(const f32x4*)(x + i);
        f32x4 c = *(const f32x4*)(x + i + 4);
        u32x4 o;
        o[0] = (u32)f2bf(a[0]) | ((u32)f2bf(a[1]) << 16);
        o[1] = (u32)f2bf(a[2]) | ((u32)f2bf(a[3]) << 16);
        o[2] = (u32)f2bf(c[0]) | ((u32)f2bf(c[1]) << 16);
        o[3] = (u32)f2bf(c[2]) | ((u32)f2bf(c[3]) << 16);
        *(u32x4*)(xb + i) = o;
    } else if (bid < 3072) {
        // ---- W transpose f32 -> bf16 [N][K]; Wq scaled by SCL2E ----
        const int idx = bid - 2048;
        const int z = idx >> 8, rem = idx & 255;
        const int n0 = (rem & 15) * 64, k0 = (rem >> 4) * 64;
        const float* W = (z == 0) ? W0 : (z == 1) ? W1 : (z == 2) ? W2 : W3;
        u16* Wt = (z == 0) ? T0 : (z == 1) ? T1 : (z == 2) ? T2 : T3;
        const float scl = (z == 0) ? SCL2E : 1.0f;
        const int c = threadIdx.x & 63, r0 = (threadIdx.x >> 6) * 16;
#pragma unroll
        for (int i = 0; i < 16; ++i)
            T[r0 + i][c] = W[(long)(k0 + r0 + i) * 1024 + n0 + c];
        __syncthreads();
#pragma unroll
        for (int i = 0; i < 16; ++i)
            Wt[(long)(n0 + r0 + i) * 1024 + k0 + c] = f2bf(T[c][r0 + i] * scl);
    } else {
        // ---- mask int32 -> bit pack (bit set == masked out) ----
        const long wi = (long)(bid - 3072) * 256 + threadIdx.x;
        const int* src = mask + wi * 32;
        u32 word = 0;
#pragma unroll
        for (int c = 0; c < 8; ++c) {
            const int4 v = *(const int4*)(src + c * 4);
            word |= (u32)(v.x != 0) << (c * 4);
            word |= (u32)(v.y != 0) << (c * 4 + 1);
            word |= (u32)(v.z != 0) << (c * 4 + 2);
            word |= (u32)(v.w != 0) << (c * 4 + 3);
        }
        mp[wi] = word;
    }
}

// transpose V [b*2048 n][h*64+d] -> vt [(b*16+h)*64 + d][2048 n]  (bf16)
__global__ __launch_bounds__(256) void vt_k(const u16* __restrict__ v, u16* __restrict__ vt) {
    __shared__ u16 T[64][66];
    const int nt = blockIdx.x, h = blockIdx.y, b = blockIdx.z;
    const int c = threadIdx.x & 63, r0 = (threadIdx.x >> 6) * 16;
    const u16* src = v + ((long)b * 2048 + nt * 64) * 1024 + h * 64;
    u16* dst = vt + ((long)(b * 16 + h) * 64) * 2048 + nt * 64;
#pragma unroll
    for (int i = 0; i < 16; ++i)
        T[r0 + i][c] = src[(long)(r0 + i) * 1024 + c];
    __syncthreads();
#pragma unroll
    for (int i = 0; i < 16; ++i)
        dst[(long)(r0 + i) * 2048 + c] = T[c][r0 + i];
}

// ---------------- fused QKV GEMM: [4096x1024] @ [1024x3072] ----------------

__global__ __launch_bounds__(256, 3) void gemm_qkv(
    const u16* __restrict__ A, const u16* __restrict__ Bt, u16* __restrict__ C0)
{
    constexpr int K = 1024;
    __shared__ u16 As[2][128 * 32];
    __shared__ u16 Bs[2][128 * 32];
    const int tid = threadIdx.x;
    const int wave = tid >> 6, lane = tid & 63;
    const int wr = wave >> 1, wc = wave & 1;
    const int g = lane >> 4, lr = lane & 15;
    const long mBase = (long)blockIdx.y * 128;
    const long nBase = (long)blockIdx.x * 128;

    f32x4 acc[4][4];
#pragma unroll
    for (int i = 0; i < 4; ++i)
#pragma unroll
        for (int j = 0; j < 4; ++j) acc[i][j] = f32x4{0.f, 0.f, 0.f, 0.f};

    const int o0 = tid * 16, o1 = (256 + tid) * 16;
    const int r0 = o0 >> 6, cb0 = o0 & 63;
    const int r1 = o1 >> 6, cb1 = o1 & 63;

    gll16(A  + (mBase + r0) * K + (cb0 >> 1), (char*)&As[0][0] + o0);
    gll16(A  + (mBase + r1) * K + (cb1 >> 1), (char*)&As[0][0] + o1);
    gll16(Bt + (nBase + r0) * K + (cb0 >> 1), (char*)&Bs[0][0] + o0);
    gll16(Bt + (nBase + r1) * K + (cb1 >> 1), (char*)&Bs[0][0] + o1);
    __syncthreads();

#pragma unroll 2
    for (int kt = 0; kt < 32; ++kt) {
        const int buf = kt & 1;
        if (kt + 1 < 32) {
            const long ko = (long)(kt + 1) * 32;
            gll16(A  + (mBase + r0) * K + ko + (cb0 >> 1), (char*)&As[buf ^ 1][0] + o0);
            gll16(A  + (mBase + r1) * K + ko + (cb1 >> 1), (char*)&As[buf ^ 1][0] + o1);
            gll16(Bt + (nBase + r0) * K + ko + (cb0 >> 1), (char*)&Bs[buf ^ 1][0] + o0);
            gll16(Bt + (nBase + r1) * K + ko + (cb1 >> 1), (char*)&Bs[buf ^ 1][0] + o1);
        }
        bf16x8 af[4], bfv[4];
#pragma unroll
        for (int mi = 0; mi < 4; ++mi)
            af[mi] = *(const bf16x8*)((const char*)&As[buf][0] + (wr * 64 + mi * 16 + lr) * 64 + g * 16);
#pragma unroll
        for (int ni = 0; ni < 4; ++ni)
            bfv[ni] = *(const bf16x8*)((const char*)&Bs[buf][0] + (wc * 64 + ni * 16 + lr) * 64 + g * 16);
#pragma unroll
        for (int mi = 0; mi < 4; ++mi)
#pragma unroll
            for (int ni = 0; ni < 4; ++ni)
                acc[mi][ni] = __builtin_amdgcn_mfma_f32_16x16x32_bf16(af[mi], bfv[ni], acc[mi][ni], 0, 0, 0);
        __syncthreads();
    }

    const int wsel = (int)(nBase >> 10);
    u16* Cw = C0 + (long)wsel * (4096l * 1024);
    const long ncl = nBase & 1023;
#pragma unroll
    for (int mi = 0; mi < 4; ++mi)
#pragma unroll
        for (int r = 0; r < 4; ++r) {
            const long row = mBase + wr * 64 + mi * 16 + g * 4 + r;
#pragma unroll
            for (int ni = 0; ni < 4; ++ni) {
                const long col = ncl + wc * 64 + ni * 16 + lr;
                Cw[row * 1024 + col] = f2bf(acc[mi][ni][r]);
            }
        }
}

// ---------------- output-proj GEMM, BM=64 (2 blocks/CU) --------------------
// C[4096][1024] f32 = inner @ WoT^T + bias. grid (8, 64).

__global__ __launch_bounds__(256, 2) void gemm_out(
    const u16* __restrict__ A, const u16* __restrict__ Bt,
    float* __restrict__ Cf, const float* __restrict__ bias)
{
    constexpr int K = 1024, N = 1024;
    __shared__ u16 As[2][64 * 32];    // 4KB per buf
    __shared__ u16 Bs[2][128 * 32];   // 8KB per buf
    const int tid = threadIdx.x;
    const int wave = tid >> 6, lane = tid & 63;
    const int wr = wave >> 1, wc = wave & 1;   // wave: 32 rows x 64 cols
    const int g = lane >> 4, lr = lane & 15;
    const long mBase = (long)blockIdx.y * 64;
    const long nBase = (long)blockIdx.x * 128;

    f32x4 acc[2][4];
#pragma unroll
    for (int i = 0; i < 2; ++i)
#pragma unroll
        for (int j = 0; j < 4; ++j) acc[i][j] = f32x4{0.f, 0.f, 0.f, 0.f};

    const int oA = tid * 16;                 // A tile: exactly 1 chunk/thread
    const int rA = oA >> 6, cbA = oA & 63;
    const int o0 = tid * 16, o1 = (256 + tid) * 16;   // B tile: 2 chunks
    const int r0 = o0 >> 6, cb0 = o0 & 63;
    const int r1 = o1 >> 6, cb1 = o1 & 63;

    gll16(A  + (mBase + rA) * K + (cbA >> 1), (char*)&As[0][0] + oA);
    gll16(Bt + (nBase + r0) * K + (cb0 >> 1), (char*)&Bs[0][0] + o0);
    gll16(Bt + (nBase + r1) * K + (cb1 >> 1), (char*)&Bs[0][0] + o1);
    __syncthreads();

#pragma unroll 2
    for (int kt = 0; kt < 32; ++kt) {
        const int buf = kt & 1;
        if (kt + 1 < 32) {
            const long ko = (long)(kt + 1) * 32;
            gll16(A  + (mBase + rA) * K + ko + (cbA >> 1), (char*)&As[buf ^ 1][0] + oA);
            gll16(Bt + (nBase + r0) * K + ko + (cb0 >> 1), (char*)&Bs[buf ^ 1][0] + o0);
            gll16(Bt + (nBase + r1) * K + ko + (cb1 >> 1), (char*)&Bs[buf ^ 1][0] + o1);
        }
        bf16x8 af[2], bfv[4];
#pragma unroll
        for (int mi = 0; mi < 2; ++mi)
            af[mi] = *(const bf16x8*)((const char*)&As[buf][0] + (wr * 32 + mi * 16 + lr) * 64 + g * 16);
#pragma unroll
        for (int ni = 0; ni < 4; ++ni)
            bfv[ni] = *(const bf16x8*)((const char*)&Bs[buf][0] + (wc * 64 + ni * 16 + lr) * 64 + g * 16);
#pragma unroll
        for (int mi = 0; mi < 2; ++mi)
#pragma unroll
            for (int ni = 0; ni < 4; ++ni)
                acc[mi][ni] = __builtin_amdgcn_mfma_f32_16x16x32_bf16(af[mi], bfv[ni], acc[mi][ni], 0, 0, 0);
        __syncthreads();
    }

#pragma unroll
    for (int mi = 0; mi < 2; ++mi)
#pragma unroll
        for (int r = 0; r < 4; ++r) {
            const long row = mBase + wr * 32 + mi * 16 + g * 4 + r;
#pragma unroll
            for (int ni = 0; ni < 4; ++ni) {
                const long col = nBase + wc * 64 + ni * 16 + lr;
                Cf[row * N + col] = acc[mi][ni][r] + bias[col];
            }
        }
}

// ---------------- flash attention (lean-VALU softmax) -----------------------
// grid 512 linear, XCD-group swizzle (16 q-blocks of one (b,h) pinned to one
// XCD -> K/V panel L2-resident; r7-verified FETCH 70->16.5MB).
// 4 waves, 32 q-rows/wave. S^T = mfma(K,Q); kappa-permuted K; V pre-transposed.
// Softmax: Q pre-scaled by 0.125*log2e (prep_k), raw v_exp_f32, no offset
// (constant cancels in normalization), row-sum via ones-MFMA (osum).
// KVBLK=128 (2 halves per sync). Mask bit set == masked -> arg -512 -> P=0.

__global__ __launch_bounds__(256, 2) void attn_fwd(
    const u16* __restrict__ Qg_, const u16* __restrict__ Kg_, const u16* __restrict__ Vtg_,
    const u32* __restrict__ maskp, u16* __restrict__ Og_)
{
    __shared__ u16 Ks[2][2][64 * 64];  // [set][half], kappa-permuted + swizzled
    __shared__ u16 Vs[2][2][64 * 64];  // [set][half], rows=d, swizzled

    const int tid = threadIdx.x, w = tid >> 6, lane = tid & 63;
    const int g = lane >> 4, lr = lane & 15;
    const int L = blockIdx.x;
    const int slot = L >> 3;
    const int grp = (L & 7) + 8 * (slot >> 4);   // (b*16+h) group, XCD-pinned
    const int q0 = (slot & 15) * 128;
    const int b = grp >> 4, h = grp & 15;
    const u16* Qg = Qg_ + ((long)b * 2048) * 1024 + h * 64;
    const u16* Kg = Kg_ + ((long)b * 2048) * 1024 + h * 64;
    const u16* Vtg = Vtg_ + ((long)grp * 64) * 2048;
    u16* Og = Og_ + ((long)b * 2048) * 1024 + h * 64;

    // ---- staging address precompute (2 chunks of 16B per thread each) ----
    long ksrc[2], vsrc[2];
    int ldso[2];
#pragma unroll
    for (int c = 0; c < 2; ++c) {
        const int o = (tid + c * 256) * 16;
        const int m = o >> 7, cb = o & 127;
        const int sb = cb ^ ((m & 7) << 4);
        ldso[c] = o;
        const int kap = ((m >> 4) & 1) * 32 + ((m >> 2) & 3) * 8 + ((m >> 5) & 1) * 4 + (m & 3);
        ksrc[c] = (long)kap * 1024 + (sb >> 1);
        vsrc[c] = (long)m * 2048 + (sb >> 1);
    }

    // ---- Q straight to registers (no LDS) ----
    bf16x8 qf[2][2];
#pragma unroll
    for (int nq = 0; nq < 2; ++nq)
#pragma unroll
        for (int ks = 0; ks < 2; ++ks)
            qf[nq][ks] = *(const bf16x8*)(Qg + (long)(q0 + w * 32 + nq * 16 + lr) * 1024 + ks * 32 + g * 8);

    const long mrow0 = (long)b * 2048 + q0 + w * 32 + lr;
    const u32* mpr0 = maskp + mrow0 * 64;
    const u32* mpr1 = maskp + (mrow0 + 16) * 64;

    // ---- prologue: mask(0) -> regs; stage set 0 (both halves) ----
    u32x4 mwC0 = *(const u32x4*)(mpr0);
    u32x4 mwC1 = *(const u32x4*)(mpr1);
#pragma unroll
    for (int hh = 0; hh < 2; ++hh)
#pragma unroll
        for (int c = 0; c < 2; ++c) {
            gll16(Kg + hh * 65536 + ksrc[c], (char*)&Ks[0][hh][0] + ldso[c]);
            gll16(Vtg + hh * 64 + vsrc[c], (char*)&Vs[0][hh][0] + ldso[c]);
        }
    __syncthreads();

    const int swz = (lr & 7) << 4;
    int kb[2];
#pragma unroll
    for (int ks = 0; ks < 2; ++ks) kb[ks] = (ks * 64 + g * 16) ^ swz;

    f32x4 oacc[2][4];
#pragma unroll
    for (int i = 0; i < 2; ++i)
#pragma unroll
        for (int j = 0; j < 4; ++j) oacc[i][j] = f32x4{0.f, 0.f, 0.f, 0.f};
    f32x4 osum[2];
    osum[0] = f32x4{0.f, 0.f, 0.f, 0.f};
    osum[1] = f32x4{0.f, 0.f, 0.f, 0.f};
    const f32x4 z4 = {0.f, 0.f, 0.f, 0.f};
    const u32x4 ones4 = {0x3F803F80u, 0x3F803F80u, 0x3F803F80u, 0x3F803F80u};
    const bf16x8 ones8 = __builtin_bit_cast(bf16x8, ones4);

    for (int t = 0; t < 16; ++t) {
        const int cur = t & 1;
        // ---- prefetch mask(t+1) -> regs; stage(t+1) -> other set ----
        u32x4 mwN0, mwN1;
        if (t + 1 < 16) {
            mwN0 = *(const u32x4*)(mpr0 + (t + 1) * 4);
            mwN1 = *(const u32x4*)(mpr1 + (t + 1) * 4);
            const long kv0 = (long)(t + 1) * 128;
#pragma unroll
            for (int hh = 0; hh < 2; ++hh)
#pragma unroll
                for (int c = 0; c < 2; ++c) {
                    gll16(Kg + (kv0 + hh * 64) * 1024 + ksrc[c], (char*)&Ks[cur ^ 1][hh][0] + ldso[c]);
                    gll16(Vtg + kv0 + hh * 64 + vsrc[c], (char*)&Vs[cur ^ 1][hh][0] + ldso[c]);
                }
        }

        // ---- two 64-kv halves ----
#pragma unroll
        for (int hh = 0; hh < 2; ++hh) {
            const char* kbase = (const char*)&Ks[cur][hh][0];
            const char* vbase = (const char*)&Vs[cur][hh][0];

            // S^T = K . Q^T (Q pre-scaled)
            f32x4 s[4][2];
            __builtin_amdgcn_s_setprio(1);
#pragma unroll
            for (int mt = 0; mt < 4; ++mt) {
                const bf16x8 kf0 = *(const bf16x8*)(kbase + (mt * 16 + lr) * 128 + kb[0]);
                const bf16x8 kf1 = *(const bf16x8*)(kbase + (mt * 16 + lr) * 128 + kb[1]);
#pragma unroll
                for (int nq = 0; nq < 2; ++nq) {
                    s[mt][nq] = __builtin_amdgcn_mfma_f32_16x16x32_bf16(kf0, qf[nq][0], z4, 0, 0, 0);
                    s[mt][nq] = __builtin_amdgcn_mfma_f32_16x16x32_bf16(kf1, qf[nq][1], s[mt][nq], 0, 0, 0);
                }
            }
            __builtin_amdgcn_s_setprio(0);

            // masked softmax: P = exp2(s) (no offset; 2^C cancels), masked -> 0
            u32 pk[4][2][2];
#pragma unroll
            for (int ts = 0; ts < 4; ++ts) {
                const int sh = g * 8 + (ts >> 1) * 4;
                const int wi = hh * 2 + (ts & 1);
#pragma unroll
                for (int nq = 0; nq < 2; ++nq) {
                    const u32 word = nq ? mwC1[wi] : mwC0[wi];
                    const u32 wsh = word >> sh;
                    float e[4];
#pragma unroll
                    for (int r = 0; r < 4; ++r) {
                        const float sv = ((wsh >> r) & 1u) ? -512.f : s[ts][nq][r];
                        e[r] = fexp2(sv);
                    }
                    pk[ts][nq][0] = cvtpk_bf16(e[0], e[1]);
                    pk[ts][nq][1] = cvtpk_bf16(e[2], e[3]);
                }
            }

            // O += P.V ; row-sum via ones-MFMA
            bf16x8 pa[2][2];
#pragma unroll
            for (int nq = 0; nq < 2; ++nq)
#pragma unroll
                for (int ks = 0; ks < 2; ++ks) {
                    u32x4 t4;
                    t4[0] = pk[ks][nq][0]; t4[1] = pk[ks][nq][1];
                    t4[2] = pk[ks + 2][nq][0]; t4[3] = pk[ks + 2][nq][1];
                    pa[nq][ks] = __builtin_bit_cast(bf16x8, t4);
                }
            __builtin_amdgcn_s_setprio(1);
#pragma unroll
            for (int nq = 0; nq < 2; ++nq)
#pragma unroll
                for (int ks = 0; ks < 2; ++ks)
                    osum[nq] = __builtin_amdgcn_mfma_f32_16x16x32_bf16(pa[nq][ks], ones8, osum[nq], 0, 0, 0);
#pragma unroll
            for (int dt = 0; dt < 4; ++dt)
#pragma unroll
                for (int ks = 0; ks < 2; ++ks) {
                    const bf16x8 vf = *(const bf16x8*)(vbase + (dt * 16 + lr) * 128 + kb[ks]);
#pragma unroll
                    for (int nq = 0; nq < 2; ++nq)
                        oacc[nq][dt] = __builtin_amdgcn_mfma_f32_16x16x32_bf16(pa[nq][ks], vf, oacc[nq][dt], 0, 0, 0);
                }
            __builtin_amdgcn_s_setprio(0);
        }
        __syncthreads();

        mwC0 = mwN0; mwC1 = mwN1;
    }

    // ---- epilogue: osum already holds per-row denominators in-lane ----
#pragma unroll
    for (int nq = 0; nq < 2; ++nq)
#pragma unroll
        for (int rr = 0; rr < 4; ++rr) {
            const float inv = __builtin_amdgcn_rcpf(osum[nq][rr]);
            const long row = (long)q0 + w * 32 + nq * 16 + g * 4 + rr;
#pragma unroll
            for (int dt = 0; dt < 4; ++dt)
                Og[row * 1024 + dt * 16 + lr] = f2bf(oacc[nq][dt][rr] * inv);
        }
}

// ---------------- launcher ----------------

extern "C" void kernel_launch(void* const* d_in, const int* in_sizes, int n_in,
                              void* d_out, int out_size, void* d_ws, size_t ws_size,
                              hipStream_t stream)
{
    (void)in_sizes; (void)n_in; (void)out_size; (void)ws_size;
    const float* x    = (const float*)d_in[0];
    const int*   mask = (const int*)d_in[1];
    const float* Wq   = (const float*)d_in[2];
    const float* Wk   = (const float*)d_in[3];
    const float* Wv   = (const float*)d_in[4];
    const float* Wo   = (const float*)d_in[5];
    const float* bo   = (const float*)d_in[6];
    float* out = (float*)d_out;

    char* ws = (char*)d_ws;
    u16* xb    = (u16*)(ws);                 // 8 MB  x as bf16 (dead after gemm_qkv)
    u16* vtws  = (u16*)(ws);                 // 8 MB  V^T, reuses xb region
    u16* WqT   = (u16*)(ws + (8l  << 20));   // 2 MB each, transposed bf16 (q,k,v contiguous)
    u16* WkT   = (u16*)(ws + (10l << 20));
    u16* WvT   = (u16*)(ws + (12l << 20));
    u16* WoT   = (u16*)(ws + (14l << 20));
    u16* qws   = (u16*)(ws + (16l << 20));   // 8 MB each (q,k,v contiguous)
    u16* kws   = (u16*)(ws + (24l << 20));
    u16* vws   = (u16*)(ws + (32l << 20));
    u16* inner = (u16*)(ws + (40l << 20));   // 8 MB
    u32* mp    = (u32*)(ws + (48l << 20));   // 1 MB packed mask

    prep_k<<<4096, 256, 0, stream>>>(x, xb, Wq, Wk, Wv, Wo, WqT, WkT, WvT, WoT, mask, mp);
    gemm_qkv<<<dim3(24, 32), 256, 0, stream>>>(xb, WqT, qws);
    vt_k<<<dim3(32, 16, 2), 256, 0, stream>>>(vws, vtws);
    attn_fwd<<<512, 256, 0, stream>>>(qws, kws, vtws, mp, inner);
    gemm_out<<<dim3(8, 64), 256, 0, stream>>>(inner, WoT, out, bo);
}

// Round 10
// 130.634 us; speedup vs baseline: 1.2926x; 1.0370x over previous
//
#include <hip/hip_runtime.h>
#include <cstdint>
#include <cstddef>

typedef float    f32x4  __attribute__((ext_vector_type(4)));
typedef __bf16   bf16x8 __attribute__((ext_vector_type(8)));
typedef unsigned u32x4  __attribute__((ext_vector_type(4)));
typedef unsigned u32x2  __attribute__((ext_vector_type(2)));
typedef unsigned short u16;
typedef unsigned int   u32;

#define SCL2E 0.18033688011112042f   /* 0.125 * log2(e), folded into Wq */

static __device__ __forceinline__ u16 f2bf(float f) {
    u32 u = __builtin_bit_cast(u32, f);
    u32 r = (u + 0x7FFFu + ((u >> 16) & 1u)) >> 16;
    return (u16)r;
}

static __device__ __forceinline__ u32 cvtpk_bf16(float lo, float hi) {
    u32 r;
    asm("v_cvt_pk_bf16_f32 %0, %1, %2" : "=v"(r) : "v"(lo), "v"(hi));
    return r;
}

// raw hardware exp2 — avoids llvm.exp2's denormal-fixup expansion (~6 VALU).
static __device__ __forceinline__ float fexp2(float x) {
    float r;
    asm("v_exp_f32 %0, %1" : "=v"(r) : "v"(x));
    return r;
}

static __device__ __forceinline__ void gll16(const u16* g, void* l) {
    __builtin_amdgcn_global_load_lds((const __attribute__((address_space(1))) void*)g,
                                     (__attribute__((address_space(3))) void*)l, 16, 0, 0);
}

// ---------------- fused prep kernel ----------------
// blocks 0..2047: x f32->bf16; 2048..3071: W transpose (Wq pre-scaled);
// 3072..4095: mask bit-pack. All independent.

__global__ __launch_bounds__(256) void prep_k(
    const float* __restrict__ x, u16* __restrict__ xb,
    const float* __restrict__ W0, const float* __restrict__ W1,
    const float* __restrict__ W2, const float* __restrict__ W3,
    u16* __restrict__ T0, u16* __restrict__ T1,
    u16* __restrict__ T2, u16* __restrict__ T3,
    const int* __restrict__ mask, u32* __restrict__ mp)
{
    __shared__ float T[64][65];
    const int bid = blockIdx.x;
    if (bid < 2048) {
        // ---- x -> bf16 ----
        const long i = ((long)bid * 256 + threadIdx.x) * 8;
        f32x4 a = *(const f32x4*)(x + i);
        f32x4 c = *(const f32x4*)(x + i + 4);
        u32x4 o;
        o[0] = (u32)f2bf(a[0]) | ((u32)f2bf(a[1]) << 16);
        o[1] = (u32)f2bf(a[2]) | ((u32)f2bf(a[3]) << 16);
        o[2] = (u32)f2bf(c[0]) | ((u32)f2bf(c[1]) << 16);
        o[3] = (u32)f2bf(c[2]) | ((u32)f2bf(c[3]) << 16);
        *(u32x4*)(xb + i) = o;
    } else if (bid < 3072) {
        // ---- W transpose f32 -> bf16 [N][K]; Wq scaled by SCL2E ----
        const int idx = bid - 2048;
        const int z = idx >> 8, rem = idx & 255;
        const int n0 = (rem & 15) * 64, k0 = (rem >> 4) * 64;
        const float* W = (z == 0) ? W0 : (z == 1) ? W1 : (z == 2) ? W2 : W3;
        u16* Wt = (z == 0) ? T0 : (z == 1) ? T1 : (z == 2) ? T2 : T3;
        const float scl = (z == 0) ? SCL2E : 1.0f;
        const int c = threadIdx.x & 63, r0 = (threadIdx.x >> 6) * 16;
#pragma unroll
        for (int i = 0; i < 16; ++i)
            T[r0 + i][c] = W[(long)(k0 + r0 + i) * 1024 + n0 + c];
        __syncthreads();
#pragma unroll
        for (int i = 0; i < 16; ++i)
            Wt[(long)(n0 + r0 + i) * 1024 + k0 + c] = f2bf(T[c][r0 + i] * scl);
    } else {
        // ---- mask int32 -> bit pack (bit set == masked out) ----
        const long wi = (long)(bid - 3072) * 256 + threadIdx.x;
        const int* src = mask + wi * 32;
        u32 word = 0;
#pragma unroll
        for (int c = 0; c < 8; ++c) {
            const int4 v = *(const int4*)(src + c * 4);
            word |= (u32)(v.x != 0) << (c * 4);
            word |= (u32)(v.y != 0) << (c * 4 + 1);
            word |= (u32)(v.z != 0) << (c * 4 + 2);
            word |= (u32)(v.w != 0) << (c * 4 + 3);
        }
        mp[wi] = word;
    }
}

// transpose V [b*2048 n][h*64+d] -> vt [(b*16+h)*64 + d][2048 n]  (bf16)
__global__ __launch_bounds__(256) void vt_k(const u16* __restrict__ v, u16* __restrict__ vt) {
    __shared__ u16 T[64][66];
    const int nt = blockIdx.x, h = blockIdx.y, b = blockIdx.z;
    const int c = threadIdx.x & 63, r0 = (threadIdx.x >> 6) * 16;
    const u16* src = v + ((long)b * 2048 + nt * 64) * 1024 + h * 64;
    u16* dst = vt + ((long)(b * 16 + h) * 64) * 2048 + nt * 64;
#pragma unroll
    for (int i = 0; i < 16; ++i)
        T[r0 + i][c] = src[(long)(r0 + i) * 1024 + c];
    __syncthreads();
#pragma unroll
    for (int i = 0; i < 16; ++i)
        dst[(long)(r0 + i) * 2048 + c] = T[c][r0 + i];
}

// ---------------- fused QKV GEMM: [4096x1024] @ [1024x3072] ----------------

__global__ __launch_bounds__(256, 3) void gemm_qkv(
    const u16* __restrict__ A, const u16* __restrict__ Bt, u16* __restrict__ C0)
{
    constexpr int K = 1024;
    __shared__ u16 As[2][128 * 32];
    __shared__ u16 Bs[2][128 * 32];
    const int tid = threadIdx.x;
    const int wave = tid >> 6, lane = tid & 63;
    const int wr = wave >> 1, wc = wave & 1;
    const int g = lane >> 4, lr = lane & 15;
    const long mBase = (long)blockIdx.y * 128;
    const long nBase = (long)blockIdx.x * 128;

    f32x4 acc[4][4];
#pragma unroll
    for (int i = 0; i < 4; ++i)
#pragma unroll
        for (int j = 0; j < 4; ++j) acc[i][j] = f32x4{0.f, 0.f, 0.f, 0.f};

    const int o0 = tid * 16, o1 = (256 + tid) * 16;
    const int r0 = o0 >> 6, cb0 = o0 & 63;
    const int r1 = o1 >> 6, cb1 = o1 & 63;

    gll16(A  + (mBase + r0) * K + (cb0 >> 1), (char*)&As[0][0] + o0);
    gll16(A  + (mBase + r1) * K + (cb1 >> 1), (char*)&As[0][0] + o1);
    gll16(Bt + (nBase + r0) * K + (cb0 >> 1), (char*)&Bs[0][0] + o0);
    gll16(Bt + (nBase + r1) * K + (cb1 >> 1), (char*)&Bs[0][0] + o1);
    __syncthreads();

#pragma unroll 2
    for (int kt = 0; kt < 32; ++kt) {
        const int buf = kt & 1;
        if (kt + 1 < 32) {
            const long ko = (long)(kt + 1) * 32;
            gll16(A  + (mBase + r0) * K + ko + (cb0 >> 1), (char*)&As[buf ^ 1][0] + o0);
            gll16(A  + (mBase + r1) * K + ko + (cb1 >> 1), (char*)&As[buf ^ 1][0] + o1);
            gll16(Bt + (nBase + r0) * K + ko + (cb0 >> 1), (char*)&Bs[buf ^ 1][0] + o0);
            gll16(Bt + (nBase + r1) * K + ko + (cb1 >> 1), (char*)&Bs[buf ^ 1][0] + o1);
        }
        bf16x8 af[4], bfv[4];
#pragma unroll
        for (int mi = 0; mi < 4; ++mi)
            af[mi] = *(const bf16x8*)((const char*)&As[buf][0] + (wr * 64 + mi * 16 + lr) * 64 + g * 16);
#pragma unroll
        for (int ni = 0; ni < 4; ++ni)
            bfv[ni] = *(const bf16x8*)((const char*)&Bs[buf][0] + (wc * 64 + ni * 16 + lr) * 64 + g * 16);
#pragma unroll
        for (int mi = 0; mi < 4; ++mi)
#pragma unroll
            for (int ni = 0; ni < 4; ++ni)
                acc[mi][ni] = __builtin_amdgcn_mfma_f32_16x16x32_bf16(af[mi], bfv[ni], acc[mi][ni], 0, 0, 0);
        __syncthreads();
    }

    const int wsel = (int)(nBase >> 10);
    u16* Cw = C0 + (long)wsel * (4096l * 1024);
    const long ncl = nBase & 1023;
#pragma unroll
    for (int mi = 0; mi < 4; ++mi)
#pragma unroll
        for (int r = 0; r < 4; ++r) {
            const long row = mBase + wr * 64 + mi * 16 + g * 4 + r;
#pragma unroll
            for (int ni = 0; ni < 4; ++ni) {
                const long col = ncl + wc * 64 + ni * 16 + lr;
                Cw[row * 1024 + col] = f2bf(acc[mi][ni][r]);
            }
        }
}

// ---------------- output-proj GEMM, BM=64 (2 blocks/CU) --------------------

__global__ __launch_bounds__(256, 2) void gemm_out(
    const u16* __restrict__ A, const u16* __restrict__ Bt,
    float* __restrict__ Cf, const float* __restrict__ bias)
{
    constexpr int K = 1024, N = 1024;
    __shared__ u16 As[2][64 * 32];
    __shared__ u16 Bs[2][128 * 32];
    const int tid = threadIdx.x;
    const int wave = tid >> 6, lane = tid & 63;
    const int wr = wave >> 1, wc = wave & 1;
    const int g = lane >> 4, lr = lane & 15;
    const long mBase = (long)blockIdx.y * 64;
    const long nBase = (long)blockIdx.x * 128;

    f32x4 acc[2][4];
#pragma unroll
    for (int i = 0; i < 2; ++i)
#pragma unroll
        for (int j = 0; j < 4; ++j) acc[i][j] = f32x4{0.f, 0.f, 0.f, 0.f};

    const int oA = tid * 16;
    const int rA = oA >> 6, cbA = oA & 63;
    const int o0 = tid * 16, o1 = (256 + tid) * 16;
    const int r0 = o0 >> 6, cb0 = o0 & 63;
    const int r1 = o1 >> 6, cb1 = o1 & 63;

    gll16(A  + (mBase + rA) * K + (cbA >> 1), (char*)&As[0][0] + oA);
    gll16(Bt + (nBase + r0) * K + (cb0 >> 1), (char*)&Bs[0][0] + o0);
    gll16(Bt + (nBase + r1) * K + (cb1 >> 1), (char*)&Bs[0][0] + o1);
    __syncthreads();

#pragma unroll 2
    for (int kt = 0; kt < 32; ++kt) {
        const int buf = kt & 1;
        if (kt + 1 < 32) {
            const long ko = (long)(kt + 1) * 32;
            gll16(A  + (mBase + rA) * K + ko + (cbA >> 1), (char*)&As[buf ^ 1][0] + oA);
            gll16(Bt + (nBase + r0) * K + ko + (cb0 >> 1), (char*)&Bs[buf ^ 1][0] + o0);
            gll16(Bt + (nBase + r1) * K + ko + (cb1 >> 1), (char*)&Bs[buf ^ 1][0] + o1);
        }
        bf16x8 af[2], bfv[4];
#pragma unroll
        for (int mi = 0; mi < 2; ++mi)
            af[mi] = *(const bf16x8*)((const char*)&As[buf][0] + (wr * 32 + mi * 16 + lr) * 64 + g * 16);
#pragma unroll
        for (int ni = 0; ni < 4; ++ni)
            bfv[ni] = *(const bf16x8*)((const char*)&Bs[buf][0] + (wc * 64 + ni * 16 + lr) * 64 + g * 16);
#pragma unroll
        for (int mi = 0; mi < 2; ++mi)
#pragma unroll
            for (int ni = 0; ni < 4; ++ni)
                acc[mi][ni] = __builtin_amdgcn_mfma_f32_16x16x32_bf16(af[mi], bfv[ni], acc[mi][ni], 0, 0, 0);
        __syncthreads();
    }

#pragma unroll
    for (int mi = 0; mi < 2; ++mi)
#pragma unroll
        for (int r = 0; r < 4; ++r) {
            const long row = mBase + wr * 32 + mi * 16 + g * 4 + r;
#pragma unroll
            for (int ni = 0; ni < 4; ++ni) {
                const long col = nBase + wc * 64 + ni * 16 + lr;
                Cf[row * N + col] = acc[mi][ni][r] + bias[col];
            }
        }
}

// ---------------- flash attention (QBLK=256, 8 waves) -----------------------
// grid 256 linear, XCD-group swizzle: 8 q-blocks of one (b,h) pinned to one
// XCD (L&7 = xcd; slot=L>>3; q-tile=slot&7; group=xcd+8*(slot>>3)).
// 8 waves x 32 q-rows. S^T = mfma(K,Q); kappa-permuted K; V pre-transposed.
// Q pre-scaled by 0.125*log2e; raw v_exp_f32; post-exp sbfe AND-masking;
// row-sum via ones-MFMA. KVBLK=128, unroll-2 t-loop (imm-folded ds addrs).

__global__ __launch_bounds__(512, 2) void attn_fwd(
    const u16* __restrict__ Qg_, const u16* __restrict__ Kg_, const u16* __restrict__ Vtg_,
    const u32* __restrict__ maskp, u16* __restrict__ Og_)
{
    __shared__ u16 Ks[2][2][64 * 64];  // [set][half], kappa-permuted + swizzled
    __shared__ u16 Vs[2][2][64 * 64];  // [set][half], rows=d, swizzled

    const int tid = threadIdx.x, w = tid >> 6, lane = tid & 63;
    const int g = lane >> 4, lr = lane & 15;
    const int L = blockIdx.x;
    const int slot = L >> 3;
    const int grp = (L & 7) + 8 * (slot >> 3);   // (b*16+h) group, XCD-pinned
    const int q0 = (slot & 7) * 256;
    const int b = grp >> 4, h = grp & 15;
    const u16* Qg = Qg_ + ((long)b * 2048) * 1024 + h * 64;
    const u16* Kg = Kg_ + ((long)b * 2048) * 1024 + h * 64;
    const u16* Vtg = Vtg_ + ((long)grp * 64) * 2048;
    u16* Og = Og_ + ((long)b * 2048) * 1024 + h * 64;

    // ---- staging addresses: one 16B chunk per thread per (half, K/V) ----
    const int ldso = tid * 16;
    const int m = ldso >> 7, cb = ldso & 127;
    const int sb = cb ^ ((m & 7) << 4);
    const int kap = ((m >> 4) & 1) * 32 + ((m >> 2) & 3) * 8 + ((m >> 5) & 1) * 4 + (m & 3);
    const long ksrc = (long)kap * 1024 + (sb >> 1);
    const long vsrc = (long)m * 2048 + (sb >> 1);

    // ---- Q straight to registers (no LDS) ----
    bf16x8 qf[2][2];
#pragma unroll
    for (int nq = 0; nq < 2; ++nq)
#pragma unroll
        for (int ks = 0; ks < 2; ++ks)
            qf[nq][ks] = *(const bf16x8*)(Qg + (long)(q0 + w * 32 + nq * 16 + lr) * 1024 + ks * 32 + g * 8);

    const long mrow0 = (long)b * 2048 + q0 + w * 32 + lr;
    const u32* mpr0 = maskp + mrow0 * 64;
    const u32* mpr1 = maskp + (mrow0 + 16) * 64;

    // ---- prologue: mask(0) -> regs; stage set 0 (both halves) ----
    u32x4 mwC0 = *(const u32x4*)(mpr0);
    u32x4 mwC1 = *(const u32x4*)(mpr1);
#pragma unroll
    for (int hh = 0; hh < 2; ++hh) {
        gll16(Kg + hh * 65536 + ksrc, (char*)&Ks[0][hh][0] + ldso);
        gll16(Vtg + hh * 64 + vsrc, (char*)&Vs[0][hh][0] + ldso);
    }
    __syncthreads();

    const int swz = (lr & 7) << 4;
    int kb[2];
#pragma unroll
    for (int ks = 0; ks < 2; ++ks) kb[ks] = (ks * 64 + g * 16) ^ swz;

    f32x4 oacc[2][4];
#pragma unroll
    for (int i = 0; i < 2; ++i)
#pragma unroll
        for (int j = 0; j < 4; ++j) oacc[i][j] = f32x4{0.f, 0.f, 0.f, 0.f};
    f32x4 osum[2];
    osum[0] = f32x4{0.f, 0.f, 0.f, 0.f};
    osum[1] = f32x4{0.f, 0.f, 0.f, 0.f};
    const f32x4 z4 = {0.f, 0.f, 0.f, 0.f};
    const u32x4 ones4 = {0x3F803F80u, 0x3F803F80u, 0x3F803F80u, 0x3F803F80u};
    const bf16x8 ones8 = __builtin_bit_cast(bf16x8, ones4);

#pragma unroll 2
    for (int t = 0; t < 16; ++t) {
        const int cur = t & 1;
        // ---- prefetch mask(t+1) -> regs; stage(t+1) -> other set ----
        u32x4 mwN0, mwN1;
        if (t + 1 < 16) {
            mwN0 = *(const u32x4*)(mpr0 + (t + 1) * 4);
            mwN1 = *(const u32x4*)(mpr1 + (t + 1) * 4);
            const long kv0 = (long)(t + 1) * 128;
#pragma unroll
            for (int hh = 0; hh < 2; ++hh) {
                gll16(Kg + (kv0 + hh * 64) * 1024 + ksrc, (char*)&Ks[cur ^ 1][hh][0] + ldso);
                gll16(Vtg + kv0 + hh * 64 + vsrc, (char*)&Vs[cur ^ 1][hh][0] + ldso);
            }
        }

        // ---- two 64-kv halves ----
#pragma unroll
        for (int hh = 0; hh < 2; ++hh) {
            const char* kbase = (const char*)&Ks[cur][hh][0];
            const char* vbase = (const char*)&Vs[cur][hh][0];

            // S^T = K . Q^T (Q pre-scaled)
            f32x4 s[4][2];
            __builtin_amdgcn_s_setprio(1);
#pragma unroll
            for (int mt = 0; mt < 4; ++mt) {
                const bf16x8 kf0 = *(const bf16x8*)(kbase + (mt * 16 + lr) * 128 + kb[0]);
                const bf16x8 kf1 = *(const bf16x8*)(kbase + (mt * 16 + lr) * 128 + kb[1]);
#pragma unroll
                for (int nq = 0; nq < 2; ++nq) {
                    s[mt][nq] = __builtin_amdgcn_mfma_f32_16x16x32_bf16(kf0, qf[nq][0], z4, 0, 0, 0);
                    s[mt][nq] = __builtin_amdgcn_mfma_f32_16x16x32_bf16(kf1, qf[nq][1], s[mt][nq], 0, 0, 0);
                }
            }
            __builtin_amdgcn_s_setprio(0);

            // masked softmax: P = exp2(s) AND keep-mask (sbfe of inverted word)
            u32 pk[4][2][2];
#pragma unroll
            for (int ts = 0; ts < 4; ++ts) {
                const int sh = g * 8 + (ts >> 1) * 4;
                const int wi = hh * 2 + (ts & 1);
#pragma unroll
                for (int nq = 0; nq < 2; ++nq) {
                    const u32 word = nq ? mwC1[wi] : mwC0[wi];
                    const u32 iwsh = (~word) >> sh;
                    float e[4];
#pragma unroll
                    for (int r = 0; r < 4; ++r) {
                        const float ev = fexp2(s[ts][nq][r]);
                        const u32 keep = (u32)__builtin_amdgcn_sbfe((int)iwsh, (u32)r, 1u);
                        e[r] = __builtin_bit_cast(float, __builtin_bit_cast(u32, ev) & keep);
                    }
                    pk[ts][nq][0] = cvtpk_bf16(e[0], e[1]);
                    pk[ts][nq][1] = cvtpk_bf16(e[2], e[3]);
                }
            }

            // O += P.V ; row-sum via ones-MFMA
            bf16x8 pa[2][2];
#pragma unroll
            for (int nq = 0; nq < 2; ++nq)
#pragma unroll
                for (int ks = 0; ks < 2; ++ks) {
                    u32x4 t4;
                    t4[0] = pk[ks][nq][0]; t4[1] = pk[ks][nq][1];
                    t4[2] = pk[ks + 2][nq][0]; t4[3] = pk[ks + 2][nq][1];
                    pa[nq][ks] = __builtin_bit_cast(bf16x8, t4);
                }
            __builtin_amdgcn_s_setprio(1);
#pragma unroll
            for (int nq = 0; nq < 2; ++nq)
#pragma unroll
                for (int ks = 0; ks < 2; ++ks)
                    osum[nq] = __builtin_amdgcn_mfma_f32_16x16x32_bf16(pa[nq][ks], ones8, osum[nq], 0, 0, 0);
#pragma unroll
            for (int dt = 0; dt < 4; ++dt)
#pragma unroll
                for (int ks = 0; ks < 2; ++ks) {
                    const bf16x8 vf = *(const bf16x8*)(vbase + (dt * 16 + lr) * 128 + kb[ks]);
#pragma unroll
                    for (int nq = 0; nq < 2; ++nq)
                        oacc[nq][dt] = __builtin_amdgcn_mfma_f32_16x16x32_bf16(pa[nq][ks], vf, oacc[nq][dt], 0, 0, 0);
                }
            __builtin_amdgcn_s_setprio(0);
        }
        __syncthreads();

        mwC0 = mwN0; mwC1 = mwN1;
    }

    // ---- epilogue: osum already holds per-row denominators in-lane ----
#pragma unroll
    for (int nq = 0; nq < 2; ++nq)
#pragma unroll
        for (int rr = 0; rr < 4; ++rr) {
            const float inv = __builtin_amdgcn_rcpf(osum[nq][rr]);
            const long row = (long)q0 + w * 32 + nq * 16 + g * 4 + rr;
#pragma unroll
            for (int dt = 0; dt < 4; ++dt)
                Og[row * 1024 + dt * 16 + lr] = f2bf(oacc[nq][dt][rr] * inv);
        }
}

// ---------------- launcher ----------------

extern "C" void kernel_launch(void* const* d_in, const int* in_sizes, int n_in,
                              void* d_out, int out_size, void* d_ws, size_t ws_size,
                              hipStream_t stream)
{
    (void)in_sizes; (void)n_in; (void)out_size; (void)ws_size;
    const float* x    = (const float*)d_in[0];
    const int*   mask = (const int*)d_in[1];
    const float* Wq   = (const float*)d_in[2];
    const float* Wk   = (const float*)d_in[3];
    const float* Wv   = (const float*)d_in[4];
    const float* Wo   = (const float*)d_in[5];
    const float* bo   = (const float*)d_in[6];
    float* out = (float*)d_out;

    char* ws = (char*)d_ws;
    u16* xb    = (u16*)(ws);                 // 8 MB  x as bf16 (dead after gemm_qkv)
    u16* vtws  = (u16*)(ws);                 // 8 MB  V^T, reuses xb region
    u16* WqT   = (u16*)(ws + (8l  << 20));   // 2 MB each, transposed bf16 (q,k,v contiguous)
    u16* WkT   = (u16*)(ws + (10l << 20));
    u16* WvT   = (u16*)(ws + (12l << 20));
    u16* WoT   = (u16*)(ws + (14l << 20));
    u16* qws   = (u16*)(ws + (16l << 20));   // 8 MB each (q,k,v contiguous)
    u16* kws   = (u16*)(ws + (24l << 20));
    u16* vws   = (u16*)(ws + (32l << 20));
    u16* inner = (u16*)(ws + (40l << 20));   // 8 MB
    u32* mp    = (u32*)(ws + (48l << 20));   // 1 MB packed mask

    prep_k<<<4096, 256, 0, stream>>>(x, xb, Wq, Wk, Wv, Wo, WqT, WkT, WvT, WoT, mask, mp);
    gemm_qkv<<<dim3(24, 32), 256, 0, stream>>>(xb, WqT, qws);
    vt_k<<<dim3(32, 16, 2), 256, 0, stream>>>(vws, vtws);
    attn_fwd<<<256, 512, 0, stream>>>(qws, kws, vtws, mp, inner);
    gemm_out<<<dim3(8, 64), 256, 0, stream>>>(inner, WoT, out, bo);
}

// Round 11
// 128.322 us; speedup vs baseline: 1.3159x; 1.0180x over previous
//
#include <hip/hip_runtime.h>
#include <cstdint>
#include <cstddef>

typedef float    f32x4  __attribute__((ext_vector_type(4)));
typedef __bf16   bf16x8 __attribute__((ext_vector_type(8)));
typedef unsigned u32x4  __attribute__((ext_vector_type(4)));
typedef unsigned u32x2  __attribute__((ext_vector_type(2)));
typedef unsigned short u16;
typedef unsigned int   u32;

#define SCL2E 0.18033688011112042f   /* 0.125 * log2(e), folded into Wq */

static __device__ __forceinline__ u16 f2bf(float f) {
    u32 u = __builtin_bit_cast(u32, f);
    u32 r = (u + 0x7FFFu + ((u >> 16) & 1u)) >> 16;
    return (u16)r;
}

static __device__ __forceinline__ u32 cvtpk_bf16(float lo, float hi) {
    u32 r;
    asm("v_cvt_pk_bf16_f32 %0, %1, %2" : "=v"(r) : "v"(lo), "v"(hi));
    return r;
}

// raw hardware exp2 — avoids llvm.exp2's denormal-fixup expansion (~6 VALU).
static __device__ __forceinline__ float fexp2(float x) {
    float r;
    asm("v_exp_f32 %0, %1" : "=v"(r) : "v"(x));
    return r;
}

static __device__ __forceinline__ void gll16(const u16* g, void* l) {
    __builtin_amdgcn_global_load_lds((const __attribute__((address_space(1))) void*)g,
                                     (__attribute__((address_space(3))) void*)l, 16, 0, 0);
}

static __device__ __forceinline__ void bar() {
    asm volatile("s_barrier" ::: "memory");
}

// ---------------- fused prep kernel ----------------

__global__ __launch_bounds__(256) void prep_k(
    const float* __restrict__ x, u16* __restrict__ xb,
    const float* __restrict__ W0, const float* __restrict__ W1,
    const float* __restrict__ W2, const float* __restrict__ W3,
    u16* __restrict__ T0, u16* __restrict__ T1,
    u16* __restrict__ T2, u16* __restrict__ T3,
    const int* __restrict__ mask, u32* __restrict__ mp)
{
    __shared__ float T[64][65];
    const int bid = blockIdx.x;
    if (bid < 2048) {
        const long i = ((long)bid * 256 + threadIdx.x) * 8;
        f32x4 a = *(const f32x4*)(x + i);
        f32x4 c = *(const f32x4*)(x + i + 4);
        u32x4 o;
        o[0] = (u32)f2bf(a[0]) | ((u32)f2bf(a[1]) << 16);
        o[1] = (u32)f2bf(a[2]) | ((u32)f2bf(a[3]) << 16);
        o[2] = (u32)f2bf(c[0]) | ((u32)f2bf(c[1]) << 16);
        o[3] = (u32)f2bf(c[2]) | ((u32)f2bf(c[3]) << 16);
        *(u32x4*)(xb + i) = o;
    } else if (bid < 3072) {
        const int idx = bid - 2048;
        const int z = idx >> 8, rem = idx & 255;
        const int n0 = (rem & 15) * 64, k0 = (rem >> 4) * 64;
        const float* W = (z == 0) ? W0 : (z == 1) ? W1 : (z == 2) ? W2 : W3;
        u16* Wt = (z == 0) ? T0 : (z == 1) ? T1 : (z == 2) ? T2 : T3;
        const float scl = (z == 0) ? SCL2E : 1.0f;
        const int c = threadIdx.x & 63, r0 = (threadIdx.x >> 6) * 16;
#pragma unroll
        for (int i = 0; i < 16; ++i)
            T[r0 + i][c] = W[(long)(k0 + r0 + i) * 1024 + n0 + c];
        __syncthreads();
#pragma unroll
        for (int i = 0; i < 16; ++i)
            Wt[(long)(n0 + r0 + i) * 1024 + k0 + c] = f2bf(T[c][r0 + i] * scl);
    } else {
        const long wi = (long)(bid - 3072) * 256 + threadIdx.x;
        const int* src = mask + wi * 32;
        u32 word = 0;
#pragma unroll
        for (int c = 0; c < 8; ++c) {
            const int4 v = *(const int4*)(src + c * 4);
            word |= (u32)(v.x != 0) << (c * 4);
            word |= (u32)(v.y != 0) << (c * 4 + 1);
            word |= (u32)(v.z != 0) << (c * 4 + 2);
            word |= (u32)(v.w != 0) << (c * 4 + 3);
        }
        mp[wi] = word;
    }
}

// transpose V [b*2048 n][h*64+d] -> vt [(b*16+h)*64 + d][2048 n]  (bf16)
__global__ __launch_bounds__(256) void vt_k(const u16* __restrict__ v, u16* __restrict__ vt) {
    __shared__ u16 T[64][66];
    const int nt = blockIdx.x, h = blockIdx.y, b = blockIdx.z;
    const int c = threadIdx.x & 63, r0 = (threadIdx.x >> 6) * 16;
    const u16* src = v + ((long)b * 2048 + nt * 64) * 1024 + h * 64;
    u16* dst = vt + ((long)(b * 16 + h) * 64) * 2048 + nt * 64;
#pragma unroll
    for (int i = 0; i < 16; ++i)
        T[r0 + i][c] = src[(long)(r0 + i) * 1024 + c];
    __syncthreads();
#pragma unroll
    for (int i = 0; i < 16; ++i)
        dst[(long)(r0 + i) * 2048 + c] = T[c][r0 + i];
}

// ---------------- QKV GEMM, 256x256 tile, 8-phase counted-vmcnt ------------
// [4096x1024] @ [1024x3072] (WqT,WkT,WvT rows contiguous). 192 blocks, 512 thr
// (8 waves 2Mx4N, 128x64 C/wave). BK=64, 2 LDS dbuf (128KB). 4 phases/K-tile:
//  p0: read A qm0(8)+B qn0(4); stage A-h0(kt+1)->d^1; MFMA mi0-3 x ni0-1
//  p1: read B qn1(4);          stage A-h1(kt+1)->d^1; MFMA mi0-3 x ni2-3
//  p2: read A qm1(8);          stage B-h0(kt+2)->d  ; MFMA mi4-7 x ni0-1
//  p3:                         stage B-h1(kt+2)->d  ; MFMA mi4-7 x ni2-3; vmcnt(4)
// Slot overwrite-issue is >=1 barrier after last read (A last-read p2 of prev
// K-tile in that buf; B last-read p1 of current). vmcnt(4) at p3 verifies all
// of K-tile kt+1 (newest 2 halves = B(kt+2)). Tail: kt14 vmcnt(0), kt15 none.
// XCD 4x6 chunking: per-XCD working set 4 A-panels + 6 B-panels ~=5MB.

__global__ __launch_bounds__(512, 2) void gemm_qkv(
    const u16* __restrict__ Ag, const u16* __restrict__ Btg, u16* __restrict__ C0)
{
    __shared__ u16 Asm[2][256 * 64];
    __shared__ u16 Bsm[2][256 * 64];

    const int tid = threadIdx.x, lane = tid & 63, w = tid >> 6;
    const int wm = w >> 2, wn = w & 3;
    const int g = lane >> 4, lr = lane & 15;

    const int L = blockIdx.x;
    const int xcd = L & 7, idx = L >> 3;
    const long mBase = (long)((xcd & 3) * 4 + (idx & 3)) * 256;
    const long nBase = (long)((xcd >> 2) * 6 + (idx >> 2)) * 256;

    // staging constants: thread covers 16B at (row = rd*64 + tid>>3, swz col)
    const int srow = tid >> 3;
    const int scolb = ((tid & 7) << 4) ^ ((srow & 7) << 4);
    const long aoff = (mBase + srow) * 1024 + (scolb >> 1);
    const long boff = (nBase + srow) * 1024 + (scolb >> 1);
    const int ldst = tid * 16;

    int kb[2];
#pragma unroll
    for (int ks = 0; ks < 2; ++ks) kb[ks] = (ks * 64 + g * 16) ^ ((lr & 7) << 4);

    auto stA = [&](int d, int h, int kt) {
        gll16(Ag + aoff + (long)h * 131072 + (long)kt * 64,
              (char*)&Asm[d][0] + h * 16384 + ldst);
        gll16(Ag + aoff + (long)h * 131072 + 65536 + (long)kt * 64,
              (char*)&Asm[d][0] + h * 16384 + 8192 + ldst);
    };
    auto stB = [&](int d, int h, int kt) {
        gll16(Btg + boff + (long)h * 131072 + (long)kt * 64,
              (char*)&Bsm[d][0] + h * 16384 + ldst);
        gll16(Btg + boff + (long)h * 131072 + 65536 + (long)kt * 64,
              (char*)&Bsm[d][0] + h * 16384 + 8192 + ldst);
    };
    auto rdA = [&](int d, int mi, int ks) {
        return *(const bf16x8*)((const char*)&Asm[d][0] + (wm * 128 + mi * 16 + lr) * 128 + kb[ks]);
    };
    auto rdB = [&](int d, int ni, int ks) {
        return *(const bf16x8*)((const char*)&Bsm[d][0] + (wn * 64 + ni * 16 + lr) * 128 + kb[ks]);
    };

    f32x4 acc[8][4];
#pragma unroll
    for (int i = 0; i < 8; ++i)
#pragma unroll
        for (int j = 0; j < 4; ++j) acc[i][j] = f32x4{0.f, 0.f, 0.f, 0.f};

    // ---- prologue: stage B(0), A(0), B(1); verify kt0 (newest 2 halves in flight)
    stB(0, 0, 0); stB(0, 1, 0);
    stA(0, 0, 0); stA(0, 1, 0);
    stB(1, 0, 1); stB(1, 1, 1);
    asm volatile("s_waitcnt vmcnt(4)" ::: "memory");
    bar();

    // K-tile body. vm: 0 -> vmcnt(4), 1 -> vmcnt(0), 2 -> none
    auto ktile = [&](int d, int ktA, int ktB, bool doA, bool doB, int vm) {
        bf16x8 af[4][2], bfr[4][2];
        // ---- phase 0 ----
#pragma unroll
        for (int mi = 0; mi < 4; ++mi) {
            af[mi][0] = rdA(d, mi, 0);
            af[mi][1] = rdA(d, mi, 1);
        }
#pragma unroll
        for (int ni = 0; ni < 2; ++ni) {
            bfr[ni][0] = rdB(d, ni, 0);
            bfr[ni][1] = rdB(d, ni, 1);
        }
        if (doA) stA(d ^ 1, 0, ktA);
        bar();
        __builtin_amdgcn_s_setprio(1);
#pragma unroll
        for (int mi = 0; mi < 4; ++mi)
#pragma unroll
            for (int ni = 0; ni < 2; ++ni) {
                acc[mi][ni] = __builtin_amdgcn_mfma_f32_16x16x32_bf16(af[mi][0], bfr[ni][0], acc[mi][ni], 0, 0, 0);
                acc[mi][ni] = __builtin_amdgcn_mfma_f32_16x16x32_bf16(af[mi][1], bfr[ni][1], acc[mi][ni], 0, 0, 0);
            }
        __builtin_amdgcn_s_setprio(0);
        bar();
        // ---- phase 1 ----
#pragma unroll
        for (int ni = 2; ni < 4; ++ni) {
            bfr[ni][0] = rdB(d, ni, 0);
            bfr[ni][1] = rdB(d, ni, 1);
        }
        if (doA) stA(d ^ 1, 1, ktA);
        bar();
        __builtin_amdgcn_s_setprio(1);
#pragma unroll
        for (int mi = 0; mi < 4; ++mi)
#pragma unroll
            for (int ni = 2; ni < 4; ++ni) {
                acc[mi][ni] = __builtin_amdgcn_mfma_f32_16x16x32_bf16(af[mi][0], bfr[ni][0], acc[mi][ni], 0, 0, 0);
                acc[mi][ni] = __builtin_amdgcn_mfma_f32_16x16x32_bf16(af[mi][1], bfr[ni][1], acc[mi][ni], 0, 0, 0);
            }
        __builtin_amdgcn_s_setprio(0);
        bar();
        // ---- phase 2 ----
#pragma unroll
        for (int mi = 0; mi < 4; ++mi) {
            af[mi][0] = rdA(d, mi + 4, 0);
            af[mi][1] = rdA(d, mi + 4, 1);
        }
        if (doB) stB(d, 0, ktB);
        bar();
        __builtin_amdgcn_s_setprio(1);
#pragma unroll
        for (int mi = 0; mi < 4; ++mi)
#pragma unroll
            for (int ni = 0; ni < 2; ++ni) {
                acc[mi + 4][ni] = __builtin_amdgcn_mfma_f32_16x16x32_bf16(af[mi][0], bfr[ni][0], acc[mi + 4][ni], 0, 0, 0);
                acc[mi + 4][ni] = __builtin_amdgcn_mfma_f32_16x16x32_bf16(af[mi][1], bfr[ni][1], acc[mi + 4][ni], 0, 0, 0);
            }
        __builtin_amdgcn_s_setprio(0);
        bar();
        // ---- phase 3 ----
        if (doB) stB(d, 1, ktB);
        bar();
        __builtin_amdgcn_s_setprio(1);
#pragma unroll
        for (int mi = 0; mi < 4; ++mi)
#pragma unroll
            for (int ni = 2; ni < 4; ++ni) {
                acc[mi + 4][ni] = __builtin_amdgcn_mfma_f32_16x16x32_bf16(af[mi][0], bfr[ni][0], acc[mi + 4][ni], 0, 0, 0);
                acc[mi + 4][ni] = __builtin_amdgcn_mfma_f32_16x16x32_bf16(af[mi][1], bfr[ni][1], acc[mi + 4][ni], 0, 0, 0);
            }
        __builtin_amdgcn_s_setprio(0);
        if (vm == 0)      asm volatile("s_waitcnt vmcnt(4)" ::: "memory");
        else if (vm == 1) asm volatile("s_waitcnt vmcnt(0)" ::: "memory");
        bar();
    };

    // ---- main loop: K-tiles 0..13 ----
    for (int c = 0; c < 14; c += 2) {
        ktile(0, c + 1, c + 2, true, true, 0);
        ktile(1, c + 2, c + 3, true, true, 0);
    }
    // ---- tail: kt14 (stage A(15) only, drain), kt15 (no staging) ----
    ktile(0, 15, 16, true, false, 1);
    ktile(1, 16, 17, false, false, 2);

    // ---- epilogue: C-write with q/k/v split select ----
    const int wsel = (int)(nBase >> 10);
    u16* Cw = C0 + (long)wsel * (4096l * 1024);
    const long ncl = (nBase & 1023) + wn * 64;
    const long rbase = mBase + wm * 128;
#pragma unroll
    for (int mi = 0; mi < 8; ++mi)
#pragma unroll
        for (int r = 0; r < 4; ++r) {
            const long row = rbase + mi * 16 + g * 4 + r;
#pragma unroll
            for (int ni = 0; ni < 4; ++ni)
                Cw[row * 1024 + ncl + ni * 16 + lr] = f2bf(acc[mi][ni][r]);
        }
}

// ---------------- output-proj GEMM, BM=64 (2 blocks/CU) --------------------

__global__ __launch_bounds__(256, 2) void gemm_out(
    const u16* __restrict__ A, const u16* __restrict__ Bt,
    float* __restrict__ Cf, const float* __restrict__ bias)
{
    constexpr int K = 1024, N = 1024;
    __shared__ u16 As[2][64 * 32];
    __shared__ u16 Bs[2][128 * 32];
    const int tid = threadIdx.x;
    const int wave = tid >> 6, lane = tid & 63;
    const int wr = wave >> 1, wc = wave & 1;
    const int g = lane >> 4, lr = lane & 15;
    const long mBase = (long)blockIdx.y * 64;
    const long nBase = (long)blockIdx.x * 128;

    f32x4 acc[2][4];
#pragma unroll
    for (int i = 0; i < 2; ++i)
#pragma unroll
        for (int j = 0; j < 4; ++j) acc[i][j] = f32x4{0.f, 0.f, 0.f, 0.f};

    const int oA = tid * 16;
    const int rA = oA >> 6, cbA = oA & 63;
    const int o0 = tid * 16, o1 = (256 + tid) * 16;
    const int r0 = o0 >> 6, cb0 = o0 & 63;
    const int r1 = o1 >> 6, cb1 = o1 & 63;

    gll16(A  + (mBase + rA) * K + (cbA >> 1), (char*)&As[0][0] + oA);
    gll16(Bt + (nBase + r0) * K + (cb0 >> 1), (char*)&Bs[0][0] + o0);
    gll16(Bt + (nBase + r1) * K + (cb1 >> 1), (char*)&Bs[0][0] + o1);
    __syncthreads();

#pragma unroll 2
    for (int kt = 0; kt < 32; ++kt) {
        const int buf = kt & 1;
        if (kt + 1 < 32) {
            const long ko = (long)(kt + 1) * 32;
            gll16(A  + (mBase + rA) * K + ko + (cbA >> 1), (char*)&As[buf ^ 1][0] + oA);
            gll16(Bt + (nBase + r0) * K + ko + (cb0 >> 1), (char*)&Bs[buf ^ 1][0] + o0);
            gll16(Bt + (nBase + r1) * K + ko + (cb1 >> 1), (char*)&Bs[buf ^ 1][0] + o1);
        }
        bf16x8 af[2], bfv[4];
#pragma unroll
        for (int mi = 0; mi < 2; ++mi)
            af[mi] = *(const bf16x8*)((const char*)&As[buf][0] + (wr * 32 + mi * 16 + lr) * 64 + g * 16);
#pragma unroll
        for (int ni = 0; ni < 4; ++ni)
            bfv[ni] = *(const bf16x8*)((const char*)&Bs[buf][0] + (wc * 64 + ni * 16 + lr) * 64 + g * 16);
#pragma unroll
        for (int mi = 0; mi < 2; ++mi)
#pragma unroll
            for (int ni = 0; ni < 4; ++ni)
                acc[mi][ni] = __builtin_amdgcn_mfma_f32_16x16x32_bf16(af[mi], bfv[ni], acc[mi][ni], 0, 0, 0);
        __syncthreads();
    }

#pragma unroll
    for (int mi = 0; mi < 2; ++mi)
#pragma unroll
        for (int r = 0; r < 4; ++r) {
            const long row = mBase + wr * 32 + mi * 16 + g * 4 + r;
#pragma unroll
            for (int ni = 0; ni < 4; ++ni) {
                const long col = nBase + wc * 64 + ni * 16 + lr;
                Cf[row * N + col] = acc[mi][ni][r] + bias[col];
            }
        }
}

// ---------------- flash attention (QBLK=256, 8 waves) -----------------------

__global__ __launch_bounds__(512, 2) void attn_fwd(
    const u16* __restrict__ Qg_, const u16* __restrict__ Kg_, const u16* __restrict__ Vtg_,
    const u32* __restrict__ maskp, u16* __restrict__ Og_)
{
    __shared__ u16 Ks[2][2][64 * 64];
    __shared__ u16 Vs[2][2][64 * 64];

    const int tid = threadIdx.x, w = tid >> 6, lane = tid & 63;
    const int g = lane >> 4, lr = lane & 15;
    const int L = blockIdx.x;
    const int slot = L >> 3;
    const int grp = (L & 7) + 8 * (slot >> 3);
    const int q0 = (slot & 7) * 256;
    const int b = grp >> 4, h = grp & 15;
    const u16* Qg = Qg_ + ((long)b * 2048) * 1024 + h * 64;
    const u16* Kg = Kg_ + ((long)b * 2048) * 1024 + h * 64;
    const u16* Vtg = Vtg_ + ((long)grp * 64) * 2048;
    u16* Og = Og_ + ((long)b * 2048) * 1024 + h * 64;

    const int ldso = tid * 16;
    const int m = ldso >> 7, cb = ldso & 127;
    const int sb = cb ^ ((m & 7) << 4);
    const int kap = ((m >> 4) & 1) * 32 + ((m >> 2) & 3) * 8 + ((m >> 5) & 1) * 4 + (m & 3);
    const long ksrc = (long)kap * 1024 + (sb >> 1);
    const long vsrc = (long)m * 2048 + (sb >> 1);

    bf16x8 qf[2][2];
#pragma unroll
    for (int nq = 0; nq < 2; ++nq)
#pragma unroll
        for (int ks = 0; ks < 2; ++ks)
            qf[nq][ks] = *(const bf16x8*)(Qg + (long)(q0 + w * 32 + nq * 16 + lr) * 1024 + ks * 32 + g * 8);

    const long mrow0 = (long)b * 2048 + q0 + w * 32 + lr;
    const u32* mpr0 = maskp + mrow0 * 64;
    const u32* mpr1 = maskp + (mrow0 + 16) * 64;

    u32x4 mwC0 = *(const u32x4*)(mpr0);
    u32x4 mwC1 = *(const u32x4*)(mpr1);
#pragma unroll
    for (int hh = 0; hh < 2; ++hh) {
        gll16(Kg + hh * 65536 + ksrc, (char*)&Ks[0][hh][0] + ldso);
        gll16(Vtg + hh * 64 + vsrc, (char*)&Vs[0][hh][0] + ldso);
    }
    __syncthreads();

    const int swz = (lr & 7) << 4;
    int kb[2];
#pragma unroll
    for (int ks = 0; ks < 2; ++ks) kb[ks] = (ks * 64 + g * 16) ^ swz;

    f32x4 oacc[2][4];
#pragma unroll
    for (int i = 0; i < 2; ++i)
#pragma unroll
        for (int j = 0; j < 4; ++j) oacc[i][j] = f32x4{0.f, 0.f, 0.f, 0.f};
    f32x4 osum[2];
    osum[0] = f32x4{0.f, 0.f, 0.f, 0.f};
    osum[1] = f32x4{0.f, 0.f, 0.f, 0.f};
    const f32x4 z4 = {0.f, 0.f, 0.f, 0.f};
    const u32x4 ones4 = {0x3F803F80u, 0x3F803F80u, 0x3F803F80u, 0x3F803F80u};
    const bf16x8 ones8 = __builtin_bit_cast(bf16x8, ones4);

#pragma unroll 2
    for (int t = 0; t < 16; ++t) {
        const int cur = t & 1;
        u32x4 mwN0, mwN1;
        if (t + 1 < 16) {
            mwN0 = *(const u32x4*)(mpr0 + (t + 1) * 4);
            mwN1 = *(const u32x4*)(mpr1 + (t + 1) * 4);
            const long kv0 = (long)(t + 1) * 128;
#pragma unroll
            for (int hh = 0; hh < 2; ++hh) {
                gll16(Kg + (kv0 + hh * 64) * 1024 + ksrc, (char*)&Ks[cur ^ 1][hh][0] + ldso);
                gll16(Vtg + kv0 + hh * 64 + vsrc, (char*)&Vs[cur ^ 1][hh][0] + ldso);
            }
        }

#pragma unroll
        for (int hh = 0; hh < 2; ++hh) {
            const char* kbase = (const char*)&Ks[cur][hh][0];
            const char* vbase = (const char*)&Vs[cur][hh][0];

            f32x4 s[4][2];
            __builtin_amdgcn_s_setprio(1);
#pragma unroll
            for (int mt = 0; mt < 4; ++mt) {
                const bf16x8 kf0 = *(const bf16x8*)(kbase + (mt * 16 + lr) * 128 + kb[0]);
                const bf16x8 kf1 = *(const bf16x8*)(kbase + (mt * 16 + lr) * 128 + kb[1]);
#pragma unroll
                for (int nq = 0; nq < 2; ++nq) {
                    s[mt][nq] = __builtin_amdgcn_mfma_f32_16x16x32_bf16(kf0, qf[nq][0], z4, 0, 0, 0);
                    s[mt][nq] = __builtin_amdgcn_mfma_f32_16x16x32_bf16(kf1, qf[nq][1], s[mt][nq], 0, 0, 0);
                }
            }
            __builtin_amdgcn_s_setprio(0);

            u32 pk[4][2][2];
#pragma unroll
            for (int ts = 0; ts < 4; ++ts) {
                const int sh = g * 8 + (ts >> 1) * 4;
                const int wi = hh * 2 + (ts & 1);
#pragma unroll
                for (int nq = 0; nq < 2; ++nq) {
                    const u32 word = nq ? mwC1[wi] : mwC0[wi];
                    const u32 iwsh = (~word) >> sh;
                    float e[4];
#pragma unroll
                    for (int r = 0; r < 4; ++r) {
                        const float ev = fexp2(s[ts][nq][r]);
                        const u32 keep = (u32)__builtin_amdgcn_sbfe((int)iwsh, (u32)r, 1u);
                        e[r] = __builtin_bit_cast(float, __builtin_bit_cast(u32, ev) & keep);
                    }
                    pk[ts][nq][0] = cvtpk_bf16(e[0], e[1]);
                    pk[ts][nq][1] = cvtpk_bf16(e[2], e[3]);
                }
            }

            bf16x8 pa[2][2];
#pragma unroll
            for (int nq = 0; nq < 2; ++nq)
#pragma unroll
                for (int ks = 0; ks < 2; ++ks) {
                    u32x4 t4;
                    t4[0] = pk[ks][nq][0]; t4[1] = pk[ks][nq][1];
                    t4[2] = pk[ks + 2][nq][0]; t4[3] = pk[ks + 2][nq][1];
                    pa[nq][ks] = __builtin_bit_cast(bf16x8, t4);
                }
            __builtin_amdgcn_s_setprio(1);
#pragma unroll
            for (int nq = 0; nq < 2; ++nq)
#pragma unroll
                for (int ks = 0; ks < 2; ++ks)
                    osum[nq] = __builtin_amdgcn_mfma_f32_16x16x32_bf16(pa[nq][ks], ones8, osum[nq], 0, 0, 0);
#pragma unroll
            for (int dt = 0; dt < 4; ++dt)
#pragma unroll
                for (int ks = 0; ks < 2; ++ks) {
                    const bf16x8 vf = *(const bf16x8*)(vbase + (dt * 16 + lr) * 128 + kb[ks]);
#pragma unroll
                    for (int nq = 0; nq < 2; ++nq)
                        oacc[nq][dt] = __builtin_amdgcn_mfma_f32_16x16x32_bf16(pa[nq][ks], vf, oacc[nq][dt], 0, 0, 0);
                }
            __builtin_amdgcn_s_setprio(0);
        }
        __syncthreads();

        mwC0 = mwN0; mwC1 = mwN1;
    }

#pragma unroll
    for (int nq = 0; nq < 2; ++nq)
#pragma unroll
        for (int rr = 0; rr < 4; ++rr) {
            const float inv = __builtin_amdgcn_rcpf(osum[nq][rr]);
            const long row = (long)q0 + w * 32 + nq * 16 + g * 4 + rr;
#pragma unroll
            for (int dt = 0; dt < 4; ++dt)
                Og[row * 1024 + dt * 16 + lr] = f2bf(oacc[nq][dt][rr] * inv);
        }
}

// ---------------- launcher ----------------

extern "C" void kernel_launch(void* const* d_in, const int* in_sizes, int n_in,
                              void* d_out, int out_size, void* d_ws, size_t ws_size,
                              hipStream_t stream)
{
    (void)in_sizes; (void)n_in; (void)out_size; (void)ws_size;
    const float* x    = (const float*)d_in[0];
    const int*   mask = (const int*)d_in[1];
    const float* Wq   = (const float*)d_in[2];
    const float* Wk   = (const float*)d_in[3];
    const float* Wv   = (const float*)d_in[4];
    const float* Wo   = (const float*)d_in[5];
    const float* bo   = (const float*)d_in[6];
    float* out = (float*)d_out;

    char* ws = (char*)d_ws;
    u16* xb    = (u16*)(ws);                 // 8 MB  x as bf16 (dead after gemm_qkv)
    u16* vtws  = (u16*)(ws);                 // 8 MB  V^T, reuses xb region
    u16* WqT   = (u16*)(ws + (8l  << 20));   // 2 MB each, transposed bf16 (q,k,v contiguous)
    u16* WkT   = (u16*)(ws + (10l << 20));
    u16* WvT   = (u16*)(ws + (12l << 20));
    u16* WoT   = (u16*)(ws + (14l << 20));
    u16* qws   = (u16*)(ws + (16l << 20));   // 8 MB each (q,k,v contiguous)
    u16* kws   = (u16*)(ws + (24l << 20));
    u16* vws   = (u16*)(ws + (32l << 20));
    u16* inner = (u16*)(ws + (40l << 20));   // 8 MB
    u32* mp    = (u32*)(ws + (48l << 20));   // 1 MB packed mask

    prep_k<<<4096, 256, 0, stream>>>(x, xb, Wq, Wk, Wv, Wo, WqT, WkT, WvT, WoT, mask, mp);
    gemm_qkv<<<192, 512, 0, stream>>>(xb, WqT, qws);
    vt_k<<<dim3(32, 16, 2), 256, 0, stream>>>(vws, vtws);
    attn_fwd<<<256, 512, 0, stream>>>(qws, kws, vtws, mp, inner);
    gemm_out<<<dim3(8, 64), 256, 0, stream>>>(inner, WoT, out, bo);
}

// Round 12
// 124.731 us; speedup vs baseline: 1.3538x; 1.0288x over previous
//
#include <hip/hip_runtime.h>
#include <cstdint>
#include <cstddef>

typedef float    f32x4  __attribute__((ext_vector_type(4)));
typedef __bf16   bf16x8 __attribute__((ext_vector_type(8)));
typedef unsigned u32x4  __attribute__((ext_vector_type(4)));
typedef unsigned u32x2  __attribute__((ext_vector_type(2)));
typedef unsigned short u16;
typedef unsigned int   u32;

#define SCL2E 0.18033688011112042f   /* 0.125 * log2(e), folded into Wq */

static __device__ __forceinline__ u16 f2bf(float f) {
    u32 u = __builtin_bit_cast(u32, f);
    u32 r = (u + 0x7FFFu + ((u >> 16) & 1u)) >> 16;
    return (u16)r;
}

static __device__ __forceinline__ u32 cvtpk_bf16(float lo, float hi) {
    u32 r;
    asm("v_cvt_pk_bf16_f32 %0, %1, %2" : "=v"(r) : "v"(lo), "v"(hi));
    return r;
}

// raw hardware exp2 — avoids llvm.exp2's denormal-fixup expansion (~6 VALU).
static __device__ __forceinline__ float fexp2(float x) {
    float r;
    asm("v_exp_f32 %0, %1" : "=v"(r) : "v"(x));
    return r;
}

static __device__ __forceinline__ void gll16(const u16* g, void* l) {
    __builtin_amdgcn_global_load_lds((const __attribute__((address_space(1))) void*)g,
                                     (__attribute__((address_space(3))) void*)l, 16, 0, 0);
}

static __device__ __forceinline__ void bar() {
    asm volatile("s_barrier" ::: "memory");
}

// ---------------- fused prep kernel ----------------

__global__ __launch_bounds__(256) void prep_k(
    const float* __restrict__ x, u16* __restrict__ xb,
    const float* __restrict__ W0, const float* __restrict__ W1,
    const float* __restrict__ W2, const float* __restrict__ W3,
    u16* __restrict__ T0, u16* __restrict__ T1,
    u16* __restrict__ T2, u16* __restrict__ T3,
    const int* __restrict__ mask, u32* __restrict__ mp)
{
    __shared__ float T[64][65];
    const int bid = blockIdx.x;
    if (bid < 2048) {
        const long i = ((long)bid * 256 + threadIdx.x) * 8;
        f32x4 a = *(const f32x4*)(x + i);
        f32x4 c = *(const f32x4*)(x + i + 4);
        u32x4 o;
        o[0] = (u32)f2bf(a[0]) | ((u32)f2bf(a[1]) << 16);
        o[1] = (u32)f2bf(a[2]) | ((u32)f2bf(a[3]) << 16);
        o[2] = (u32)f2bf(c[0]) | ((u32)f2bf(c[1]) << 16);
        o[3] = (u32)f2bf(c[2]) | ((u32)f2bf(c[3]) << 16);
        *(u32x4*)(xb + i) = o;
    } else if (bid < 3072) {
        const int idx = bid - 2048;
        const int z = idx >> 8, rem = idx & 255;
        const int n0 = (rem & 15) * 64, k0 = (rem >> 4) * 64;
        const float* W = (z == 0) ? W0 : (z == 1) ? W1 : (z == 2) ? W2 : W3;
        u16* Wt = (z == 0) ? T0 : (z == 1) ? T1 : (z == 2) ? T2 : T3;
        const float scl = (z == 0) ? SCL2E : 1.0f;
        const int c = threadIdx.x & 63, r0 = (threadIdx.x >> 6) * 16;
#pragma unroll
        for (int i = 0; i < 16; ++i)
            T[r0 + i][c] = W[(long)(k0 + r0 + i) * 1024 + n0 + c];
        __syncthreads();
#pragma unroll
        for (int i = 0; i < 16; ++i)
            Wt[(long)(n0 + r0 + i) * 1024 + k0 + c] = f2bf(T[c][r0 + i] * scl);
    } else {
        const long wi = (long)(bid - 3072) * 256 + threadIdx.x;
        const int* src = mask + wi * 32;
        u32 word = 0;
#pragma unroll
        for (int c = 0; c < 8; ++c) {
            const int4 v = *(const int4*)(src + c * 4);
            word |= (u32)(v.x != 0) << (c * 4);
            word |= (u32)(v.y != 0) << (c * 4 + 1);
            word |= (u32)(v.z != 0) << (c * 4 + 2);
            word |= (u32)(v.w != 0) << (c * 4 + 3);
        }
        mp[wi] = word;
    }
}

// ---------------- QKV GEMM, 256x256 tile, 8-phase counted-vmcnt ------------
// [4096x1024] @ [1024x3072]. 192 blocks, 512 thr (8 waves 2Mx4N). BK=64,
// 2 LDS dbuf (128KB). Schedule as r11 (refcheck-verified).
// V-blocks (nBase>=2048): A-slot<-WvT panel, B-slot<-X panel (pointer swap
// only) so the identical pipeline computes V^T = Wv^T X; epilogue writes
// V^T [1024 hd][4096 tok] coalesced. Kills the separate vt_k pass.

__global__ __launch_bounds__(512, 2) void gemm_qkv(
    const u16* __restrict__ Ag, const u16* __restrict__ Btg,
    u16* __restrict__ C0, u16* __restrict__ Vt)
{
    __shared__ u16 Asm[2][256 * 64];
    __shared__ u16 Bsm[2][256 * 64];

    const int tid = threadIdx.x, lane = tid & 63, w = tid >> 6;
    const int wm = w >> 2, wn = w & 3;
    const int g = lane >> 4, lr = lane & 15;

    const int L = blockIdx.x;
    const int xcd = L & 7, idx = L >> 3;
    const long mBase = (long)((xcd & 3) * 4 + (idx & 3)) * 256;
    const long nBase = (long)((xcd >> 2) * 6 + (idx >> 2)) * 256;
    const bool vblk = (nBase >= 2048);

    const int srow = tid >> 3;
    const int scolb = ((tid & 7) << 4) ^ ((srow & 7) << 4);
    const long aoff = (mBase + srow) * 1024 + (scolb >> 1);
    const long boff = (nBase + srow) * 1024 + (scolb >> 1);
    const int ldst = tid * 16;

    // V-blocks: swap which matrix feeds which LDS slot (transposed output).
    const u16* AsrcP = vblk ? Btg : Ag;
    const u16* BsrcP = vblk ? Ag  : Btg;
    const long aoffE = vblk ? boff : aoff;
    const long boffE = vblk ? aoff : boff;

    int kb[2];
#pragma unroll
    for (int ks = 0; ks < 2; ++ks) kb[ks] = (ks * 64 + g * 16) ^ ((lr & 7) << 4);

    auto stA = [&](int d, int h, int kt) {
        gll16(AsrcP + aoffE + (long)h * 131072 + (long)kt * 64,
              (char*)&Asm[d][0] + h * 16384 + ldst);
        gll16(AsrcP + aoffE + (long)h * 131072 + 65536 + (long)kt * 64,
              (char*)&Asm[d][0] + h * 16384 + 8192 + ldst);
    };
    auto stB = [&](int d, int h, int kt) {
        gll16(BsrcP + boffE + (long)h * 131072 + (long)kt * 64,
              (char*)&Bsm[d][0] + h * 16384 + ldst);
        gll16(BsrcP + boffE + (long)h * 131072 + 65536 + (long)kt * 64,
              (char*)&Bsm[d][0] + h * 16384 + 8192 + ldst);
    };
    auto rdA = [&](int d, int mi, int ks) {
        return *(const bf16x8*)((const char*)&Asm[d][0] + (wm * 128 + mi * 16 + lr) * 128 + kb[ks]);
    };
    auto rdB = [&](int d, int ni, int ks) {
        return *(const bf16x8*)((const char*)&Bsm[d][0] + (wn * 64 + ni * 16 + lr) * 128 + kb[ks]);
    };

    f32x4 acc[8][4];
#pragma unroll
    for (int i = 0; i < 8; ++i)
#pragma unroll
        for (int j = 0; j < 4; ++j) acc[i][j] = f32x4{0.f, 0.f, 0.f, 0.f};

    // ---- prologue
    stB(0, 0, 0); stB(0, 1, 0);
    stA(0, 0, 0); stA(0, 1, 0);
    stB(1, 0, 1); stB(1, 1, 1);
    asm volatile("s_waitcnt vmcnt(4)" ::: "memory");
    bar();

    auto ktile = [&](int d, int ktA, int ktB, bool doA, bool doB, int vm) {
        bf16x8 af[4][2], bfr[4][2];
        // ---- phase 0 ----
#pragma unroll
        for (int mi = 0; mi < 4; ++mi) {
            af[mi][0] = rdA(d, mi, 0);
            af[mi][1] = rdA(d, mi, 1);
        }
#pragma unroll
        for (int ni = 0; ni < 2; ++ni) {
            bfr[ni][0] = rdB(d, ni, 0);
            bfr[ni][1] = rdB(d, ni, 1);
        }
        if (doA) stA(d ^ 1, 0, ktA);
        bar();
        __builtin_amdgcn_s_setprio(1);
#pragma unroll
        for (int mi = 0; mi < 4; ++mi)
#pragma unroll
            for (int ni = 0; ni < 2; ++ni) {
                acc[mi][ni] = __builtin_amdgcn_mfma_f32_16x16x32_bf16(af[mi][0], bfr[ni][0], acc[mi][ni], 0, 0, 0);
                acc[mi][ni] = __builtin_amdgcn_mfma_f32_16x16x32_bf16(af[mi][1], bfr[ni][1], acc[mi][ni], 0, 0, 0);
            }
        __builtin_amdgcn_s_setprio(0);
        bar();
        // ---- phase 1 ----
#pragma unroll
        for (int ni = 2; ni < 4; ++ni) {
            bfr[ni][0] = rdB(d, ni, 0);
            bfr[ni][1] = rdB(d, ni, 1);
        }
        if (doA) stA(d ^ 1, 1, ktA);
        bar();
        __builtin_amdgcn_s_setprio(1);
#pragma unroll
        for (int mi = 0; mi < 4; ++mi)
#pragma unroll
            for (int ni = 2; ni < 4; ++ni) {
                acc[mi][ni] = __builtin_amdgcn_mfma_f32_16x16x32_bf16(af[mi][0], bfr[ni][0], acc[mi][ni], 0, 0, 0);
                acc[mi][ni] = __builtin_amdgcn_mfma_f32_16x16x32_bf16(af[mi][1], bfr[ni][1], acc[mi][ni], 0, 0, 0);
            }
        __builtin_amdgcn_s_setprio(0);
        bar();
        // ---- phase 2 ----
#pragma unroll
        for (int mi = 0; mi < 4; ++mi) {
            af[mi][0] = rdA(d, mi + 4, 0);
            af[mi][1] = rdA(d, mi + 4, 1);
        }
        if (doB) stB(d, 0, ktB);
        bar();
        __builtin_amdgcn_s_setprio(1);
#pragma unroll
        for (int mi = 0; mi < 4; ++mi)
#pragma unroll
            for (int ni = 0; ni < 2; ++ni) {
                acc[mi + 4][ni] = __builtin_amdgcn_mfma_f32_16x16x32_bf16(af[mi][0], bfr[ni][0], acc[mi + 4][ni], 0, 0, 0);
                acc[mi + 4][ni] = __builtin_amdgcn_mfma_f32_16x16x32_bf16(af[mi][1], bfr[ni][1], acc[mi + 4][ni], 0, 0, 0);
            }
        __builtin_amdgcn_s_setprio(0);
        bar();
        // ---- phase 3 ----
        if (doB) stB(d, 1, ktB);
        bar();
        __builtin_amdgcn_s_setprio(1);
#pragma unroll
        for (int mi = 0; mi < 4; ++mi)
#pragma unroll
            for (int ni = 2; ni < 4; ++ni) {
                acc[mi + 4][ni] = __builtin_amdgcn_mfma_f32_16x16x32_bf16(af[mi][0], bfr[ni][0], acc[mi + 4][ni], 0, 0, 0);
                acc[mi + 4][ni] = __builtin_amdgcn_mfma_f32_16x16x32_bf16(af[mi][1], bfr[ni][1], acc[mi + 4][ni], 0, 0, 0);
            }
        __builtin_amdgcn_s_setprio(0);
        if (vm == 0)      asm volatile("s_waitcnt vmcnt(4)" ::: "memory");
        else if (vm == 1) asm volatile("s_waitcnt vmcnt(0)" ::: "memory");
        bar();
    };

    for (int c = 0; c < 14; c += 2) {
        ktile(0, c + 1, c + 2, true, true, 0);
        ktile(1, c + 2, c + 3, true, true, 0);
    }
    ktile(0, 15, 16, true, false, 1);
    ktile(1, 16, 17, false, false, 2);

    // ---- epilogue ----
    if (!vblk) {
        const int wsel = (int)(nBase >> 10);
        u16* Cw = C0 + (long)wsel * (4096l * 1024);
        const long ncl = (nBase & 1023) + wn * 64;
        const long rbase = mBase + wm * 128;
#pragma unroll
        for (int mi = 0; mi < 8; ++mi)
#pragma unroll
            for (int r = 0; r < 4; ++r) {
                const long row = rbase + mi * 16 + g * 4 + r;
#pragma unroll
                for (int ni = 0; ni < 4; ++ni)
                    Cw[row * 1024 + ncl + ni * 16 + lr] = f2bf(acc[mi][ni][r]);
            }
    } else {
        // acc rows = hd (V^T rows), cols = token. V^T [1024][4096].
        const long nb = nBase - 2048;
#pragma unroll
        for (int mi = 0; mi < 8; ++mi)
#pragma unroll
            for (int r = 0; r < 4; ++r) {
                const long rowN = nb + wm * 128 + mi * 16 + g * 4 + r;
#pragma unroll
                for (int ni = 0; ni < 4; ++ni) {
                    const long colT = mBase + wn * 64 + ni * 16 + lr;
                    Vt[rowN * 4096 + colT] = f2bf(acc[mi][ni][r]);
                }
            }
    }
}

// ---------------- output-proj GEMM, BM=64 (2 blocks/CU) --------------------

__global__ __launch_bounds__(256, 2) void gemm_out(
    const u16* __restrict__ A, const u16* __restrict__ Bt,
    float* __restrict__ Cf, const float* __restrict__ bias)
{
    constexpr int K = 1024, N = 1024;
    __shared__ u16 As[2][64 * 32];
    __shared__ u16 Bs[2][128 * 32];
    const int tid = threadIdx.x;
    const int wave = tid >> 6, lane = tid & 63;
    const int wr = wave >> 1, wc = wave & 1;
    const int g = lane >> 4, lr = lane & 15;
    const long mBase = (long)blockIdx.y * 64;
    const long nBase = (long)blockIdx.x * 128;

    f32x4 acc[2][4];
#pragma unroll
    for (int i = 0; i < 2; ++i)
#pragma unroll
        for (int j = 0; j < 4; ++j) acc[i][j] = f32x4{0.f, 0.f, 0.f, 0.f};

    const int oA = tid * 16;
    const int rA = oA >> 6, cbA = oA & 63;
    const int o0 = tid * 16, o1 = (256 + tid) * 16;
    const int r0 = o0 >> 6, cb0 = o0 & 63;
    const int r1 = o1 >> 6, cb1 = o1 & 63;

    gll16(A  + (mBase + rA) * K + (cbA >> 1), (char*)&As[0][0] + oA);
    gll16(Bt + (nBase + r0) * K + (cb0 >> 1), (char*)&Bs[0][0] + o0);
    gll16(Bt + (nBase + r1) * K + (cb1 >> 1), (char*)&Bs[0][0] + o1);
    __syncthreads();

#pragma unroll 2
    for (int kt = 0; kt < 32; ++kt) {
        const int buf = kt & 1;
        if (kt + 1 < 32) {
            const long ko = (long)(kt + 1) * 32;
            gll16(A  + (mBase + rA) * K + ko + (cbA >> 1), (char*)&As[buf ^ 1][0] + oA);
            gll16(Bt + (nBase + r0) * K + ko + (cb0 >> 1), (char*)&Bs[buf ^ 1][0] + o0);
            gll16(Bt + (nBase + r1) * K + ko + (cb1 >> 1), (char*)&Bs[buf ^ 1][0] + o1);
        }
        bf16x8 af[2], bfv[4];
#pragma unroll
        for (int mi = 0; mi < 2; ++mi)
            af[mi] = *(const bf16x8*)((const char*)&As[buf][0] + (wr * 32 + mi * 16 + lr) * 64 + g * 16);
#pragma unroll
        for (int ni = 0; ni < 4; ++ni)
            bfv[ni] = *(const bf16x8*)((const char*)&Bs[buf][0] + (wc * 64 + ni * 16 + lr) * 64 + g * 16);
#pragma unroll
        for (int mi = 0; mi < 2; ++mi)
#pragma unroll
            for (int ni = 0; ni < 4; ++ni)
                acc[mi][ni] = __builtin_amdgcn_mfma_f32_16x16x32_bf16(af[mi], bfv[ni], acc[mi][ni], 0, 0, 0);
        __syncthreads();
    }

#pragma unroll
    for (int mi = 0; mi < 2; ++mi)
#pragma unroll
        for (int r = 0; r < 4; ++r) {
            const long row = mBase + wr * 32 + mi * 16 + g * 4 + r;
#pragma unroll
            for (int ni = 0; ni < 4; ++ni) {
                const long col = nBase + wc * 64 + ni * 16 + lr;
                Cf[row * N + col] = acc[mi][ni][r] + bias[col];
            }
        }
}

// ---------------- flash attention (QBLK=256, 8 waves, QK-both-first) -------
// V^T now [1024 hd][4096 tok] (from gemm_qkv), row stride 4096.
// Per t-iter: QK(h0),QK(h1) MFMA first, then SM+PV per half — SM(h0)'s
// quarter-rate exp VALU overlaps QK(h1)'s in-flight MFMAs; SM(h1) overlaps
// PV(h0) (T15 mechanism, within-wave MFMA||VALU overlap at 2 waves/SIMD).

__global__ __launch_bounds__(512, 2) void attn_fwd(
    const u16* __restrict__ Qg_, const u16* __restrict__ Kg_, const u16* __restrict__ Vtg_,
    const u32* __restrict__ maskp, u16* __restrict__ Og_)
{
    __shared__ u16 Ks[2][2][64 * 64];
    __shared__ u16 Vs[2][2][64 * 64];

    const int tid = threadIdx.x, w = tid >> 6, lane = tid & 63;
    const int g = lane >> 4, lr = lane & 15;
    const int L = blockIdx.x;
    const int slot = L >> 3;
    const int grp = (L & 7) + 8 * (slot >> 3);
    const int q0 = (slot & 7) * 256;
    const int b = grp >> 4, h = grp & 15;
    const u16* Qg = Qg_ + ((long)b * 2048) * 1024 + h * 64;
    const u16* Kg = Kg_ + ((long)b * 2048) * 1024 + h * 64;
    const u16* Vtg = Vtg_ + (long)(h * 64) * 4096 + (long)b * 2048;
    u16* Og = Og_ + ((long)b * 2048) * 1024 + h * 64;

    const int ldso = tid * 16;
    const int m = ldso >> 7, cb = ldso & 127;
    const int sb = cb ^ ((m & 7) << 4);
    const int kap = ((m >> 4) & 1) * 32 + ((m >> 2) & 3) * 8 + ((m >> 5) & 1) * 4 + (m & 3);
    const long ksrc = (long)kap * 1024 + (sb >> 1);
    const long vsrc = (long)m * 4096 + (sb >> 1);

    bf16x8 qf[2][2];
#pragma unroll
    for (int nq = 0; nq < 2; ++nq)
#pragma unroll
        for (int ks = 0; ks < 2; ++ks)
            qf[nq][ks] = *(const bf16x8*)(Qg + (long)(q0 + w * 32 + nq * 16 + lr) * 1024 + ks * 32 + g * 8);

    const long mrow0 = (long)b * 2048 + q0 + w * 32 + lr;
    const u32* mpr0 = maskp + mrow0 * 64;
    const u32* mpr1 = maskp + (mrow0 + 16) * 64;

    u32x4 mwC0 = *(const u32x4*)(mpr0);
    u32x4 mwC1 = *(const u32x4*)(mpr1);
#pragma unroll
    for (int hh = 0; hh < 2; ++hh) {
        gll16(Kg + hh * 65536 + ksrc, (char*)&Ks[0][hh][0] + ldso);
        gll16(Vtg + hh * 64 + vsrc, (char*)&Vs[0][hh][0] + ldso);
    }
    __syncthreads();

    const int swz = (lr & 7) << 4;
    int kb[2];
#pragma unroll
    for (int ks = 0; ks < 2; ++ks) kb[ks] = (ks * 64 + g * 16) ^ swz;

    f32x4 oacc[2][4];
#pragma unroll
    for (int i = 0; i < 2; ++i)
#pragma unroll
        for (int j = 0; j < 4; ++j) oacc[i][j] = f32x4{0.f, 0.f, 0.f, 0.f};
    f32x4 osum[2];
    osum[0] = f32x4{0.f, 0.f, 0.f, 0.f};
    osum[1] = f32x4{0.f, 0.f, 0.f, 0.f};
    const f32x4 z4 = {0.f, 0.f, 0.f, 0.f};
    const u32x4 ones4 = {0x3F803F80u, 0x3F803F80u, 0x3F803F80u, 0x3F803F80u};
    const bf16x8 ones8 = __builtin_bit_cast(bf16x8, ones4);

#pragma unroll 2
    for (int t = 0; t < 16; ++t) {
        const int cur = t & 1;
        u32x4 mwN0, mwN1;
        if (t + 1 < 16) {
            mwN0 = *(const u32x4*)(mpr0 + (t + 1) * 4);
            mwN1 = *(const u32x4*)(mpr1 + (t + 1) * 4);
            const long kv0 = (long)(t + 1) * 128;
#pragma unroll
            for (int hh = 0; hh < 2; ++hh) {
                gll16(Kg + (kv0 + hh * 64) * 1024 + ksrc, (char*)&Ks[cur ^ 1][hh][0] + ldso);
                gll16(Vtg + kv0 + hh * 64 + vsrc, (char*)&Vs[cur ^ 1][hh][0] + ldso);
            }
        }

        // ---- QK^T for BOTH halves first ----
        f32x4 s2[2][4][2];
        __builtin_amdgcn_s_setprio(1);
#pragma unroll
        for (int hh = 0; hh < 2; ++hh) {
            const char* kbase = (const char*)&Ks[cur][hh][0];
#pragma unroll
            for (int mt = 0; mt < 4; ++mt) {
                const bf16x8 kf0 = *(const bf16x8*)(kbase + (mt * 16 + lr) * 128 + kb[0]);
                const bf16x8 kf1 = *(const bf16x8*)(kbase + (mt * 16 + lr) * 128 + kb[1]);
#pragma unroll
                for (int nq = 0; nq < 2; ++nq) {
                    s2[hh][mt][nq] = __builtin_amdgcn_mfma_f32_16x16x32_bf16(kf0, qf[nq][0], z4, 0, 0, 0);
                    s2[hh][mt][nq] = __builtin_amdgcn_mfma_f32_16x16x32_bf16(kf1, qf[nq][1], s2[hh][mt][nq], 0, 0, 0);
                }
            }
        }
        __builtin_amdgcn_s_setprio(0);

        // ---- SM + PV per half (SM(h1) overlaps PV(h0) MFMAs) ----
#pragma unroll
        for (int hh = 0; hh < 2; ++hh) {
            const char* vbase = (const char*)&Vs[cur][hh][0];

            u32 pk[4][2][2];
#pragma unroll
            for (int ts = 0; ts < 4; ++ts) {
                const int sh = g * 8 + (ts >> 1) * 4;
                const int wi = hh * 2 + (ts & 1);
#pragma unroll
                for (int nq = 0; nq < 2; ++nq) {
                    const u32 word = nq ? mwC1[wi] : mwC0[wi];
                    const u32 iwsh = (~word) >> sh;
                    float e[4];
#pragma unroll
                    for (int r = 0; r < 4; ++r) {
                        const float ev = fexp2(s2[hh][ts][nq][r]);
                        const u32 keep = (u32)__builtin_amdgcn_sbfe((int)iwsh, (u32)r, 1u);
                        e[r] = __builtin_bit_cast(float, __builtin_bit_cast(u32, ev) & keep);
                    }
                    pk[ts][nq][0] = cvtpk_bf16(e[0], e[1]);
                    pk[ts][nq][1] = cvtpk_bf16(e[2], e[3]);
                }
            }

            bf16x8 pa[2][2];
#pragma unroll
            for (int nq = 0; nq < 2; ++nq)
#pragma unroll
                for (int ks = 0; ks < 2; ++ks) {
                    u32x4 t4;
                    t4[0] = pk[ks][nq][0]; t4[1] = pk[ks][nq][1];
                    t4[2] = pk[ks + 2][nq][0]; t4[3] = pk[ks + 2][nq][1];
                    pa[nq][ks] = __builtin_bit_cast(bf16x8, t4);
                }
            __builtin_amdgcn_s_setprio(1);
#pragma unroll
            for (int nq = 0; nq < 2; ++nq)
#pragma unroll
                for (int ks = 0; ks < 2; ++ks)
                    osum[nq] = __builtin_amdgcn_mfma_f32_16x16x32_bf16(pa[nq][ks], ones8, osum[nq], 0, 0, 0);
#pragma unroll
            for (int dt = 0; dt < 4; ++dt)
#pragma unroll
                for (int ks = 0; ks < 2; ++ks) {
                    const bf16x8 vf = *(const bf16x8*)(vbase + (dt * 16 + lr) * 128 + kb[ks]);
#pragma unroll
                    for (int nq = 0; nq < 2; ++nq)
                        oacc[nq][dt] = __builtin_amdgcn_mfma_f32_16x16x32_bf16(pa[nq][ks], vf, oacc[nq][dt], 0, 0, 0);
                }
            __builtin_amdgcn_s_setprio(0);
        }
        __syncthreads();

        mwC0 = mwN0; mwC1 = mwN1;
    }

#pragma unroll
    for (int nq = 0; nq < 2; ++nq)
#pragma unroll
        for (int rr = 0; rr < 4; ++rr) {
            const float inv = __builtin_amdgcn_rcpf(osum[nq][rr]);
            const long row = (long)q0 + w * 32 + nq * 16 + g * 4 + rr;
#pragma unroll
            for (int dt = 0; dt < 4; ++dt)
                Og[row * 1024 + dt * 16 + lr] = f2bf(oacc[nq][dt][rr] * inv);
        }
}

// ---------------- launcher ----------------

extern "C" void kernel_launch(void* const* d_in, const int* in_sizes, int n_in,
                              void* d_out, int out_size, void* d_ws, size_t ws_size,
                              hipStream_t stream)
{
    (void)in_sizes; (void)n_in; (void)out_size; (void)ws_size;
    const float* x    = (const float*)d_in[0];
    const int*   mask = (const int*)d_in[1];
    const float* Wq   = (const float*)d_in[2];
    const float* Wk   = (const float*)d_in[3];
    const float* Wv   = (const float*)d_in[4];
    const float* Wo   = (const float*)d_in[5];
    const float* bo   = (const float*)d_in[6];
    float* out = (float*)d_out;

    char* ws = (char*)d_ws;
    u16* xb    = (u16*)(ws);                 // 8 MB  x as bf16
    u16* WqT   = (u16*)(ws + (8l  << 20));   // 2 MB each, transposed bf16 (q,k,v contiguous)
    u16* WkT   = (u16*)(ws + (10l << 20));
    u16* WvT   = (u16*)(ws + (12l << 20));
    u16* WoT   = (u16*)(ws + (14l << 20));
    u16* qws   = (u16*)(ws + (16l << 20));   // 8 MB each (q,k contiguous)
    u16* kws   = (u16*)(ws + (24l << 20));
    u16* vtws  = (u16*)(ws + (32l << 20));   // 8 MB  V^T [1024][4096] (from gemm_qkv)
    u16* inner = (u16*)(ws + (40l << 20));   // 8 MB
    u32* mp    = (u32*)(ws + (48l << 20));   // 1 MB packed mask

    prep_k<<<4096, 256, 0, stream>>>(x, xb, Wq, Wk, Wv, Wo, WqT, WkT, WvT, WoT, mask, mp);
    gemm_qkv<<<192, 512, 0, stream>>>(xb, WqT, qws, vtws);
    attn_fwd<<<256, 512, 0, stream>>>(qws, kws, vtws, mp, inner);
    gemm_out<<<dim3(8, 64), 256, 0, stream>>>(inner, WoT, out, bo);
    (void)kws;
}

// Round 13
// 121.610 us; speedup vs baseline: 1.3886x; 1.0257x over previous
//
#include <hip/hip_runtime.h>
#include <cstdint>
#include <cstddef>

typedef float    f32x4  __attribute__((ext_vector_type(4)));
typedef __bf16   bf16x8 __attribute__((ext_vector_type(8)));
typedef unsigned u32x4  __attribute__((ext_vector_type(4)));
typedef unsigned u32x2  __attribute__((ext_vector_type(2)));
typedef unsigned short u16;
typedef unsigned int   u32;

#define SCL2E 0.18033688011112042f   /* 0.125 * log2(e), folded into Wq */

static __device__ __forceinline__ u16 f2bf(float f) {
    u32 u = __builtin_bit_cast(u32, f);
    u32 r = (u + 0x7FFFu + ((u >> 16) & 1u)) >> 16;
    return (u16)r;
}

static __device__ __forceinline__ u32 cvtpk_bf16(float lo, float hi) {
    u32 r;
    asm("v_cvt_pk_bf16_f32 %0, %1, %2" : "=v"(r) : "v"(lo), "v"(hi));
    return r;
}

// raw hardware exp2 — avoids llvm.exp2's denormal-fixup expansion (~6 VALU).
static __device__ __forceinline__ float fexp2(float x) {
    float r;
    asm("v_exp_f32 %0, %1" : "=v"(r) : "v"(x));
    return r;
}

static __device__ __forceinline__ void gll16(const u16* g, void* l) {
    __builtin_amdgcn_global_load_lds((const __attribute__((address_space(1))) void*)g,
                                     (__attribute__((address_space(3))) void*)l, 16, 0, 0);
}

static __device__ __forceinline__ void bar() {
    asm volatile("s_barrier" ::: "memory");
}

// ---------------- fused prep kernel ----------------

__global__ __launch_bounds__(256) void prep_k(
    const float* __restrict__ x, u16* __restrict__ xb,
    const float* __restrict__ W0, const float* __restrict__ W1,
    const float* __restrict__ W2, const float* __restrict__ W3,
    u16* __restrict__ T0, u16* __restrict__ T1,
    u16* __restrict__ T2, u16* __restrict__ T3,
    const int* __restrict__ mask, u32* __restrict__ mp)
{
    __shared__ float T[64][65];
    const int bid = blockIdx.x;
    if (bid < 2048) {
        const long i = ((long)bid * 256 + threadIdx.x) * 8;
        f32x4 a = *(const f32x4*)(x + i);
        f32x4 c = *(const f32x4*)(x + i + 4);
        u32x4 o;
        o[0] = (u32)f2bf(a[0]) | ((u32)f2bf(a[1]) << 16);
        o[1] = (u32)f2bf(a[2]) | ((u32)f2bf(a[3]) << 16);
        o[2] = (u32)f2bf(c[0]) | ((u32)f2bf(c[1]) << 16);
        o[3] = (u32)f2bf(c[2]) | ((u32)f2bf(c[3]) << 16);
        *(u32x4*)(xb + i) = o;
    } else if (bid < 3072) {
        const int idx = bid - 2048;
        const int z = idx >> 8, rem = idx & 255;
        const int n0 = (rem & 15) * 64, k0 = (rem >> 4) * 64;
        const float* W = (z == 0) ? W0 : (z == 1) ? W1 : (z == 2) ? W2 : W3;
        u16* Wt = (z == 0) ? T0 : (z == 1) ? T1 : (z == 2) ? T2 : T3;
        const float scl = (z == 0) ? SCL2E : 1.0f;
        const int c = threadIdx.x & 63, r0 = (threadIdx.x >> 6) * 16;
#pragma unroll
        for (int i = 0; i < 16; ++i)
            T[r0 + i][c] = W[(long)(k0 + r0 + i) * 1024 + n0 + c];
        __syncthreads();
#pragma unroll
        for (int i = 0; i < 16; ++i)
            Wt[(long)(n0 + r0 + i) * 1024 + k0 + c] = f2bf(T[c][r0 + i] * scl);
    } else {
        const long wi = (long)(bid - 3072) * 256 + threadIdx.x;
        const int* src = mask + wi * 32;
        u32 word = 0;
#pragma unroll
        for (int c = 0; c < 8; ++c) {
            const int4 v = *(const int4*)(src + c * 4);
            word |= (u32)(v.x != 0) << (c * 4);
            word |= (u32)(v.y != 0) << (c * 4 + 1);
            word |= (u32)(v.z != 0) << (c * 4 + 2);
            word |= (u32)(v.w != 0) << (c * 4 + 3);
        }
        mp[wi] = word;
    }
}

// ---------------- QKV GEMM, 256x256 tile, 8-phase counted-vmcnt ------------
// [4096x1024] @ [1024x3072]. 192 blocks, 512 thr (8 waves 2Mx4N). BK=64,
// 2 LDS dbuf (128KB). Schedule r11-refcheck-verified.
// V-blocks (nBase>=2048): A-slot<-WvT panel, B-slot<-X panel so the identical
// pipeline computes V^T = Wv^T X; epilogue writes V^T [1024 hd][4096 tok].

__global__ __launch_bounds__(512, 2) void gemm_qkv(
    const u16* __restrict__ Ag, const u16* __restrict__ Btg,
    u16* __restrict__ C0, u16* __restrict__ Vt)
{
    __shared__ u16 Asm[2][256 * 64];
    __shared__ u16 Bsm[2][256 * 64];

    const int tid = threadIdx.x, lane = tid & 63, w = tid >> 6;
    const int wm = w >> 2, wn = w & 3;
    const int g = lane >> 4, lr = lane & 15;

    const int L = blockIdx.x;
    const int xcd = L & 7, idx = L >> 3;
    const long mBase = (long)((xcd & 3) * 4 + (idx & 3)) * 256;
    const long nBase = (long)((xcd >> 2) * 6 + (idx >> 2)) * 256;
    const bool vblk = (nBase >= 2048);

    const int srow = tid >> 3;
    const int scolb = ((tid & 7) << 4) ^ ((srow & 7) << 4);
    const long aoff = (mBase + srow) * 1024 + (scolb >> 1);
    const long boff = (nBase + srow) * 1024 + (scolb >> 1);
    const int ldst = tid * 16;

    const u16* AsrcP = vblk ? Btg : Ag;
    const u16* BsrcP = vblk ? Ag  : Btg;
    const long aoffE = vblk ? boff : aoff;
    const long boffE = vblk ? aoff : boff;

    int kb[2];
#pragma unroll
    for (int ks = 0; ks < 2; ++ks) kb[ks] = (ks * 64 + g * 16) ^ ((lr & 7) << 4);

    auto stA = [&](int d, int h, int kt) {
        gll16(AsrcP + aoffE + (long)h * 131072 + (long)kt * 64,
              (char*)&Asm[d][0] + h * 16384 + ldst);
        gll16(AsrcP + aoffE + (long)h * 131072 + 65536 + (long)kt * 64,
              (char*)&Asm[d][0] + h * 16384 + 8192 + ldst);
    };
    auto stB = [&](int d, int h, int kt) {
        gll16(BsrcP + boffE + (long)h * 131072 + (long)kt * 64,
              (char*)&Bsm[d][0] + h * 16384 + ldst);
        gll16(BsrcP + boffE + (long)h * 131072 + 65536 + (long)kt * 64,
              (char*)&Bsm[d][0] + h * 16384 + 8192 + ldst);
    };
    auto rdA = [&](int d, int mi, int ks) {
        return *(const bf16x8*)((const char*)&Asm[d][0] + (wm * 128 + mi * 16 + lr) * 128 + kb[ks]);
    };
    auto rdB = [&](int d, int ni, int ks) {
        return *(const bf16x8*)((const char*)&Bsm[d][0] + (wn * 64 + ni * 16 + lr) * 128 + kb[ks]);
    };

    f32x4 acc[8][4];
#pragma unroll
    for (int i = 0; i < 8; ++i)
#pragma unroll
        for (int j = 0; j < 4; ++j) acc[i][j] = f32x4{0.f, 0.f, 0.f, 0.f};

    // ---- prologue
    stB(0, 0, 0); stB(0, 1, 0);
    stA(0, 0, 0); stA(0, 1, 0);
    stB(1, 0, 1); stB(1, 1, 1);
    asm volatile("s_waitcnt vmcnt(4)" ::: "memory");
    bar();

    auto ktile = [&](int d, int ktA, int ktB, bool doA, bool doB, int vm) {
        bf16x8 af[4][2], bfr[4][2];
        // ---- phase 0 ----
#pragma unroll
        for (int mi = 0; mi < 4; ++mi) {
            af[mi][0] = rdA(d, mi, 0);
            af[mi][1] = rdA(d, mi, 1);
        }
#pragma unroll
        for (int ni = 0; ni < 2; ++ni) {
            bfr[ni][0] = rdB(d, ni, 0);
            bfr[ni][1] = rdB(d, ni, 1);
        }
        if (doA) stA(d ^ 1, 0, ktA);
        bar();
        __builtin_amdgcn_s_setprio(1);
#pragma unroll
        for (int mi = 0; mi < 4; ++mi)
#pragma unroll
            for (int ni = 0; ni < 2; ++ni) {
                acc[mi][ni] = __builtin_amdgcn_mfma_f32_16x16x32_bf16(af[mi][0], bfr[ni][0], acc[mi][ni], 0, 0, 0);
                acc[mi][ni] = __builtin_amdgcn_mfma_f32_16x16x32_bf16(af[mi][1], bfr[ni][1], acc[mi][ni], 0, 0, 0);
            }
        __builtin_amdgcn_s_setprio(0);
        bar();
        // ---- phase 1 ----
#pragma unroll
        for (int ni = 2; ni < 4; ++ni) {
            bfr[ni][0] = rdB(d, ni, 0);
            bfr[ni][1] = rdB(d, ni, 1);
        }
        if (doA) stA(d ^ 1, 1, ktA);
        bar();
        __builtin_amdgcn_s_setprio(1);
#pragma unroll
        for (int mi = 0; mi < 4; ++mi)
#pragma unroll
            for (int ni = 2; ni < 4; ++ni) {
                acc[mi][ni] = __builtin_amdgcn_mfma_f32_16x16x32_bf16(af[mi][0], bfr[ni][0], acc[mi][ni], 0, 0, 0);
                acc[mi][ni] = __builtin_amdgcn_mfma_f32_16x16x32_bf16(af[mi][1], bfr[ni][1], acc[mi][ni], 0, 0, 0);
            }
        __builtin_amdgcn_s_setprio(0);
        bar();
        // ---- phase 2 ----
#pragma unroll
        for (int mi = 0; mi < 4; ++mi) {
            af[mi][0] = rdA(d, mi + 4, 0);
            af[mi][1] = rdA(d, mi + 4, 1);
        }
        if (doB) stB(d, 0, ktB);
        bar();
        __builtin_amdgcn_s_setprio(1);
#pragma unroll
        for (int mi = 0; mi < 4; ++mi)
#pragma unroll
            for (int ni = 0; ni < 2; ++ni) {
                acc[mi + 4][ni] = __builtin_amdgcn_mfma_f32_16x16x32_bf16(af[mi][0], bfr[ni][0], acc[mi + 4][ni], 0, 0, 0);
                acc[mi + 4][ni] = __builtin_amdgcn_mfma_f32_16x16x32_bf16(af[mi][1], bfr[ni][1], acc[mi + 4][ni], 0, 0, 0);
            }
        __builtin_amdgcn_s_setprio(0);
        bar();
        // ---- phase 3 ----
        if (doB) stB(d, 1, ktB);
        bar();
        __builtin_amdgcn_s_setprio(1);
#pragma unroll
        for (int mi = 0; mi < 4; ++mi)
#pragma unroll
            for (int ni = 2; ni < 4; ++ni) {
                acc[mi + 4][ni] = __builtin_amdgcn_mfma_f32_16x16x32_bf16(af[mi][0], bfr[ni][0], acc[mi + 4][ni], 0, 0, 0);
                acc[mi + 4][ni] = __builtin_amdgcn_mfma_f32_16x16x32_bf16(af[mi][1], bfr[ni][1], acc[mi + 4][ni], 0, 0, 0);
            }
        __builtin_amdgcn_s_setprio(0);
        if (vm == 0)      asm volatile("s_waitcnt vmcnt(4)" ::: "memory");
        else if (vm == 1) asm volatile("s_waitcnt vmcnt(0)" ::: "memory");
        bar();
    };

    for (int c = 0; c < 14; c += 2) {
        ktile(0, c + 1, c + 2, true, true, 0);
        ktile(1, c + 2, c + 3, true, true, 0);
    }
    ktile(0, 15, 16, true, false, 1);
    ktile(1, 16, 17, false, false, 2);

    // ---- epilogue ----
    if (!vblk) {
        const int wsel = (int)(nBase >> 10);
        u16* Cw = C0 + (long)wsel * (4096l * 1024);
        const long ncl = (nBase & 1023) + wn * 64;
        const long rbase = mBase + wm * 128;
#pragma unroll
        for (int mi = 0; mi < 8; ++mi)
#pragma unroll
            for (int r = 0; r < 4; ++r) {
                const long row = rbase + mi * 16 + g * 4 + r;
#pragma unroll
                for (int ni = 0; ni < 4; ++ni)
                    Cw[row * 1024 + ncl + ni * 16 + lr] = f2bf(acc[mi][ni][r]);
            }
    } else {
        const long nb = nBase - 2048;
#pragma unroll
        for (int mi = 0; mi < 8; ++mi)
#pragma unroll
            for (int r = 0; r < 4; ++r) {
                const long rowN = nb + wm * 128 + mi * 16 + g * 4 + r;
#pragma unroll
                for (int ni = 0; ni < 4; ++ni) {
                    const long colT = mBase + wn * 64 + ni * 16 + lr;
                    Vt[rowN * 4096 + colT] = f2bf(acc[mi][ni][r]);
                }
            }
    }
}

// ---------------- output-proj GEMM, BM=64 (2 blocks/CU) --------------------

__global__ __launch_bounds__(256, 2) void gemm_out(
    const u16* __restrict__ A, const u16* __restrict__ Bt,
    float* __restrict__ Cf, const float* __restrict__ bias)
{
    constexpr int K = 1024, N = 1024;
    __shared__ u16 As[2][64 * 32];
    __shared__ u16 Bs[2][128 * 32];
    const int tid = threadIdx.x;
    const int wave = tid >> 6, lane = tid & 63;
    const int wr = wave >> 1, wc = wave & 1;
    const int g = lane >> 4, lr = lane & 15;
    const long mBase = (long)blockIdx.y * 64;
    const long nBase = (long)blockIdx.x * 128;

    f32x4 acc[2][4];
#pragma unroll
    for (int i = 0; i < 2; ++i)
#pragma unroll
        for (int j = 0; j < 4; ++j) acc[i][j] = f32x4{0.f, 0.f, 0.f, 0.f};

    const int oA = tid * 16;
    const int rA = oA >> 6, cbA = oA & 63;
    const int o0 = tid * 16, o1 = (256 + tid) * 16;
    const int r0 = o0 >> 6, cb0 = o0 & 63;
    const int r1 = o1 >> 6, cb1 = o1 & 63;

    gll16(A  + (mBase + rA) * K + (cbA >> 1), (char*)&As[0][0] + oA);
    gll16(Bt + (nBase + r0) * K + (cb0 >> 1), (char*)&Bs[0][0] + o0);
    gll16(Bt + (nBase + r1) * K + (cb1 >> 1), (char*)&Bs[0][0] + o1);
    __syncthreads();

#pragma unroll 2
    for (int kt = 0; kt < 32; ++kt) {
        const int buf = kt & 1;
        if (kt + 1 < 32) {
            const long ko = (long)(kt + 1) * 32;
            gll16(A  + (mBase + rA) * K + ko + (cbA >> 1), (char*)&As[buf ^ 1][0] + oA);
            gll16(Bt + (nBase + r0) * K + ko + (cb0 >> 1), (char*)&Bs[buf ^ 1][0] + o0);
            gll16(Bt + (nBase + r1) * K + ko + (cb1 >> 1), (char*)&Bs[buf ^ 1][0] + o1);
        }
        bf16x8 af[2], bfv[4];
#pragma unroll
        for (int mi = 0; mi < 2; ++mi)
            af[mi] = *(const bf16x8*)((const char*)&As[buf][0] + (wr * 32 + mi * 16 + lr) * 64 + g * 16);
#pragma unroll
        for (int ni = 0; ni < 4; ++ni)
            bfv[ni] = *(const bf16x8*)((const char*)&Bs[buf][0] + (wc * 64 + ni * 16 + lr) * 64 + g * 16);
#pragma unroll
        for (int mi = 0; mi < 2; ++mi)
#pragma unroll
            for (int ni = 0; ni < 4; ++ni)
                acc[mi][ni] = __builtin_amdgcn_mfma_f32_16x16x32_bf16(af[mi], bfv[ni], acc[mi][ni], 0, 0, 0);
        __syncthreads();
    }

#pragma unroll
    for (int mi = 0; mi < 2; ++mi)
#pragma unroll
        for (int r = 0; r < 4; ++r) {
            const long row = mBase + wr * 32 + mi * 16 + g * 4 + r;
#pragma unroll
            for (int ni = 0; ni < 4; ++ni) {
                const long col = nBase + wc * 64 + ni * 16 + lr;
                Cf[row * N + col] = acc[mi][ni][r] + bias[col];
            }
        }
}

// ---------------- flash attention (QBLK=256, 8 waves, per-half sequence) ---
// r10/r11-proven t-loop body: per half {QK, SM, PV} (the r12 QK-both-first
// variant regressed: +64 live VGPRs stretched dep chains; compiler already
// overlaps MFMA/VALU). V^T [1024 hd][4096 tok] from fused gemm_qkv.

__global__ __launch_bounds__(512, 2) void attn_fwd(
    const u16* __restrict__ Qg_, const u16* __restrict__ Kg_, const u16* __restrict__ Vtg_,
    const u32* __restrict__ maskp, u16* __restrict__ Og_)
{
    __shared__ u16 Ks[2][2][64 * 64];
    __shared__ u16 Vs[2][2][64 * 64];

    const int tid = threadIdx.x, w = tid >> 6, lane = tid & 63;
    const int g = lane >> 4, lr = lane & 15;
    const int L = blockIdx.x;
    const int slot = L >> 3;
    const int grp = (L & 7) + 8 * (slot >> 3);
    const int q0 = (slot & 7) * 256;
    const int b = grp >> 4, h = grp & 15;
    const u16* Qg = Qg_ + ((long)b * 2048) * 1024 + h * 64;
    const u16* Kg = Kg_ + ((long)b * 2048) * 1024 + h * 64;
    const u16* Vtg = Vtg_ + (long)(h * 64) * 4096 + (long)b * 2048;
    u16* Og = Og_ + ((long)b * 2048) * 1024 + h * 64;

    const int ldso = tid * 16;
    const int m = ldso >> 7, cb = ldso & 127;
    const int sb = cb ^ ((m & 7) << 4);
    const int kap = ((m >> 4) & 1) * 32 + ((m >> 2) & 3) * 8 + ((m >> 5) & 1) * 4 + (m & 3);
    const long ksrc = (long)kap * 1024 + (sb >> 1);
    const long vsrc = (long)m * 4096 + (sb >> 1);

    bf16x8 qf[2][2];
#pragma unroll
    for (int nq = 0; nq < 2; ++nq)
#pragma unroll
        for (int ks = 0; ks < 2; ++ks)
            qf[nq][ks] = *(const bf16x8*)(Qg + (long)(q0 + w * 32 + nq * 16 + lr) * 1024 + ks * 32 + g * 8);

    const long mrow0 = (long)b * 2048 + q0 + w * 32 + lr;
    const u32* mpr0 = maskp + mrow0 * 64;
    const u32* mpr1 = maskp + (mrow0 + 16) * 64;

    u32x4 mwC0 = *(const u32x4*)(mpr0);
    u32x4 mwC1 = *(const u32x4*)(mpr1);
#pragma unroll
    for (int hh = 0; hh < 2; ++hh) {
        gll16(Kg + hh * 65536 + ksrc, (char*)&Ks[0][hh][0] + ldso);
        gll16(Vtg + hh * 64 + vsrc, (char*)&Vs[0][hh][0] + ldso);
    }
    __syncthreads();

    const int swz = (lr & 7) << 4;
    int kb[2];
#pragma unroll
    for (int ks = 0; ks < 2; ++ks) kb[ks] = (ks * 64 + g * 16) ^ swz;

    f32x4 oacc[2][4];
#pragma unroll
    for (int i = 0; i < 2; ++i)
#pragma unroll
        for (int j = 0; j < 4; ++j) oacc[i][j] = f32x4{0.f, 0.f, 0.f, 0.f};
    f32x4 osum[2];
    osum[0] = f32x4{0.f, 0.f, 0.f, 0.f};
    osum[1] = f32x4{0.f, 0.f, 0.f, 0.f};
    const f32x4 z4 = {0.f, 0.f, 0.f, 0.f};
    const u32x4 ones4 = {0x3F803F80u, 0x3F803F80u, 0x3F803F80u, 0x3F803F80u};
    const bf16x8 ones8 = __builtin_bit_cast(bf16x8, ones4);

#pragma unroll 2
    for (int t = 0; t < 16; ++t) {
        const int cur = t & 1;
        u32x4 mwN0, mwN1;
        if (t + 1 < 16) {
            mwN0 = *(const u32x4*)(mpr0 + (t + 1) * 4);
            mwN1 = *(const u32x4*)(mpr1 + (t + 1) * 4);
            const long kv0 = (long)(t + 1) * 128;
#pragma unroll
            for (int hh = 0; hh < 2; ++hh) {
                gll16(Kg + (kv0 + hh * 64) * 1024 + ksrc, (char*)&Ks[cur ^ 1][hh][0] + ldso);
                gll16(Vtg + kv0 + hh * 64 + vsrc, (char*)&Vs[cur ^ 1][hh][0] + ldso);
            }
        }

#pragma unroll
        for (int hh = 0; hh < 2; ++hh) {
            const char* kbase = (const char*)&Ks[cur][hh][0];
            const char* vbase = (const char*)&Vs[cur][hh][0];

            // S^T = K . Q^T (Q pre-scaled)
            f32x4 s[4][2];
            __builtin_amdgcn_s_setprio(1);
#pragma unroll
            for (int mt = 0; mt < 4; ++mt) {
                const bf16x8 kf0 = *(const bf16x8*)(kbase + (mt * 16 + lr) * 128 + kb[0]);
                const bf16x8 kf1 = *(const bf16x8*)(kbase + (mt * 16 + lr) * 128 + kb[1]);
#pragma unroll
                for (int nq = 0; nq < 2; ++nq) {
                    s[mt][nq] = __builtin_amdgcn_mfma_f32_16x16x32_bf16(kf0, qf[nq][0], z4, 0, 0, 0);
                    s[mt][nq] = __builtin_amdgcn_mfma_f32_16x16x32_bf16(kf1, qf[nq][1], s[mt][nq], 0, 0, 0);
                }
            }
            __builtin_amdgcn_s_setprio(0);

            // masked softmax: P = exp2(s) AND keep-mask (sbfe of inverted word)
            u32 pk[4][2][2];
#pragma unroll
            for (int ts = 0; ts < 4; ++ts) {
                const int sh = g * 8 + (ts >> 1) * 4;
                const int wi = hh * 2 + (ts & 1);
#pragma unroll
                for (int nq = 0; nq < 2; ++nq) {
                    const u32 word = nq ? mwC1[wi] : mwC0[wi];
                    const u32 iwsh = (~word) >> sh;
                    float e[4];
#pragma unroll
                    for (int r = 0; r < 4; ++r) {
                        const float ev = fexp2(s[ts][nq][r]);
                        const u32 keep = (u32)__builtin_amdgcn_sbfe((int)iwsh, (u32)r, 1u);
                        e[r] = __builtin_bit_cast(float, __builtin_bit_cast(u32, ev) & keep);
                    }
                    pk[ts][nq][0] = cvtpk_bf16(e[0], e[1]);
                    pk[ts][nq][1] = cvtpk_bf16(e[2], e[3]);
                }
            }

            // O += P.V ; row-sum via ones-MFMA
            bf16x8 pa[2][2];
#pragma unroll
            for (int nq = 0; nq < 2; ++nq)
#pragma unroll
                for (int ks = 0; ks < 2; ++ks) {
                    u32x4 t4;
                    t4[0] = pk[ks][nq][0]; t4[1] = pk[ks][nq][1];
                    t4[2] = pk[ks + 2][nq][0]; t4[3] = pk[ks + 2][nq][1];
                    pa[nq][ks] = __builtin_bit_cast(bf16x8, t4);
                }
            __builtin_amdgcn_s_setprio(1);
#pragma unroll
            for (int nq = 0; nq < 2; ++nq)
#pragma unroll
                for (int ks = 0; ks < 2; ++ks)
                    osum[nq] = __builtin_amdgcn_mfma_f32_16x16x32_bf16(pa[nq][ks], ones8, osum[nq], 0, 0, 0);
#pragma unroll
            for (int dt = 0; dt < 4; ++dt)
#pragma unroll
                for (int ks = 0; ks < 2; ++ks) {
                    const bf16x8 vf = *(const bf16x8*)(vbase + (dt * 16 + lr) * 128 + kb[ks]);
#pragma unroll
                    for (int nq = 0; nq < 2; ++nq)
                        oacc[nq][dt] = __builtin_amdgcn_mfma_f32_16x16x32_bf16(pa[nq][ks], vf, oacc[nq][dt], 0, 0, 0);
                }
            __builtin_amdgcn_s_setprio(0);
        }
        __syncthreads();

        mwC0 = mwN0; mwC1 = mwN1;
    }

#pragma unroll
    for (int nq = 0; nq < 2; ++nq)
#pragma unroll
        for (int rr = 0; rr < 4; ++rr) {
            const float inv = __builtin_amdgcn_rcpf(osum[nq][rr]);
            const long row = (long)q0 + w * 32 + nq * 16 + g * 4 + rr;
#pragma unroll
            for (int dt = 0; dt < 4; ++dt)
                Og[row * 1024 + dt * 16 + lr] = f2bf(oacc[nq][dt][rr] * inv);
        }
}

// ---------------- launcher ----------------

extern "C" void kernel_launch(void* const* d_in, const int* in_sizes, int n_in,
                              void* d_out, int out_size, void* d_ws, size_t ws_size,
                              hipStream_t stream)
{
    (void)in_sizes; (void)n_in; (void)out_size; (void)ws_size;
    const float* x    = (const float*)d_in[0];
    const int*   mask = (const int*)d_in[1];
    const float* Wq   = (const float*)d_in[2];
    const float* Wk   = (const float*)d_in[3];
    const float* Wv   = (const float*)d_in[4];
    const float* Wo   = (const float*)d_in[5];
    const float* bo   = (const float*)d_in[6];
    float* out = (float*)d_out;

    char* ws = (char*)d_ws;
    u16* xb    = (u16*)(ws);                 // 8 MB  x as bf16
    u16* WqT   = (u16*)(ws + (8l  << 20));   // 2 MB each, transposed bf16 (q,k,v contiguous)
    u16* WkT   = (u16*)(ws + (10l << 20));
    u16* WvT   = (u16*)(ws + (12l << 20));
    u16* WoT   = (u16*)(ws + (14l << 20));
    u16* qws   = (u16*)(ws + (16l << 20));   // 8 MB each (q,k contiguous)
    u16* kws   = (u16*)(ws + (24l << 20));
    u16* vtws  = (u16*)(ws + (32l << 20));   // 8 MB  V^T [1024][4096] (from gemm_qkv)
    u16* inner = (u16*)(ws + (40l << 20));   // 8 MB
    u32* mp    = (u32*)(ws + (48l << 20));   // 1 MB packed mask

    prep_k<<<4096, 256, 0, stream>>>(x, xb, Wq, Wk, Wv, Wo, WqT, WkT, WvT, WoT, mask, mp);
    gemm_qkv<<<192, 512, 0, stream>>>(xb, WqT, qws, vtws);
    attn_fwd<<<256, 512, 0, stream>>>(qws, kws, vtws, mp, inner);
    gemm_out<<<dim3(8, 64), 256, 0, stream>>>(inner, WoT, out, bo);
    (void)kws;
}